// Round 9
// baseline (329.236 us; speedup 1.0000x reference)
//
#include <hip/hip_runtime.h>
#include <math.h>

#define LL 4096
#define NBATCH 4
#define CM 192
#define DI 384
#define NST 16
#define RK 12
#define NCH 44
#define SGH 96

typedef unsigned short ushort_t;
typedef __attribute__((ext_vector_type(8))) short bf16x8;
typedef __attribute__((ext_vector_type(4))) float f32x4;
typedef __attribute__((ext_vector_type(8))) unsigned short ushort8;
typedef __attribute__((ext_vector_type(4))) unsigned short ushort4v;

// workspace offsets (float units)
#define O_WT_IN   0
#define O_WT_LOW  147456
#define O_WT_XP   221184
#define O_WT_XPL  245760
#define O_WT_OUT  270336
#define O_XN      344064
#define O_LOWT    3489792
#define O_XH      6635520
#define O_Z       12926976
#define O_LOWP    19218432
#define O_XS      25509888
#define O_DBCH    31801344
#define O_DBCL    32522240
#define O_DBC     33243136
#define O_BS      33964032
#define O_CS      34226176
#define O_DELTA   O_LOWP   // lowp dead after x_proj GEMMs
#define O_Y       O_XH     // xh dead after conv2d
#define O_DTS     O_DBCH   // dbcH dead after gates_kernel

__device__ __forceinline__ ushort_t f2bf(float v) {
    unsigned u = __float_as_uint(v);
    return (ushort_t)((u + 0x7FFFu + ((u >> 16) & 1u)) >> 16);
}
__device__ __forceinline__ float bf2f(ushort_t h) {
    return __uint_as_float(((unsigned)h) << 16);
}

// ---- chunk-transposed ("perm") layout within each 4096-element row ----------
__device__ __forceinline__ int permidx(int l) {
    return ((l >> 2) & 3) * 1024 + ((l >> 4) << 2) + (l & 3);
}

// -------- merged weight prep: hi/lo splits + padded x_proj weights ------------
__global__ void wprep_kernel(const float* __restrict__ i0, ushort_t* h0, ushort_t* l0_,
                             const float* __restrict__ i1, ushort_t* h1, ushort_t* l1,
                             const float* __restrict__ i2, ushort_t* h2, ushort_t* l2,
                             const float* __restrict__ p0, ushort_t* ph0, ushort_t* pl0,
                             const float* __restrict__ p1, ushort_t* ph1, ushort_t* pl1)
{
    int bx = blockIdx.x;
    if (bx < 288) {
        const float* in; ushort_t* oh; ushort_t* ol; int base;
        if (bx < 144)      { in = i0; oh = h0; ol = l0_; base = bx * 1024; }
        else if (bx < 216) { in = i1; oh = h1; ol = l1;  base = (bx-144) * 1024; }
        else               { in = i2; oh = h2; ol = l2;  base = (bx-216) * 1024; }
        int i = base + threadIdx.x * 4;
        float4 v = *(const float4*)&in[i];
        ushort4v h, l;
        h.x = f2bf(v.x); l.x = f2bf(v.x - bf2f(h.x));
        h.y = f2bf(v.y); l.y = f2bf(v.y - bf2f(h.y));
        h.z = f2bf(v.z); l.z = f2bf(v.z - bf2f(h.z));
        h.w = f2bf(v.w); l.w = f2bf(v.w - bf2f(h.w));
        *(ushort4v*)&oh[i] = h;
        *(ushort4v*)&ol[i] = l;
    } else {
        int bb = bx - 288;
        int sel = bb / 24, bxx = bb % 24;
        const float* in = sel ? p1 : p0;
        ushort_t* oh = sel ? ph1 : ph0;
        ushort_t* ol = sel ? pl1 : pl0;
        int idx = (bxx * 256 + threadIdx.x) * 4;
        int n = idx / 384;
        float4 v = (n < NCH) ? *(const float4*)&in[idx] : make_float4(0.f,0.f,0.f,0.f);
        ushort4v h, l;
        h.x = f2bf(v.x); l.x = f2bf(v.x - bf2f(h.x));
        h.y = f2bf(v.y); l.y = f2bf(v.y - bf2f(h.y));
        h.z = f2bf(v.z); l.z = f2bf(v.z - bf2f(h.z));
        h.w = f2bf(v.w); l.w = f2bf(v.w - bf2f(h.w));
        *(ushort4v*)&oh[idx] = h;
        *(ushort4v*)&ol[idx] = l;
    }
}

// -------- merged activation prep: LN(192)+split (x) and plain split (low) -----
__global__ __launch_bounds__(256) void actprep_kernel(const float* __restrict__ X,
    const float* __restrict__ gw, const float* __restrict__ bw,
    ushort_t* __restrict__ oh, ushort_t* __restrict__ ol,
    const float* __restrict__ LOW, ushort_t* __restrict__ lh, ushort_t* __restrict__ llo)
{
    __shared__ float xt[64][193];
    __shared__ float reds[64][4], redq[64][4];
    __shared__ float mu_s[64], rs_s[64];
    int tid = threadIdx.x;
    if (blockIdx.x >= 256) {
        int i = ((blockIdx.x - 256) * 256 + tid) * 4;
        float4 v = *(const float4*)&LOW[i];
        ushort4v h, l;
        h.x = f2bf(v.x); l.x = f2bf(v.x - bf2f(h.x));
        h.y = f2bf(v.y); l.y = f2bf(v.y - bf2f(h.y));
        h.z = f2bf(v.z); l.z = f2bf(v.z - bf2f(h.z));
        h.w = f2bf(v.w); l.w = f2bf(v.w - bf2f(h.w));
        *(ushort4v*)&lh[i] = h;
        *(ushort4v*)&llo[i] = l;
        return;
    }
    int t0 = blockIdx.x * 64;
    const float* Xb = X + (size_t)t0 * CM;
#pragma unroll
    for (int i = 0; i < 12; i++) {
        int f4 = tid + 256 * i;
        float4 v = *(const float4*)&Xb[f4 * 4];
        int row = f4 / 48, c = (f4 % 48) * 4;
        xt[row][c] = v.x; xt[row][c+1] = v.y; xt[row][c+2] = v.z; xt[row][c+3] = v.w;
    }
    __syncthreads();
    int tok = tid & 63, p = tid >> 6;
    float s = 0.f, q = 0.f;
#pragma unroll 8
    for (int i = 0; i < 48; i++) { float v = xt[tok][p*48+i]; s += v; q = fmaf(v, v, q); }
    reds[tok][p] = s; redq[tok][p] = q;
    __syncthreads();
    if (tid < 64) {
        float ss = reds[tid][0]+reds[tid][1]+reds[tid][2]+reds[tid][3];
        float qq = redq[tid][0]+redq[tid][1]+redq[tid][2]+redq[tid][3];
        float mu = ss * (1.f/CM);
        float var = qq * (1.f/CM) - mu*mu;
        mu_s[tid] = mu; rs_s[tid] = rsqrtf(var + 1e-5f);
    }
    __syncthreads();
    int tok2 = tid >> 2, c0 = (tid & 3) * 48;
    float mu = mu_s[tok2], rs = rs_s[tok2];
    size_t tb = (size_t)(t0 + tok2) * CM;
#pragma unroll 8
    for (int i = 0; i < 48; i++) {
        int c = c0 + i;
        float v = (xt[tok2][c] - mu) * rs * gw[c] + bw[c];
        ushort_t h = f2bf(v);
        oh[tb + c] = h;
        ol[tb + c] = f2bf(v - bf2f(h));
    }
}

// -------- split-bf16 MFMA GEMM, token-major bf16 A planes ---------------------
template<int MODE, int SPLIT, int KDIM>
__global__ __launch_bounds__(256) void gemm_mfma(
    const ushort_t* __restrict__ Ahi, const ushort_t* __restrict__ Alo,
    const ushort_t* __restrict__ Whi, const ushort_t* __restrict__ Wlo,
    float* __restrict__ out0, float* __restrict__ out1)
{
    __shared__ __align__(16) char smem[33280];
    ushort_t* sAh = (ushort_t*)smem;        // [4][128][8]
    ushort_t* sAl = sAh + 4096;
    ushort_t* sWh = sAh + 8192;             // [4][64][8]
    ushort_t* sWl = sAh + 10240;
    int tid = threadIdx.x;
    int t0 = blockIdx.x * 128;
    int b = t0 >> 12, l0 = t0 & 4095;
    int n0 = blockIdx.y * 64;
    int arow = tid >> 1, kgA = (tid & 1) * 2;
    int wrow = tid >> 2, kgW = tid & 3;
    const ushort_t* gAh = Ahi + (size_t)(t0 + arow) * KDIM + kgA * 8;
    const ushort_t* gAl = Alo + (size_t)(t0 + arow) * KDIM + kgA * 8;
    const ushort_t* gWh = Whi + (size_t)(n0 + wrow) * KDIM + kgW * 8;
    const ushort_t* gWl = Wlo + (size_t)(n0 + wrow) * KDIM + kgW * 8;
    int lane = tid & 63, w = tid >> 6;
    int ln = lane & 15, kg = lane >> 4;
    int am0 = w * 32 + ln;
    f32x4 acc[2][4];
#pragma unroll
    for (int mf = 0; mf < 2; mf++)
#pragma unroll
        for (int nf = 0; nf < 4; nf++) acc[mf][nf] = (f32x4){0.f, 0.f, 0.f, 0.f};

    for (int k0 = 0; k0 < KDIM; k0 += 32) {
        __syncthreads();
        {
            ushort8 a0 = *(const ushort8*)(gAh + k0);
            ushort8 a1 = *(const ushort8*)(gAh + k0 + 8);
            *(ushort8*)(sAh + kgA*1024 + arow*8) = a0;
            *(ushort8*)(sAh + (kgA+1)*1024 + arow*8) = a1;
            ushort8 w0 = *(const ushort8*)(gWh + k0);
            *(ushort8*)(sWh + kgW*512 + wrow*8) = w0;
            if (SPLIT == 3) {
                ushort8 b0 = *(const ushort8*)(gAl + k0);
                ushort8 b1 = *(const ushort8*)(gAl + k0 + 8);
                *(ushort8*)(sAl + kgA*1024 + arow*8) = b0;
                *(ushort8*)(sAl + (kgA+1)*1024 + arow*8) = b1;
                ushort8 w1 = *(const ushort8*)(gWl + k0);
                *(ushort8*)(sWl + kgW*512 + wrow*8) = w1;
            }
        }
        __syncthreads();
        bf16x8 aH[2], bH[4];
#pragma unroll
        for (int mf = 0; mf < 2; mf++)
            aH[mf] = *(const bf16x8*)(sAh + kg*1024 + (am0 + mf*16)*8);
#pragma unroll
        for (int nf = 0; nf < 4; nf++)
            bH[nf] = *(const bf16x8*)(sWh + kg*512 + (nf*16 + ln)*8);
#pragma unroll
        for (int mf = 0; mf < 2; mf++)
#pragma unroll
            for (int nf = 0; nf < 4; nf++)
                acc[mf][nf] = __builtin_amdgcn_mfma_f32_16x16x32_bf16(aH[mf], bH[nf], acc[mf][nf], 0, 0, 0);
        if (SPLIT == 3) {
            bf16x8 aL[2], bL[4];
#pragma unroll
            for (int mf = 0; mf < 2; mf++)
                aL[mf] = *(const bf16x8*)(sAl + kg*1024 + (am0 + mf*16)*8);
#pragma unroll
            for (int nf = 0; nf < 4; nf++)
                bL[nf] = *(const bf16x8*)(sWl + kg*512 + (nf*16 + ln)*8);
#pragma unroll
            for (int mf = 0; mf < 2; mf++)
#pragma unroll
                for (int nf = 0; nf < 4; nf++) {
                    acc[mf][nf] = __builtin_amdgcn_mfma_f32_16x16x32_bf16(aH[mf], bL[nf], acc[mf][nf], 0, 0, 0);
                    acc[mf][nf] = __builtin_amdgcn_mfma_f32_16x16x32_bf16(aL[mf], bH[nf], acc[mf][nf], 0, 0, 0);
                }
        }
    }
    __syncthreads();
    float* st = (float*)smem;   // [64][130]
#pragma unroll
    for (int mf = 0; mf < 2; mf++)
#pragma unroll
        for (int nf = 0; nf < 4; nf++)
#pragma unroll
            for (int j = 0; j < 4; j++) {
                int ml = w*32 + mf*16 + (lane>>4)*4 + j;
                int nl = nf*16 + ln;
                st[nl*130 + ml] = acc[mf][nf][j];
            }
    __syncthreads();
    int nl = tid >> 2, mq = (tid & 3) * 32;
    int n = n0 + nl;
    float* dst;
    if (MODE == 0) {
        dst = (n < DI) ? (out0 + ((size_t)b*DI + n)*LL + l0 + mq)
                       : (out1 + ((size_t)b*DI + (n - DI))*LL + l0 + mq);
    } else {
        dst = out0 + ((size_t)b*DI + n)*LL + l0 + mq;
    }
#pragma unroll
    for (int i = 0; i < 8; i++)
        *(float4*)(dst + i*4) = *(const float4*)&st[nl*130 + mq + i*4];
}

// -------- channel-major-A MFMA GEMM (fp32 A staged + on-the-fly bf16 split) ---
template<int MODE, int SPLIT, int PERM0>
__global__ __launch_bounds__(256) void gemm_cmaj(
    const float* __restrict__ A0, const float* __restrict__ A1,
    const ushort_t* __restrict__ W0h, const ushort_t* __restrict__ W0l,
    const ushort_t* __restrict__ W1h, const ushort_t* __restrict__ W1l,
    const float* __restrict__ resid,
    float* __restrict__ o0, float* __restrict__ o1, int Nreal)
{
    __shared__ __align__(16) char smem[33280];
    float* sA = (float*)smem;                       // [32][132]
    ushort_t* sWh = (ushort_t*)(smem + 16896);      // [4][64][8]
    ushort_t* sWl = (ushort_t*)(smem + 20992);
    bool sel = (blockIdx.z == 1);
    const float* A = sel ? A1 : A0;
    const ushort_t* Wh = sel ? W1h : W0h;
    const ushort_t* Wl = sel ? W1l : W0l;
    float* out0 = sel ? o1 : o0;
    const bool perm = sel ? false : (PERM0 != 0);
    int tid = threadIdx.x;
    int t0 = blockIdx.x * 128;
    int b = t0 >> 12, l0 = t0 & 4095;
    int n0 = blockIdx.y * 64;
    const float* Ab = A + (size_t)b * 384 * LL;
    int srow = tid >> 3, sc8 = tid & 7;
    int wrow = tid >> 2, kgW = tid & 3;
    int lane = tid & 63, w = tid >> 6;
    int ln = lane & 15, kg = lane >> 4;
    int am0 = w * 32 + ln;
    f32x4 acc[2][4];
#pragma unroll
    for (int mf = 0; mf < 2; mf++)
#pragma unroll
        for (int nf = 0; nf < 4; nf++) acc[mf][nf] = (f32x4){0.f, 0.f, 0.f, 0.f};

    for (int k0 = 0; k0 < 384; k0 += 32) {
        __syncthreads();
#pragma unroll
        for (int i = 0; i < 4; i++) {
            int m = (sc8 + 8*i) * 4;
            int src = perm ? ((((m >> 2) & 3) * 1024) + (((l0 + m) >> 4) << 2))
                           : (l0 + m);
            float4 v = *(const float4*)&Ab[(size_t)(k0 + srow)*LL + src];
            *(float4*)&sA[srow*132 + m] = v;
        }
        {
            ushort8 wv = *(const ushort8*)(Wh + (size_t)(n0 + wrow)*384 + k0 + kgW*8);
            *(ushort8*)(sWh + kgW*512 + wrow*8) = wv;
            if (SPLIT == 3) {
                ushort8 wl = *(const ushort8*)(Wl + (size_t)(n0 + wrow)*384 + k0 + kgW*8);
                *(ushort8*)(sWl + kgW*512 + wrow*8) = wl;
            }
        }
        __syncthreads();
        bf16x8 aH[2], aL[2];
#pragma unroll
        for (int mf = 0; mf < 2; mf++) {
            int am = am0 + mf*16;
#pragma unroll
            for (int e = 0; e < 8; e++) {
                float v = sA[(kg*8 + e)*132 + am];
                ushort_t h = f2bf(v);
                aH[mf][e] = (short)h;
                if (SPLIT == 3) aL[mf][e] = (short)f2bf(v - bf2f(h));
            }
        }
        bf16x8 bH[4], bL[4];
#pragma unroll
        for (int nf = 0; nf < 4; nf++) {
            bH[nf] = *(const bf16x8*)(sWh + kg*512 + (nf*16 + ln)*8);
            if (SPLIT == 3) bL[nf] = *(const bf16x8*)(sWl + kg*512 + (nf*16 + ln)*8);
        }
#pragma unroll
        for (int mf = 0; mf < 2; mf++)
#pragma unroll
            for (int nf = 0; nf < 4; nf++) {
                acc[mf][nf] = __builtin_amdgcn_mfma_f32_16x16x32_bf16(aH[mf], bH[nf], acc[mf][nf], 0, 0, 0);
                if (SPLIT == 3) {
                    acc[mf][nf] = __builtin_amdgcn_mfma_f32_16x16x32_bf16(aH[mf], bL[nf], acc[mf][nf], 0, 0, 0);
                    acc[mf][nf] = __builtin_amdgcn_mfma_f32_16x16x32_bf16(aL[mf], bH[nf], acc[mf][nf], 0, 0, 0);
                }
            }
    }

    if (MODE == 2) {
#pragma unroll
        for (int mf = 0; mf < 2; mf++)
#pragma unroll
            for (int j = 0; j < 4; j++) {
                int t = t0 + w*32 + mf*16 + (lane>>4)*4 + j;
#pragma unroll
                for (int nf = 0; nf < 4; nf++) {
                    int n = n0 + nf*16 + ln;
                    out0[(size_t)t*CM + n] = resid[(size_t)t*CM + n] + acc[mf][nf][j];
                }
            }
    } else {
        __syncthreads();
        float* st = (float*)smem;   // [64][130]
#pragma unroll
        for (int mf = 0; mf < 2; mf++)
#pragma unroll
            for (int nf = 0; nf < 4; nf++)
#pragma unroll
                for (int j = 0; j < 4; j++) {
                    int ml = w*32 + mf*16 + (lane>>4)*4 + j;
                    int nl = nf*16 + ln;
                    st[nl*130 + ml] = acc[mf][nf][j];
                }
        __syncthreads();
        int nl = tid >> 2, mq = (tid & 3) * 32;
        int n = n0 + nl;
        if (n < Nreal) {
            float* dst = out0 + ((size_t)b*Nreal + n)*LL + l0 + mq;
#pragma unroll
            for (int i = 0; i < 8; i++)
                *(float4*)(dst + i*4) = *(const float4*)&st[nl*130 + mq + i*4];
        }
    }
}

// -------- depthwise 3x3 conv + bias + SiLU -> xs in PERM layout ---------------
__global__ __launch_bounds__(256) void conv2d_silu_kernel(const float* __restrict__ xh,
    const float* __restrict__ w, const float* __restrict__ bias, float* __restrict__ xs)
{
    int tid = threadIdx.x;
    int l = blockIdx.x * 256 + tid;
    int c = blockIdx.y, b = blockIdx.z;
    const float* P = xh + ((size_t)b*DI + c)*LL;
    int h = l >> 6, ww = l & 63;
    float acc = bias[c];
#pragma unroll
    for (int kh = 0; kh < 3; kh++) {
        int hh = h + kh - 1;
        if ((unsigned)hh < 64u) {
#pragma unroll
            for (int kw = 0; kw < 3; kw++) {
                int wv = ww + kw - 1;
                if ((unsigned)wv < 64u) acc = fmaf(w[c*9 + kh*3 + kw], P[hh*64 + wv], acc);
            }
        }
    }
    float sg = 1.f / (1.f + __expf(-acc));
    xs[((size_t)b*DI + c)*LL + permidx(l)] = acc * sg;
}

// -------- SimpleGates on low B/C + sum high+low -> dbc [B][44][L] -------------
__global__ __launch_bounds__(256) void gates_kernel(const float* __restrict__ dbcH,
    const float* __restrict__ dbcL,
    const float* __restrict__ sgb1, const float* __restrict__ sgb2,
    const float* __restrict__ sgc1, const float* __restrict__ sgc2,
    float* __restrict__ dbc)
{
    __shared__ float w1[2][192*16];
    __shared__ float w2[2][16*96];
    __shared__ float red[4][16][64];
    int tid = threadIdx.x;
    for (int i = tid; i < 192*16; i += 256) { w1[0][i] = sgb1[i]; w1[1][i] = sgc1[i]; }
    for (int i = tid; i < 16*96;  i += 256) { w2[0][i] = sgb2[i]; w2[1][i] = sgc2[i]; }
    int lq = tid & 63, p = tid >> 6;
    int l = blockIdx.x * 64 + lq;
    int b = blockIdx.y;
    size_t pb_ = (size_t)b*NCH*LL + l;
    __syncthreads();
#pragma unroll
    for (int i = 0; i < 3; i++) {
        int c = p*3 + i;
        dbc[pb_ + (size_t)c*LL] = dbcH[pb_ + (size_t)c*LL] + dbcL[pb_ + (size_t)c*LL];
    }
    for (int gate = 0; gate < 2; gate++) {
        int coff = RK + gate*NST;
        float xin[16], og[16];
#pragma unroll
        for (int n = 0; n < 16; n++) { xin[n] = dbcL[pb_ + (size_t)(coff+n)*LL]; og[n] = 0.f; }
        int h0 = p * 24;
        for (int h = h0; h < h0 + 24; h++) {
            float ya = 0.f, yb = 0.f;
#pragma unroll
            for (int n = 0; n < 16; n++) {
                ya = fmaf(w1[gate][h*16+n], xin[n], ya);
                yb = fmaf(w1[gate][(h+SGH)*16+n], xin[n], yb);
            }
            float gg = 0.5f * ya * (1.f + erff(ya * 0.70710678f)) * yb;
#pragma unroll
            for (int n = 0; n < 16; n++) og[n] = fmaf(w2[gate][n*SGH+h], gg, og[n]);
        }
#pragma unroll
        for (int n = 0; n < 16; n++) red[p][n][lq] = og[n];
        __syncthreads();
#pragma unroll
        for (int i = 0; i < 4; i++) {
            int n = p*4 + i;
            float v = red[0][n][lq] + red[1][n][lq] + red[2][n][lq] + red[3][n][lq];
            dbc[pb_ + (size_t)(coff+n)*LL] = dbcH[pb_ + (size_t)(coff+n)*LL] + v;
        }
        __syncthreads();
    }
}

// -------- residual dilated dwconv1d: dts normal; Bs/Cs in PERM layout ---------
__global__ __launch_bounds__(256) void conv_dbc_kernel(const float* __restrict__ dbc,
    const float* __restrict__ wdt, const float* __restrict__ wB, const float* __restrict__ wC,
    float* __restrict__ dts, float* __restrict__ Bs, float* __restrict__ Cs)
{
    int l = blockIdx.x * 256 + threadIdx.x;
    int c = blockIdx.y, b = blockIdx.z;
    const float* wsrc = (c < RK) ? (wdt + c*15)
                      : (c < RK+NST ? wB + (c-RK)*15 : wC + (c-RK-NST)*15);
    float w[15];
#pragma unroll
    for (int k = 0; k < 15; k++) w[k] = wsrc[k];
    const float* P = dbc + ((size_t)b*NCH + c)*LL;
    float a = P[l];
#pragma unroll
    for (int k = 0; k < 15; k++) {
        int lt = l + 2*k - 14;
        if ((unsigned)lt < (unsigned)LL) a = fmaf(w[k], P[lt], a);
    }
    if (c < RK)            dts[((size_t)b*RK  + c)*LL + l] = a;
    else if (c < RK+NST)   Bs [((size_t)b*NST + (c-RK))*LL + permidx(l)] = a;
    else                   Cs [((size_t)b*NST + (c-RK-NST))*LL + permidx(l)] = a;
}

// -------- delta projection + softplus -> delta in PERM layout -----------------
__global__ __launch_bounds__(256) void delta_kernel(const float* __restrict__ dts,
    const float* __restrict__ dtw, const float* __restrict__ dtb, float* __restrict__ delta)
{
    __shared__ float sdt[RK][128];
    __shared__ float sw[64][RK];
    int tid = threadIdx.x;
    int l0 = blockIdx.x * 128, d0 = blockIdx.y * 64, b = blockIdx.z;
    for (int i = tid; i < RK*128; i += 256) {
        int r = i >> 7, lq = i & 127;
        sdt[r][lq] = dts[((size_t)b*RK + r)*LL + l0 + lq];
    }
    for (int i = tid; i < 64*RK; i += 256) {
        int dq = i / RK, r = i - dq*RK;
        sw[dq][r] = dtw[(size_t)(d0+dq)*RK + r];
    }
    __syncthreads();
    int lq = tid & 63, g = tid >> 6;
    for (int dd = 0; dd < 16; dd++) {
        int dqq = g*16 + dd, d = d0 + dqq;
        float wr[RK];
#pragma unroll
        for (int r = 0; r < RK; r++) wr[r] = sw[dqq][r];
        float bias = dtb[d];
#pragma unroll
        for (int li = 0; li < 2; li++) {
            int lloc = lq + li*64;
            float s = bias;
#pragma unroll
            for (int r = 0; r < RK; r++) s = fmaf(wr[r], sdt[r][lloc], s);
            float sp = fmaxf(s, 0.f) + log1pf(__expf(-fabsf(s)));
            delta[((size_t)b*DI + d)*LL + permidx(l0 + lloc)] = sp;
        }
    }
}

// -------- selective scan v7: d-PAIR block (shared B/C reads), 512 thr x 8 tok -
// Each block handles (b, d0=2p, d1=2p+1): B/C rows loaded ONCE for both d's.
// Cuts L2/L3 read volume 1.2GB -> ~0.45GB (the measured invariant limiter).
// Per-j: local chains for both d + wave shuffle scan + 1 barrier + acum fixup
// (no phase-B reload). Fast path A_n=-(n+1) verified at runtime; generic
// fallback preserves correctness.
#define LD8P(dst, row) { \
  float4 _a = *(const float4*)((row) + o0); \
  float4 _b4 = *(const float4*)((row) + o1); \
  dst[0]=_a.x; dst[1]=_a.y; dst[2]=_a.z; dst[3]=_a.w; \
  dst[4]=_b4.x; dst[5]=_b4.y; dst[6]=_b4.z; dst[7]=_b4.w; }

__global__ __launch_bounds__(512) void scan_kernel(
    const float* __restrict__ u_, const float* __restrict__ delta_,
    const float* __restrict__ Bs_, const float* __restrict__ Cs_,
    const float* __restrict__ Alogs, const float* __restrict__ Ds,
    float* __restrict__ y_)
{
    __shared__ float wA[16][2][8], wB[16][2][8];
    __shared__ float yt[8][520];
    int tid = threadIdx.x;           // 0..511
    int bd = blockIdx.x;             // 768 = 4b * 192 pairs
    int b = bd / 192, pr = bd % 192;
    int d0 = pr * 2, d1 = d0 + 1;
    size_t row0 = ((size_t)b*DI + d0)*LL;
    size_t row1 = ((size_t)b*DI + d1)*LL;
    // perm addressing: thread owns tokens [tid*8, tid*8+8)
    int base = (tid >> 1) * 4;
    int o0 = ((2*tid) & 3) * 1024 + base;
    int o1 = ((2*tid + 1) & 3) * 1024 + base;
    float dl0[8], dl1[8], du0[8], du1[8], ya0[8], ya1[8], E0[8], E1[8];
    LD8P(du0, u_ + row0);  LD8P(du1, u_ + row1);
    LD8P(dl0, delta_ + row0);  LD8P(dl1, delta_ + row1);
    float Dd0 = Ds[d0], Dd1 = Ds[d1];
#pragma unroll
    for (int s = 0; s < 8; s++) {
        ya0[s] = du0[s]*Dd0; du0[s] *= dl0[s]; E0[s] = 1.f;
        ya1[s] = du1[s]*Dd1; du1[s] *= dl1[s]; E1[s] = 1.f;
    }
    bool fast = true;
#pragma unroll 1
    for (int n = 0; n < NST; n++) {
        float A0v = -__expf(Alogs[d0*NST + n]);
        float A1v = -__expf(Alogs[d1*NST + n]);
        fast = fast && (fabsf(A0v + (float)(n+1)) < 1e-3f * (float)(n+1))
                    && (fabsf(A1v + (float)(n+1)) < 1e-3f * (float)(n+1));
    }
    if (fast) {
#pragma unroll
        for (int s = 0; s < 8; s++) { dl0[s] = __expf(-dl0[s]); dl1[s] = __expf(-dl1[s]); }
    }
    int lane = tid & 63, w = tid >> 6;
#pragma unroll 1
    for (int j = 0; j < NST; j++) {
        float Bn[8], Cn[8];
        LD8P(Bn, Bs_ + ((size_t)b*NST + j)*LL);
        LD8P(Cn, Cs_ + ((size_t)b*NST + j)*LL);
        float a0 = 1.f, h0 = 0.f, a1 = 1.f, h1 = 0.f;
        float ac0[8], ac1[8];
        if (fast) {
#pragma unroll
            for (int s = 0; s < 8; s++) {
                E0[s] *= dl0[s];
                h0 = fmaf(E0[s], h0, du0[s]*Bn[s]);
                ya0[s] = fmaf(Cn[s], h0, ya0[s]);
                a0 *= E0[s]; ac0[s] = a0;
                E1[s] *= dl1[s];
                h1 = fmaf(E1[s], h1, du1[s]*Bn[s]);
                ya1[s] = fmaf(Cn[s], h1, ya1[s]);
                a1 *= E1[s]; ac1[s] = a1;
            }
        } else {
            float An0 = -__expf(Alogs[d0*NST + j]);
            float An1 = -__expf(Alogs[d1*NST + j]);
#pragma unroll
            for (int s = 0; s < 8; s++) {
                float e0 = __expf(dl0[s]*An0);
                h0 = fmaf(e0, h0, du0[s]*Bn[s]);
                ya0[s] = fmaf(Cn[s], h0, ya0[s]);
                a0 *= e0; ac0[s] = a0;
                float e1 = __expf(dl1[s]*An1);
                h1 = fmaf(e1, h1, du1[s]*Bn[s]);
                ya1[s] = fmaf(Cn[s], h1, ya1[s]);
                a1 *= e1; ac1[s] = a1;
            }
        }
        // wave-level inclusive shuffle scans (both d's interleaved)
        for (int off = 1; off < 64; off <<= 1) {
            float pa0 = __shfl_up(a0, (unsigned)off, 64);
            float pb0 = __shfl_up(h0, (unsigned)off, 64);
            float pa1 = __shfl_up(a1, (unsigned)off, 64);
            float pb1 = __shfl_up(h1, (unsigned)off, 64);
            if (lane >= off) {
                h0 = fmaf(a0, pb0, h0); a0 *= pa0;
                h1 = fmaf(a1, pb1, h1); a1 *= pa1;
            }
        }
        if (lane == 63) {
            wA[j][0][w] = a0; wB[j][0][w] = h0;
            wA[j][1][w] = a1; wB[j][1][w] = h1;
        }
        __syncthreads();
        float PB0 = 0.f, PB1 = 0.f;
        for (int ww = 0; ww < w; ww++) {
            PB0 = fmaf(wA[j][0][ww], PB0, wB[j][0][ww]);
            PB1 = fmaf(wA[j][1][ww], PB1, wB[j][1][ww]);
        }
        float hf0 = fmaf(a0, PB0, h0);
        float hf1 = fmaf(a1, PB1, h1);
        float t0v = __shfl_up(hf0, 1u, 64);
        float t1v = __shfl_up(hf1, 1u, 64);
        float hin0 = lane ? t0v : PB0;
        float hin1 = lane ? t1v : PB1;
#pragma unroll
        for (int s = 0; s < 8; s++) {
            ya0[s] = fmaf(Cn[s]*ac0[s], hin0, ya0[s]);
            ya1[s] = fmaf(Cn[s]*ac1[s], hin1, ya1[s]);
        }
    }
    // store d0 then d1 via LDS transpose (pad 520 -> 2-way banks, free)
#pragma unroll
    for (int i = 0; i < 8; i++) yt[i][tid] = ya0[i];
    __syncthreads();
#pragma unroll
    for (int r = 0; r < 8; r++)
        y_[row0 + r*512 + tid] = yt[tid & 7][r*64 + (tid >> 3)];
    __syncthreads();
#pragma unroll
    for (int i = 0; i < 8; i++) yt[i][tid] = ya1[i];
    __syncthreads();
#pragma unroll
    for (int r = 0; r < 8; r++)
        y_[row1 + r*512 + tid] = yt[tid & 7][r*64 + (tid >> 3)];
}

// -------- out-norm LN(384) on y + z-SiLU gating (in-place over y) -------------
__global__ __launch_bounds__(256) void outnorm_gate_kernel(float* yio,
    const float* __restrict__ z,
    const float* __restrict__ g, const float* __restrict__ bt)
{
    __shared__ float rs_[4][64], rq_[4][64];
    __shared__ float mu_s[64], rstd_s[64];
    int tid = threadIdx.x;
    int lq = tid & 63, p = tid >> 6;
    int l = blockIdx.x * 64 + lq;
    int b = blockIdx.y;
    float* yp = yio + (size_t)b*DI*LL + l;
    float s = 0.f, q = 0.f;
#pragma unroll 4
    for (int i = 0; i < 96; i++) {
        int d = p*96 + i;
        float v = yp[(size_t)d*LL];
        s += v; q = fmaf(v, v, q);
    }
    rs_[p][lq] = s; rq_[p][lq] = q;
    __syncthreads();
    if (p == 0) {
        float ss = rs_[0][lq]+rs_[1][lq]+rs_[2][lq]+rs_[3][lq];
        float qq = rq_[0][lq]+rq_[1][lq]+rq_[2][lq]+rq_[3][lq];
        float mu = ss * (1.f/DI);
        float var = qq * (1.f/DI) - mu*mu;
        mu_s[lq] = mu; rstd_s[lq] = rsqrtf(var + 1e-5f);
    }
    __syncthreads();
    float mu = mu_s[lq], rs = rstd_s[lq];
    const float* zp = z + (size_t)b*DI*LL + l;
#pragma unroll 4
    for (int i = 0; i < 96; i++) {
        int d = p*96 + i;
        float v = (yp[(size_t)d*LL] - mu)*rs*g[d] + bt[d];
        float zv = zp[(size_t)d*LL];
        float sg = 1.f / (1.f + __expf(-zv));
        yp[(size_t)d*LL] = v * (zv * sg);
    }
}

extern "C" void kernel_launch(void* const* d_in, const int* in_sizes, int n_in,
                              void* d_out, int out_size, void* d_ws, size_t ws_size,
                              hipStream_t stream)
{
    (void)in_sizes; (void)n_in; (void)out_size; (void)ws_size;
    const float* x     = (const float*)d_in[0];
    const float* low   = (const float*)d_in[1];
    const float* ln_g  = (const float*)d_in[2];
    const float* ln_b  = (const float*)d_in[3];
    const float* w_in  = (const float*)d_in[4];
    const float* w_low = (const float*)d_in[5];
    const float* w_c2d = (const float*)d_in[6];
    const float* b_c2d = (const float*)d_in[7];
    const float* w_xp  = (const float*)d_in[8];
    const float* w_xpl = (const float*)d_in[9];
    const float* w_cdt = (const float*)d_in[10];
    const float* w_cB  = (const float*)d_in[11];
    const float* w_cC  = (const float*)d_in[12];
    const float* sgb1  = (const float*)d_in[13];
    const float* sgb2  = (const float*)d_in[14];
    const float* sgc1  = (const float*)d_in[15];
    const float* sgc2  = (const float*)d_in[16];
    const float* dtw   = (const float*)d_in[17];
    const float* dtb   = (const float*)d_in[18];
    const float* Alogs = (const float*)d_in[19];
    const float* Ds    = (const float*)d_in[20];
    const float* ong   = (const float*)d_in[21];
    const float* onb   = (const float*)d_in[22];
    const float* w_out = (const float*)d_in[23];
    float* ws  = (float*)d_ws;
    float* out = (float*)d_out;
    dim3 blk(256);

    // bf16 plane aliases
    ushort_t* wInH  = (ushort_t*)(ws + O_WT_IN);   ushort_t* wInL  = wInH + 147456;
    ushort_t* wLowH = (ushort_t*)(ws + O_WT_LOW);  ushort_t* wLowL = wLowH + 73728;
    ushort_t* wOutH = (ushort_t*)(ws + O_WT_OUT);  ushort_t* wOutL = wOutH + 73728;
    ushort_t* wXpH  = (ushort_t*)(ws + O_WT_XP);   ushort_t* wXpL  = wXpH + 24576;
    ushort_t* wXplH = (ushort_t*)(ws + O_WT_XPL);  ushort_t* wXplL = wXplH + 24576;
    ushort_t* xnh   = (ushort_t*)(ws + O_XN);      ushort_t* xnl   = xnh + 3145728;
    ushort_t* lowh  = (ushort_t*)(ws + O_LOWT);    ushort_t* lowl  = lowh + 3145728;

    wprep_kernel<<<336, blk, 0, stream>>>(w_in, wInH, wInL, w_low, wLowH, wLowL,
                                          w_out, wOutH, wOutL,
                                          w_xp, wXpH, wXpL, w_xpl, wXplH, wXplL);

    actprep_kernel<<<3328, blk, 0, stream>>>(x, ln_g, ln_b, xnh, xnl, low, lowh, lowl);

    gemm_mfma<0,3,192><<<dim3(128,12), blk, 0, stream>>>(xnh, xnl, wInH, wInL,
                                                         ws+O_XH, ws+O_Z);
    gemm_mfma<1,3,192><<<dim3(128,6),  blk, 0, stream>>>(lowh, lowl, wLowH, wLowL,
                                                         ws+O_LOWP, nullptr);

    conv2d_silu_kernel<<<dim3(16,384,4), blk, 0, stream>>>(ws+O_XH, w_c2d, b_c2d, ws+O_XS);

    gemm_cmaj<1,3,1><<<dim3(128,1,2), blk, 0, stream>>>(ws+O_XS, ws+O_LOWP,
                                                        wXpH, wXpL, wXplH, wXplL,
                                                        nullptr, ws+O_DBCH, ws+O_DBCL, NCH);

    gates_kernel<<<dim3(64,4), blk, 0, stream>>>(ws+O_DBCH, ws+O_DBCL, sgb1, sgb2, sgc1, sgc2, ws+O_DBC);

    conv_dbc_kernel<<<dim3(16,44,4), blk, 0, stream>>>(ws+O_DBC, w_cdt, w_cB, w_cC,
                                                       ws+O_DTS, ws+O_BS, ws+O_CS);
    delta_kernel<<<dim3(32,6,4), blk, 0, stream>>>(ws+O_DTS, dtw, dtb, ws+O_DELTA);

    scan_kernel<<<768, dim3(512), 0, stream>>>(ws+O_XS, ws+O_DELTA, ws+O_BS, ws+O_CS, Alogs, Ds,
                                               ws+O_Y);

    outnorm_gate_kernel<<<dim3(64,4), blk, 0, stream>>>(ws+O_Y, ws+O_Z, ong, onb);

    gemm_cmaj<2,1,0><<<dim3(128,3,1), blk, 0, stream>>>(ws+O_Y, nullptr,
                                                        wOutH, wOutL, nullptr, nullptr,
                                                        x, out, nullptr, CM);
}

// Round 10
// 318.158 us; speedup vs baseline: 1.0348x; 1.0348x over previous
//
#include <hip/hip_runtime.h>
#include <math.h>

#define LL 4096
#define NBATCH 4
#define CM 192
#define DI 384
#define NST 16
#define RK 12
#define NCH 44
#define SGH 96

typedef unsigned short ushort_t;
typedef __attribute__((ext_vector_type(8))) short bf16x8;
typedef __attribute__((ext_vector_type(4))) float f32x4;
typedef __attribute__((ext_vector_type(8))) unsigned short ushort8;
typedef __attribute__((ext_vector_type(4))) unsigned short ushort4v;

// workspace offsets (float units)
#define O_WT_IN   0
#define O_WT_LOW  147456
#define O_WT_XP   221184
#define O_WT_XPL  245760
#define O_WT_OUT  270336
#define O_XN      344064
#define O_LOWT    3489792
#define O_XH      6635520
#define O_Z       12926976
#define O_LOWP    19218432
#define O_XS      25509888
#define O_DBCH    31801344
#define O_DBCL    32522240
#define O_DBC     33243136
#define O_BS      33964032
#define O_CS      34226176
#define O_DELTA   O_LOWP   // lowp dead after x_proj GEMMs
#define O_Y       O_XH     // xh dead after conv2d
#define O_Y1      O_XN     // xn/lowt bf16 planes dead after in/low GEMMs
#define O_DTS     O_DBCH   // dbcH dead after gates_kernel

__device__ __forceinline__ ushort_t f2bf(float v) {
    unsigned u = __float_as_uint(v);
    return (ushort_t)((u + 0x7FFFu + ((u >> 16) & 1u)) >> 16);
}
__device__ __forceinline__ float bf2f(ushort_t h) {
    return __uint_as_float(((unsigned)h) << 16);
}

// ---- chunk-transposed ("perm") layout within each 4096-element row ----------
__device__ __forceinline__ int permidx(int l) {
    return ((l >> 2) & 3) * 1024 + ((l >> 4) << 2) + (l & 3);
}

#define LD16P(dst, row, t4) { \
  float4 _a = *(const float4*)((row) + (t4)); \
  float4 _b = *(const float4*)((row) + 1024 + (t4)); \
  float4 _c = *(const float4*)((row) + 2048 + (t4)); \
  float4 _d = *(const float4*)((row) + 3072 + (t4)); \
  dst[0]=_a.x; dst[1]=_a.y; dst[2]=_a.z; dst[3]=_a.w; \
  dst[4]=_b.x; dst[5]=_b.y; dst[6]=_b.z; dst[7]=_b.w; \
  dst[8]=_c.x; dst[9]=_c.y; dst[10]=_c.z; dst[11]=_c.w; \
  dst[12]=_d.x; dst[13]=_d.y; dst[14]=_d.z; dst[15]=_d.w; }

// -------- merged weight prep: hi/lo splits + padded x_proj weights ------------
__global__ void wprep_kernel(const float* __restrict__ i0, ushort_t* h0, ushort_t* l0_,
                             const float* __restrict__ i1, ushort_t* h1, ushort_t* l1,
                             const float* __restrict__ i2, ushort_t* h2, ushort_t* l2,
                             const float* __restrict__ p0, ushort_t* ph0, ushort_t* pl0,
                             const float* __restrict__ p1, ushort_t* ph1, ushort_t* pl1)
{
    int bx = blockIdx.x;
    if (bx < 288) {
        const float* in; ushort_t* oh; ushort_t* ol; int base;
        if (bx < 144)      { in = i0; oh = h0; ol = l0_; base = bx * 1024; }
        else if (bx < 216) { in = i1; oh = h1; ol = l1;  base = (bx-144) * 1024; }
        else               { in = i2; oh = h2; ol = l2;  base = (bx-216) * 1024; }
        int i = base + threadIdx.x * 4;
        float4 v = *(const float4*)&in[i];
        ushort4v h, l;
        h.x = f2bf(v.x); l.x = f2bf(v.x - bf2f(h.x));
        h.y = f2bf(v.y); l.y = f2bf(v.y - bf2f(h.y));
        h.z = f2bf(v.z); l.z = f2bf(v.z - bf2f(h.z));
        h.w = f2bf(v.w); l.w = f2bf(v.w - bf2f(h.w));
        *(ushort4v*)&oh[i] = h;
        *(ushort4v*)&ol[i] = l;
    } else {
        int bb = bx - 288;
        int sel = bb / 24, bxx = bb % 24;
        const float* in = sel ? p1 : p0;
        ushort_t* oh = sel ? ph1 : ph0;
        ushort_t* ol = sel ? pl1 : pl0;
        int idx = (bxx * 256 + threadIdx.x) * 4;
        int n = idx / 384;
        float4 v = (n < NCH) ? *(const float4*)&in[idx] : make_float4(0.f,0.f,0.f,0.f);
        ushort4v h, l;
        h.x = f2bf(v.x); l.x = f2bf(v.x - bf2f(h.x));
        h.y = f2bf(v.y); l.y = f2bf(v.y - bf2f(h.y));
        h.z = f2bf(v.z); l.z = f2bf(v.z - bf2f(h.z));
        h.w = f2bf(v.w); l.w = f2bf(v.w - bf2f(h.w));
        *(ushort4v*)&oh[idx] = h;
        *(ushort4v*)&ol[idx] = l;
    }
}

// -------- merged activation prep: LN(192)+split (x) and plain split (low) -----
__global__ __launch_bounds__(256) void actprep_kernel(const float* __restrict__ X,
    const float* __restrict__ gw, const float* __restrict__ bw,
    ushort_t* __restrict__ oh, ushort_t* __restrict__ ol,
    const float* __restrict__ LOW, ushort_t* __restrict__ lh, ushort_t* __restrict__ llo)
{
    __shared__ float xt[64][193];
    __shared__ float reds[64][4], redq[64][4];
    __shared__ float mu_s[64], rs_s[64];
    int tid = threadIdx.x;
    if (blockIdx.x >= 256) {
        int i = ((blockIdx.x - 256) * 256 + tid) * 4;
        float4 v = *(const float4*)&LOW[i];
        ushort4v h, l;
        h.x = f2bf(v.x); l.x = f2bf(v.x - bf2f(h.x));
        h.y = f2bf(v.y); l.y = f2bf(v.y - bf2f(h.y));
        h.z = f2bf(v.z); l.z = f2bf(v.z - bf2f(h.z));
        h.w = f2bf(v.w); l.w = f2bf(v.w - bf2f(h.w));
        *(ushort4v*)&lh[i] = h;
        *(ushort4v*)&llo[i] = l;
        return;
    }
    int t0 = blockIdx.x * 64;
    const float* Xb = X + (size_t)t0 * CM;
#pragma unroll
    for (int i = 0; i < 12; i++) {
        int f4 = tid + 256 * i;
        float4 v = *(const float4*)&Xb[f4 * 4];
        int row = f4 / 48, c = (f4 % 48) * 4;
        xt[row][c] = v.x; xt[row][c+1] = v.y; xt[row][c+2] = v.z; xt[row][c+3] = v.w;
    }
    __syncthreads();
    int tok = tid & 63, p = tid >> 6;
    float s = 0.f, q = 0.f;
#pragma unroll 8
    for (int i = 0; i < 48; i++) { float v = xt[tok][p*48+i]; s += v; q = fmaf(v, v, q); }
    reds[tok][p] = s; redq[tok][p] = q;
    __syncthreads();
    if (tid < 64) {
        float ss = reds[tid][0]+reds[tid][1]+reds[tid][2]+reds[tid][3];
        float qq = redq[tid][0]+redq[tid][1]+redq[tid][2]+redq[tid][3];
        float mu = ss * (1.f/CM);
        float var = qq * (1.f/CM) - mu*mu;
        mu_s[tid] = mu; rs_s[tid] = rsqrtf(var + 1e-5f);
    }
    __syncthreads();
    int tok2 = tid >> 2, c0 = (tid & 3) * 48;
    float mu = mu_s[tok2], rs = rs_s[tok2];
    size_t tb = (size_t)(t0 + tok2) * CM;
#pragma unroll 8
    for (int i = 0; i < 48; i++) {
        int c = c0 + i;
        float v = (xt[tok2][c] - mu) * rs * gw[c] + bw[c];
        ushort_t h = f2bf(v);
        oh[tb + c] = h;
        ol[tb + c] = f2bf(v - bf2f(h));
    }
}

// -------- split-bf16 MFMA GEMM, token-major bf16 A planes ---------------------
template<int MODE, int SPLIT, int KDIM>
__global__ __launch_bounds__(256) void gemm_mfma(
    const ushort_t* __restrict__ Ahi, const ushort_t* __restrict__ Alo,
    const ushort_t* __restrict__ Whi, const ushort_t* __restrict__ Wlo,
    float* __restrict__ out0, float* __restrict__ out1)
{
    __shared__ __align__(16) char smem[33280];
    ushort_t* sAh = (ushort_t*)smem;        // [4][128][8]
    ushort_t* sAl = sAh + 4096;
    ushort_t* sWh = sAh + 8192;             // [4][64][8]
    ushort_t* sWl = sAh + 10240;
    int tid = threadIdx.x;
    int t0 = blockIdx.x * 128;
    int b = t0 >> 12, l0 = t0 & 4095;
    int n0 = blockIdx.y * 64;
    int arow = tid >> 1, kgA = (tid & 1) * 2;
    int wrow = tid >> 2, kgW = tid & 3;
    const ushort_t* gAh = Ahi + (size_t)(t0 + arow) * KDIM + kgA * 8;
    const ushort_t* gAl = Alo + (size_t)(t0 + arow) * KDIM + kgA * 8;
    const ushort_t* gWh = Whi + (size_t)(n0 + wrow) * KDIM + kgW * 8;
    const ushort_t* gWl = Wlo + (size_t)(n0 + wrow) * KDIM + kgW * 8;
    int lane = tid & 63, w = tid >> 6;
    int ln = lane & 15, kg = lane >> 4;
    int am0 = w * 32 + ln;
    f32x4 acc[2][4];
#pragma unroll
    for (int mf = 0; mf < 2; mf++)
#pragma unroll
        for (int nf = 0; nf < 4; nf++) acc[mf][nf] = (f32x4){0.f, 0.f, 0.f, 0.f};

    for (int k0 = 0; k0 < KDIM; k0 += 32) {
        __syncthreads();
        {
            ushort8 a0 = *(const ushort8*)(gAh + k0);
            ushort8 a1 = *(const ushort8*)(gAh + k0 + 8);
            *(ushort8*)(sAh + kgA*1024 + arow*8) = a0;
            *(ushort8*)(sAh + (kgA+1)*1024 + arow*8) = a1;
            ushort8 w0 = *(const ushort8*)(gWh + k0);
            *(ushort8*)(sWh + kgW*512 + wrow*8) = w0;
            if (SPLIT == 3) {
                ushort8 b0 = *(const ushort8*)(gAl + k0);
                ushort8 b1 = *(const ushort8*)(gAl + k0 + 8);
                *(ushort8*)(sAl + kgA*1024 + arow*8) = b0;
                *(ushort8*)(sAl + (kgA+1)*1024 + arow*8) = b1;
                ushort8 w1 = *(const ushort8*)(gWl + k0);
                *(ushort8*)(sWl + kgW*512 + wrow*8) = w1;
            }
        }
        __syncthreads();
        bf16x8 aH[2], bH[4];
#pragma unroll
        for (int mf = 0; mf < 2; mf++)
            aH[mf] = *(const bf16x8*)(sAh + kg*1024 + (am0 + mf*16)*8);
#pragma unroll
        for (int nf = 0; nf < 4; nf++)
            bH[nf] = *(const bf16x8*)(sWh + kg*512 + (nf*16 + ln)*8);
#pragma unroll
        for (int mf = 0; mf < 2; mf++)
#pragma unroll
            for (int nf = 0; nf < 4; nf++)
                acc[mf][nf] = __builtin_amdgcn_mfma_f32_16x16x32_bf16(aH[mf], bH[nf], acc[mf][nf], 0, 0, 0);
        if (SPLIT == 3) {
            bf16x8 aL[2], bL[4];
#pragma unroll
            for (int mf = 0; mf < 2; mf++)
                aL[mf] = *(const bf16x8*)(sAl + kg*1024 + (am0 + mf*16)*8);
#pragma unroll
            for (int nf = 0; nf < 4; nf++)
                bL[nf] = *(const bf16x8*)(sWl + kg*512 + (nf*16 + ln)*8);
#pragma unroll
            for (int mf = 0; mf < 2; mf++)
#pragma unroll
                for (int nf = 0; nf < 4; nf++) {
                    acc[mf][nf] = __builtin_amdgcn_mfma_f32_16x16x32_bf16(aH[mf], bL[nf], acc[mf][nf], 0, 0, 0);
                    acc[mf][nf] = __builtin_amdgcn_mfma_f32_16x16x32_bf16(aL[mf], bH[nf], acc[mf][nf], 0, 0, 0);
                }
        }
    }
    __syncthreads();
    float* st = (float*)smem;   // [64][130]
#pragma unroll
    for (int mf = 0; mf < 2; mf++)
#pragma unroll
        for (int nf = 0; nf < 4; nf++)
#pragma unroll
            for (int j = 0; j < 4; j++) {
                int ml = w*32 + mf*16 + (lane>>4)*4 + j;
                int nl = nf*16 + ln;
                st[nl*130 + ml] = acc[mf][nf][j];
            }
    __syncthreads();
    int nl = tid >> 2, mq = (tid & 3) * 32;
    int n = n0 + nl;
    float* dst;
    if (MODE == 0) {
        dst = (n < DI) ? (out0 + ((size_t)b*DI + n)*LL + l0 + mq)
                       : (out1 + ((size_t)b*DI + (n - DI))*LL + l0 + mq);
    } else {
        dst = out0 + ((size_t)b*DI + n)*LL + l0 + mq;
    }
#pragma unroll
    for (int i = 0; i < 8; i++)
        *(float4*)(dst + i*4) = *(const float4*)&st[nl*130 + mq + i*4];
}

// -------- channel-major-A MFMA GEMM (fp32 A staged + on-the-fly bf16 split) ---
template<int MODE, int SPLIT, int PERM0>
__global__ __launch_bounds__(256) void gemm_cmaj(
    const float* __restrict__ A0, const float* __restrict__ A1,
    const ushort_t* __restrict__ W0h, const ushort_t* __restrict__ W0l,
    const ushort_t* __restrict__ W1h, const ushort_t* __restrict__ W1l,
    const float* __restrict__ resid,
    float* __restrict__ o0, float* __restrict__ o1, int Nreal)
{
    __shared__ __align__(16) char smem[33280];
    float* sA = (float*)smem;                       // [32][132]
    ushort_t* sWh = (ushort_t*)(smem + 16896);      // [4][64][8]
    ushort_t* sWl = (ushort_t*)(smem + 20992);
    bool sel = (blockIdx.z == 1);
    const float* A = sel ? A1 : A0;
    const ushort_t* Wh = sel ? W1h : W0h;
    const ushort_t* Wl = sel ? W1l : W0l;
    float* out0 = sel ? o1 : o0;
    const bool perm = sel ? false : (PERM0 != 0);
    int tid = threadIdx.x;
    int t0 = blockIdx.x * 128;
    int b = t0 >> 12, l0 = t0 & 4095;
    int n0 = blockIdx.y * 64;
    const float* Ab = A + (size_t)b * 384 * LL;
    int srow = tid >> 3, sc8 = tid & 7;
    int wrow = tid >> 2, kgW = tid & 3;
    int lane = tid & 63, w = tid >> 6;
    int ln = lane & 15, kg = lane >> 4;
    int am0 = w * 32 + ln;
    f32x4 acc[2][4];
#pragma unroll
    for (int mf = 0; mf < 2; mf++)
#pragma unroll
        for (int nf = 0; nf < 4; nf++) acc[mf][nf] = (f32x4){0.f, 0.f, 0.f, 0.f};

    for (int k0 = 0; k0 < 384; k0 += 32) {
        __syncthreads();
#pragma unroll
        for (int i = 0; i < 4; i++) {
            int m = (sc8 + 8*i) * 4;
            int src = perm ? ((((m >> 2) & 3) * 1024) + (((l0 + m) >> 4) << 2))
                           : (l0 + m);
            float4 v = *(const float4*)&Ab[(size_t)(k0 + srow)*LL + src];
            *(float4*)&sA[srow*132 + m] = v;
        }
        {
            ushort8 wv = *(const ushort8*)(Wh + (size_t)(n0 + wrow)*384 + k0 + kgW*8);
            *(ushort8*)(sWh + kgW*512 + wrow*8) = wv;
            if (SPLIT == 3) {
                ushort8 wl = *(const ushort8*)(Wl + (size_t)(n0 + wrow)*384 + k0 + kgW*8);
                *(ushort8*)(sWl + kgW*512 + wrow*8) = wl;
            }
        }
        __syncthreads();
        bf16x8 aH[2], aL[2];
#pragma unroll
        for (int mf = 0; mf < 2; mf++) {
            int am = am0 + mf*16;
#pragma unroll
            for (int e = 0; e < 8; e++) {
                float v = sA[(kg*8 + e)*132 + am];
                ushort_t h = f2bf(v);
                aH[mf][e] = (short)h;
                if (SPLIT == 3) aL[mf][e] = (short)f2bf(v - bf2f(h));
            }
        }
        bf16x8 bH[4], bL[4];
#pragma unroll
        for (int nf = 0; nf < 4; nf++) {
            bH[nf] = *(const bf16x8*)(sWh + kg*512 + (nf*16 + ln)*8);
            if (SPLIT == 3) bL[nf] = *(const bf16x8*)(sWl + kg*512 + (nf*16 + ln)*8);
        }
#pragma unroll
        for (int mf = 0; mf < 2; mf++)
#pragma unroll
            for (int nf = 0; nf < 4; nf++) {
                acc[mf][nf] = __builtin_amdgcn_mfma_f32_16x16x32_bf16(aH[mf], bH[nf], acc[mf][nf], 0, 0, 0);
                if (SPLIT == 3) {
                    acc[mf][nf] = __builtin_amdgcn_mfma_f32_16x16x32_bf16(aH[mf], bL[nf], acc[mf][nf], 0, 0, 0);
                    acc[mf][nf] = __builtin_amdgcn_mfma_f32_16x16x32_bf16(aL[mf], bH[nf], acc[mf][nf], 0, 0, 0);
                }
            }
    }

    if (MODE == 2) {
#pragma unroll
        for (int mf = 0; mf < 2; mf++)
#pragma unroll
            for (int j = 0; j < 4; j++) {
                int t = t0 + w*32 + mf*16 + (lane>>4)*4 + j;
#pragma unroll
                for (int nf = 0; nf < 4; nf++) {
                    int n = n0 + nf*16 + ln;
                    out0[(size_t)t*CM + n] = resid[(size_t)t*CM + n] + acc[mf][nf][j];
                }
            }
    } else {
        __syncthreads();
        float* st = (float*)smem;   // [64][130]
#pragma unroll
        for (int mf = 0; mf < 2; mf++)
#pragma unroll
            for (int nf = 0; nf < 4; nf++)
#pragma unroll
                for (int j = 0; j < 4; j++) {
                    int ml = w*32 + mf*16 + (lane>>4)*4 + j;
                    int nl = nf*16 + ln;
                    st[nl*130 + ml] = acc[mf][nf][j];
                }
        __syncthreads();
        int nl = tid >> 2, mq = (tid & 3) * 32;
        int n = n0 + nl;
        if (n < Nreal) {
            float* dst = out0 + ((size_t)b*Nreal + n)*LL + l0 + mq;
#pragma unroll
            for (int i = 0; i < 8; i++)
                *(float4*)(dst + i*4) = *(const float4*)&st[nl*130 + mq + i*4];
        }
    }
}

// -------- depthwise 3x3 conv + bias + SiLU -> xs in PERM layout ---------------
__global__ __launch_bounds__(256) void conv2d_silu_kernel(const float* __restrict__ xh,
    const float* __restrict__ w, const float* __restrict__ bias, float* __restrict__ xs)
{
    int tid = threadIdx.x;
    int l = blockIdx.x * 256 + tid;
    int c = blockIdx.y, b = blockIdx.z;
    const float* P = xh + ((size_t)b*DI + c)*LL;
    int h = l >> 6, ww = l & 63;
    float acc = bias[c];
#pragma unroll
    for (int kh = 0; kh < 3; kh++) {
        int hh = h + kh - 1;
        if ((unsigned)hh < 64u) {
#pragma unroll
            for (int kw = 0; kw < 3; kw++) {
                int wv = ww + kw - 1;
                if ((unsigned)wv < 64u) acc = fmaf(w[c*9 + kh*3 + kw], P[hh*64 + wv], acc);
            }
        }
    }
    float sg = 1.f / (1.f + __expf(-acc));
    xs[((size_t)b*DI + c)*LL + permidx(l)] = acc * sg;
}

// -------- SimpleGates on low B/C + sum high+low -> dbc [B][44][L] -------------
__global__ __launch_bounds__(256) void gates_kernel(const float* __restrict__ dbcH,
    const float* __restrict__ dbcL,
    const float* __restrict__ sgb1, const float* __restrict__ sgb2,
    const float* __restrict__ sgc1, const float* __restrict__ sgc2,
    float* __restrict__ dbc)
{
    __shared__ float w1[2][192*16];
    __shared__ float w2[2][16*96];
    __shared__ float red[4][16][64];
    int tid = threadIdx.x;
    for (int i = tid; i < 192*16; i += 256) { w1[0][i] = sgb1[i]; w1[1][i] = sgc1[i]; }
    for (int i = tid; i < 16*96;  i += 256) { w2[0][i] = sgb2[i]; w2[1][i] = sgc2[i]; }
    int lq = tid & 63, p = tid >> 6;
    int l = blockIdx.x * 64 + lq;
    int b = blockIdx.y;
    size_t pb_ = (size_t)b*NCH*LL + l;
    __syncthreads();
#pragma unroll
    for (int i = 0; i < 3; i++) {
        int c = p*3 + i;
        dbc[pb_ + (size_t)c*LL] = dbcH[pb_ + (size_t)c*LL] + dbcL[pb_ + (size_t)c*LL];
    }
    for (int gate = 0; gate < 2; gate++) {
        int coff = RK + gate*NST;
        float xin[16], og[16];
#pragma unroll
        for (int n = 0; n < 16; n++) { xin[n] = dbcL[pb_ + (size_t)(coff+n)*LL]; og[n] = 0.f; }
        int h0 = p * 24;
        for (int h = h0; h < h0 + 24; h++) {
            float ya = 0.f, yb = 0.f;
#pragma unroll
            for (int n = 0; n < 16; n++) {
                ya = fmaf(w1[gate][h*16+n], xin[n], ya);
                yb = fmaf(w1[gate][(h+SGH)*16+n], xin[n], yb);
            }
            float gg = 0.5f * ya * (1.f + erff(ya * 0.70710678f)) * yb;
#pragma unroll
            for (int n = 0; n < 16; n++) og[n] = fmaf(w2[gate][n*SGH+h], gg, og[n]);
        }
#pragma unroll
        for (int n = 0; n < 16; n++) red[p][n][lq] = og[n];
        __syncthreads();
#pragma unroll
        for (int i = 0; i < 4; i++) {
            int n = p*4 + i;
            float v = red[0][n][lq] + red[1][n][lq] + red[2][n][lq] + red[3][n][lq];
            dbc[pb_ + (size_t)(coff+n)*LL] = dbcH[pb_ + (size_t)(coff+n)*LL] + v;
        }
        __syncthreads();
    }
}

// -------- residual dilated dwconv1d: dts normal; Bs/Cs in PERM layout ---------
__global__ __launch_bounds__(256) void conv_dbc_kernel(const float* __restrict__ dbc,
    const float* __restrict__ wdt, const float* __restrict__ wB, const float* __restrict__ wC,
    float* __restrict__ dts, float* __restrict__ Bs, float* __restrict__ Cs)
{
    int l = blockIdx.x * 256 + threadIdx.x;
    int c = blockIdx.y, b = blockIdx.z;
    const float* wsrc = (c < RK) ? (wdt + c*15)
                      : (c < RK+NST ? wB + (c-RK)*15 : wC + (c-RK-NST)*15);
    float w[15];
#pragma unroll
    for (int k = 0; k < 15; k++) w[k] = wsrc[k];
    const float* P = dbc + ((size_t)b*NCH + c)*LL;
    float a = P[l];
#pragma unroll
    for (int k = 0; k < 15; k++) {
        int lt = l + 2*k - 14;
        if ((unsigned)lt < (unsigned)LL) a = fmaf(w[k], P[lt], a);
    }
    if (c < RK)            dts[((size_t)b*RK  + c)*LL + l] = a;
    else if (c < RK+NST)   Bs [((size_t)b*NST + (c-RK))*LL + permidx(l)] = a;
    else                   Cs [((size_t)b*NST + (c-RK-NST))*LL + permidx(l)] = a;
}

// -------- delta projection + softplus -> delta in PERM layout -----------------
__global__ __launch_bounds__(256) void delta_kernel(const float* __restrict__ dts,
    const float* __restrict__ dtw, const float* __restrict__ dtb, float* __restrict__ delta)
{
    __shared__ float sdt[RK][128];
    __shared__ float sw[64][RK];
    int tid = threadIdx.x;
    int l0 = blockIdx.x * 128, d0 = blockIdx.y * 64, b = blockIdx.z;
    for (int i = tid; i < RK*128; i += 256) {
        int r = i >> 7, lq = i & 127;
        sdt[r][lq] = dts[((size_t)b*RK + r)*LL + l0 + lq];
    }
    for (int i = tid; i < 64*RK; i += 256) {
        int dq = i / RK, r = i - dq*RK;
        sw[dq][r] = dtw[(size_t)(d0+dq)*RK + r];
    }
    __syncthreads();
    int lq = tid & 63, g = tid >> 6;
    for (int dd = 0; dd < 16; dd++) {
        int dqq = g*16 + dd, d = d0 + dqq;
        float wr[RK];
#pragma unroll
        for (int r = 0; r < RK; r++) wr[r] = sw[dqq][r];
        float bias = dtb[d];
#pragma unroll
        for (int li = 0; li < 2; li++) {
            int lloc = lq + li*64;
            float s = bias;
#pragma unroll
            for (int r = 0; r < RK; r++) s = fmaf(wr[r], sdt[r][lloc], s);
            float sp = fmaxf(s, 0.f) + log1pf(__expf(-fabsf(s)));
            delta[((size_t)b*DI + d)*LL + permidx(l0 + lloc)] = sp;
        }
    }
}

// -------- selective scan v8: v4 structure + 2-state ILP pairs -----------------
// v4 (best measured, 56.6us): half-split (8 states/block, 3072 blocks), single
// pass with deferred prefix fixup (t[s]=C*a). v8 processes states in PAIRS:
// two independent serial h-chains + two interleaved shuffle scans per iter so
// the ~4cy fma dependency latency of one chain is filled by the other.
// Barriers: 4/block (one per pair; wAs slots distinct across pairs).
__global__ __launch_bounds__(256) void scan_kernel(
    const float* __restrict__ u_, const float* __restrict__ delta_,
    const float* __restrict__ Bs_, const float* __restrict__ Cs_,
    const float* __restrict__ Alogs, const float* __restrict__ Ds,
    float* __restrict__ y0_, float* __restrict__ y1_)
{
    __shared__ float wAs[8][4], wBs[8][4];
    __shared__ float yt[16][258];
    int tid = threadIdx.x;
    int t4 = tid * 4;
    int bid = blockIdx.x;
    int half = bid & 1, bd = bid >> 1;
    int b = bd / DI, d = bd % DI;
    int n0 = half * 8;
    size_t rowoff = ((size_t)b*DI + d)*LL;
    float dl[16], du[16], yac[16];
    LD16P(du, u_ + rowoff, t4);
    LD16P(dl, delta_ + rowoff, t4);
    float Dd = Ds[d];
#pragma unroll
    for (int s = 0; s < 16; s++) {
        yac[s] = half ? 0.f : du[s]*Dd;
        du[s] = dl[s]*du[s];
    }
    int lane = tid & 63, w = tid >> 6;
#pragma unroll 1
    for (int p = 0; p < 4; p++) {
        int j0 = 2*p, j1 = 2*p + 1;
        float An0 = -__expf(Alogs[d*NST + n0 + j0]);
        float An1 = -__expf(Alogs[d*NST + n0 + j1]);
        float B0[16], C0[16], B1[16], C1[16], t0[16], t1[16];
        LD16P(B0, Bs_ + ((size_t)b*NST + n0 + j0)*LL, t4);
        LD16P(C0, Cs_ + ((size_t)b*NST + n0 + j0)*LL, t4);
        LD16P(B1, Bs_ + ((size_t)b*NST + n0 + j1)*LL, t4);
        LD16P(C1, Cs_ + ((size_t)b*NST + n0 + j1)*LL, t4);
        float a0 = 1.f, h0 = 0.f, a1 = 1.f, h1 = 0.f;
#pragma unroll
        for (int s = 0; s < 16; s++) {
            float e0 = __expf(dl[s]*An0);
            float e1 = __expf(dl[s]*An1);
            a0 *= e0; a1 *= e1;
            h0 = fmaf(e0, h0, du[s]*B0[s]);
            h1 = fmaf(e1, h1, du[s]*B1[s]);
            yac[s] = fmaf(C0[s], h0, yac[s]);
            yac[s] = fmaf(C1[s], h1, yac[s]);
            t0[s] = C0[s]*a0;
            t1[s] = C1[s]*a1;
        }
        // dual interleaved wave-level shuffle scans
        float ap0 = a0, hv0 = h0, ap1 = a1, hv1 = h1;
        for (int off = 1; off < 64; off <<= 1) {
            float pa0 = __shfl_up(ap0, (unsigned)off, 64);
            float pb0 = __shfl_up(hv0, (unsigned)off, 64);
            float pa1 = __shfl_up(ap1, (unsigned)off, 64);
            float pb1 = __shfl_up(hv1, (unsigned)off, 64);
            if (lane >= off) {
                hv0 = fmaf(ap0, pb0, hv0); ap0 *= pa0;
                hv1 = fmaf(ap1, pb1, hv1); ap1 *= pa1;
            }
        }
        if (lane == 63) {
            wAs[j0][w] = ap0; wBs[j0][w] = hv0;
            wAs[j1][w] = ap1; wBs[j1][w] = hv1;
        }
        __syncthreads();
        float PB0 = 0.f, PB1 = 0.f;
        for (int ww = 0; ww < w; ww++) {
            PB0 = fmaf(wAs[j0][ww], PB0, wBs[j0][ww]);
            PB1 = fmaf(wAs[j1][ww], PB1, wBs[j1][ww]);
        }
        hv0 = fmaf(ap0, PB0, hv0);
        hv1 = fmaf(ap1, PB1, hv1);
        float q0 = __shfl_up(hv0, 1u, 64);
        float q1 = __shfl_up(hv1, 1u, 64);
        float hin0 = lane ? q0 : PB0;
        float hin1 = lane ? q1 : PB1;
#pragma unroll
        for (int s = 0; s < 16; s++) {
            yac[s] = fmaf(t0[s], hin0, yac[s]);
            yac[s] = fmaf(t1[s], hin1, yac[s]);
        }
    }
#pragma unroll
    for (int i = 0; i < 16; i++) yt[i][tid] = yac[i];
    __syncthreads();
    float* yout = (half ? y1_ : y0_) + rowoff;
#pragma unroll
    for (int r = 0; r < 16; r++)
        yout[r*256 + tid] = yt[tid & 15][r*16 + (tid >> 4)];
}

// -------- out-norm LN(384) on y0+y1 + z-SiLU gating (in-place over y1) --------
__global__ __launch_bounds__(256) void outnorm_gate_kernel(const float* __restrict__ y0,
    float* y1g, const float* __restrict__ z,
    const float* __restrict__ g, const float* __restrict__ bt)
{
    __shared__ float rs_[4][64], rq_[4][64];
    __shared__ float mu_s[64], rstd_s[64];
    int tid = threadIdx.x;
    int lq = tid & 63, p = tid >> 6;
    int l = blockIdx.x * 64 + lq;
    int b = blockIdx.y;
    const float* yp0 = y0 + (size_t)b*DI*LL + l;
    float* yp1 = y1g + (size_t)b*DI*LL + l;
    float s = 0.f, q = 0.f;
#pragma unroll 4
    for (int i = 0; i < 96; i++) {
        int d = p*96 + i;
        float v = yp0[(size_t)d*LL] + yp1[(size_t)d*LL];
        s += v; q = fmaf(v, v, q);
    }
    rs_[p][lq] = s; rq_[p][lq] = q;
    __syncthreads();
    if (p == 0) {
        float ss = rs_[0][lq]+rs_[1][lq]+rs_[2][lq]+rs_[3][lq];
        float qq = rq_[0][lq]+rq_[1][lq]+rq_[2][lq]+rq_[3][lq];
        float mu = ss * (1.f/DI);
        float var = qq * (1.f/DI) - mu*mu;
        mu_s[lq] = mu; rstd_s[lq] = rsqrtf(var + 1e-5f);
    }
    __syncthreads();
    float mu = mu_s[lq], rs = rstd_s[lq];
    const float* zp = z + (size_t)b*DI*LL + l;
#pragma unroll 4
    for (int i = 0; i < 96; i++) {
        int d = p*96 + i;
        float v = ((yp0[(size_t)d*LL] + yp1[(size_t)d*LL]) - mu)*rs*g[d] + bt[d];
        float zv = zp[(size_t)d*LL];
        float sg = 1.f / (1.f + __expf(-zv));
        yp1[(size_t)d*LL] = v * (zv * sg);
    }
}

extern "C" void kernel_launch(void* const* d_in, const int* in_sizes, int n_in,
                              void* d_out, int out_size, void* d_ws, size_t ws_size,
                              hipStream_t stream)
{
    (void)in_sizes; (void)n_in; (void)out_size; (void)ws_size;
    const float* x     = (const float*)d_in[0];
    const float* low   = (const float*)d_in[1];
    const float* ln_g  = (const float*)d_in[2];
    const float* ln_b  = (const float*)d_in[3];
    const float* w_in  = (const float*)d_in[4];
    const float* w_low = (const float*)d_in[5];
    const float* w_c2d = (const float*)d_in[6];
    const float* b_c2d = (const float*)d_in[7];
    const float* w_xp  = (const float*)d_in[8];
    const float* w_xpl = (const float*)d_in[9];
    const float* w_cdt = (const float*)d_in[10];
    const float* w_cB  = (const float*)d_in[11];
    const float* w_cC  = (const float*)d_in[12];
    const float* sgb1  = (const float*)d_in[13];
    const float* sgb2  = (const float*)d_in[14];
    const float* sgc1  = (const float*)d_in[15];
    const float* sgc2  = (const float*)d_in[16];
    const float* dtw   = (const float*)d_in[17];
    const float* dtb   = (const float*)d_in[18];
    const float* Alogs = (const float*)d_in[19];
    const float* Ds    = (const float*)d_in[20];
    const float* ong   = (const float*)d_in[21];
    const float* onb   = (const float*)d_in[22];
    const float* w_out = (const float*)d_in[23];
    float* ws  = (float*)d_ws;
    float* out = (float*)d_out;
    dim3 blk(256);

    // bf16 plane aliases
    ushort_t* wInH  = (ushort_t*)(ws + O_WT_IN);   ushort_t* wInL  = wInH + 147456;
    ushort_t* wLowH = (ushort_t*)(ws + O_WT_LOW);  ushort_t* wLowL = wLowH + 73728;
    ushort_t* wOutH = (ushort_t*)(ws + O_WT_OUT);  ushort_t* wOutL = wOutH + 73728;
    ushort_t* wXpH  = (ushort_t*)(ws + O_WT_XP);   ushort_t* wXpL  = wXpH + 24576;
    ushort_t* wXplH = (ushort_t*)(ws + O_WT_XPL);  ushort_t* wXplL = wXplH + 24576;
    ushort_t* xnh   = (ushort_t*)(ws + O_XN);      ushort_t* xnl   = xnh + 3145728;
    ushort_t* lowh  = (ushort_t*)(ws + O_LOWT);    ushort_t* lowl  = lowh + 3145728;

    wprep_kernel<<<336, blk, 0, stream>>>(w_in, wInH, wInL, w_low, wLowH, wLowL,
                                          w_out, wOutH, wOutL,
                                          w_xp, wXpH, wXpL, w_xpl, wXplH, wXplL);

    actprep_kernel<<<3328, blk, 0, stream>>>(x, ln_g, ln_b, xnh, xnl, low, lowh, lowl);

    gemm_mfma<0,3,192><<<dim3(128,12), blk, 0, stream>>>(xnh, xnl, wInH, wInL,
                                                         ws+O_XH, ws+O_Z);
    gemm_mfma<1,3,192><<<dim3(128,6),  blk, 0, stream>>>(lowh, lowl, wLowH, wLowL,
                                                         ws+O_LOWP, nullptr);

    conv2d_silu_kernel<<<dim3(16,384,4), blk, 0, stream>>>(ws+O_XH, w_c2d, b_c2d, ws+O_XS);

    gemm_cmaj<1,3,1><<<dim3(128,1,2), blk, 0, stream>>>(ws+O_XS, ws+O_LOWP,
                                                        wXpH, wXpL, wXplH, wXplL,
                                                        nullptr, ws+O_DBCH, ws+O_DBCL, NCH);

    gates_kernel<<<dim3(64,4), blk, 0, stream>>>(ws+O_DBCH, ws+O_DBCL, sgb1, sgb2, sgc1, sgc2, ws+O_DBC);

    conv_dbc_kernel<<<dim3(16,44,4), blk, 0, stream>>>(ws+O_DBC, w_cdt, w_cB, w_cC,
                                                       ws+O_DTS, ws+O_BS, ws+O_CS);
    delta_kernel<<<dim3(32,6,4), blk, 0, stream>>>(ws+O_DTS, dtw, dtb, ws+O_DELTA);

    scan_kernel<<<3072, blk, 0, stream>>>(ws+O_XS, ws+O_DELTA, ws+O_BS, ws+O_CS, Alogs, Ds,
                                          ws+O_Y, ws+O_Y1);

    outnorm_gate_kernel<<<dim3(64,4), blk, 0, stream>>>(ws+O_Y, ws+O_Y1, ws+O_Z, ong, onb);

    gemm_cmaj<2,1,0><<<dim3(128,3,1), blk, 0, stream>>>(ws+O_Y1, nullptr,
                                                        wOutH, wOutL, nullptr, nullptr,
                                                        x, out, nullptr, CM);
}

// Round 11
// 279.698 us; speedup vs baseline: 1.1771x; 1.1375x over previous
//
#include <hip/hip_runtime.h>
#include <math.h>

#define LL 4096
#define NBATCH 4
#define CM 192
#define DI 384
#define NST 16
#define RK 12
#define NCH 44
#define SGH 96

typedef unsigned short ushort_t;
typedef __attribute__((ext_vector_type(8))) short bf16x8;
typedef __attribute__((ext_vector_type(4))) float f32x4;
typedef __attribute__((ext_vector_type(8))) unsigned short ushort8;
typedef __attribute__((ext_vector_type(4))) unsigned short ushort4v;

// workspace offsets (float units)
#define O_WT_IN   0
#define O_WT_LOW  147456
#define O_WT_XP   221184
#define O_WT_XPL  245760
#define O_WT_OUT  270336
#define O_XN      344064
#define O_LOWT    3489792
#define O_XH      6635520
#define O_Z       12926976
#define O_LOWP    19218432
#define O_XS      25509888
#define O_DBCH    31801344
#define O_DBCL    32522240
#define O_DBC     33243136
#define O_BS      33964032
#define O_CS      34226176
#define O_DELTA   O_LOWP   // lowp dead after x_proj GEMMs
#define O_Y       O_XH     // xh dead after conv2d
#define O_Y1      O_XN     // xn/lowt bf16 planes dead after in/low GEMMs
#define O_DTS     O_DBCH   // dbcH dead after gates_kernel

__device__ __forceinline__ ushort_t f2bf(float v) {
    unsigned u = __float_as_uint(v);
    return (ushort_t)((u + 0x7FFFu + ((u >> 16) & 1u)) >> 16);
}
__device__ __forceinline__ float bf2f(ushort_t h) {
    return __uint_as_float(((unsigned)h) << 16);
}

// ---- chunk-transposed ("perm") layout within each 4096-element row ----------
__device__ __forceinline__ int permidx(int l) {
    return ((l >> 2) & 3) * 1024 + ((l >> 4) << 2) + (l & 3);
}

#define LD16P(dst, row, t4) { \
  float4 _a = *(const float4*)((row) + (t4)); \
  float4 _b = *(const float4*)((row) + 1024 + (t4)); \
  float4 _c = *(const float4*)((row) + 2048 + (t4)); \
  float4 _d = *(const float4*)((row) + 3072 + (t4)); \
  dst[0]=_a.x; dst[1]=_a.y; dst[2]=_a.z; dst[3]=_a.w; \
  dst[4]=_b.x; dst[5]=_b.y; dst[6]=_b.z; dst[7]=_b.w; \
  dst[8]=_c.x; dst[9]=_c.y; dst[10]=_c.z; dst[11]=_c.w; \
  dst[12]=_d.x; dst[13]=_d.y; dst[14]=_d.z; dst[15]=_d.w; }

// -------- merged weight prep: hi/lo splits + padded x_proj weights ------------
__global__ void wprep_kernel(const float* __restrict__ i0, ushort_t* h0, ushort_t* l0_,
                             const float* __restrict__ i1, ushort_t* h1, ushort_t* l1,
                             const float* __restrict__ i2, ushort_t* h2, ushort_t* l2,
                             const float* __restrict__ p0, ushort_t* ph0, ushort_t* pl0,
                             const float* __restrict__ p1, ushort_t* ph1, ushort_t* pl1)
{
    int bx = blockIdx.x;
    if (bx < 288) {
        const float* in; ushort_t* oh; ushort_t* ol; int base;
        if (bx < 144)      { in = i0; oh = h0; ol = l0_; base = bx * 1024; }
        else if (bx < 216) { in = i1; oh = h1; ol = l1;  base = (bx-144) * 1024; }
        else               { in = i2; oh = h2; ol = l2;  base = (bx-216) * 1024; }
        int i = base + threadIdx.x * 4;
        float4 v = *(const float4*)&in[i];
        ushort4v h, l;
        h.x = f2bf(v.x); l.x = f2bf(v.x - bf2f(h.x));
        h.y = f2bf(v.y); l.y = f2bf(v.y - bf2f(h.y));
        h.z = f2bf(v.z); l.z = f2bf(v.z - bf2f(h.z));
        h.w = f2bf(v.w); l.w = f2bf(v.w - bf2f(h.w));
        *(ushort4v*)&oh[i] = h;
        *(ushort4v*)&ol[i] = l;
    } else {
        int bb = bx - 288;
        int sel = bb / 24, bxx = bb % 24;
        const float* in = sel ? p1 : p0;
        ushort_t* oh = sel ? ph1 : ph0;
        ushort_t* ol = sel ? pl1 : pl0;
        int idx = (bxx * 256 + threadIdx.x) * 4;
        int n = idx / 384;
        float4 v = (n < NCH) ? *(const float4*)&in[idx] : make_float4(0.f,0.f,0.f,0.f);
        ushort4v h, l;
        h.x = f2bf(v.x); l.x = f2bf(v.x - bf2f(h.x));
        h.y = f2bf(v.y); l.y = f2bf(v.y - bf2f(h.y));
        h.z = f2bf(v.z); l.z = f2bf(v.z - bf2f(h.z));
        h.w = f2bf(v.w); l.w = f2bf(v.w - bf2f(h.w));
        *(ushort4v*)&oh[idx] = h;
        *(ushort4v*)&ol[idx] = l;
    }
}

// -------- merged activation prep: LN(192)+split (x) and plain split (low) -----
__global__ __launch_bounds__(256) void actprep_kernel(const float* __restrict__ X,
    const float* __restrict__ gw, const float* __restrict__ bw,
    ushort_t* __restrict__ oh, ushort_t* __restrict__ ol,
    const float* __restrict__ LOW, ushort_t* __restrict__ lh, ushort_t* __restrict__ llo)
{
    __shared__ float xt[64][193];
    __shared__ float reds[64][4], redq[64][4];
    __shared__ float mu_s[64], rs_s[64];
    int tid = threadIdx.x;
    if (blockIdx.x >= 256) {
        int i = ((blockIdx.x - 256) * 256 + tid) * 4;
        float4 v = *(const float4*)&LOW[i];
        ushort4v h, l;
        h.x = f2bf(v.x); l.x = f2bf(v.x - bf2f(h.x));
        h.y = f2bf(v.y); l.y = f2bf(v.y - bf2f(h.y));
        h.z = f2bf(v.z); l.z = f2bf(v.z - bf2f(h.z));
        h.w = f2bf(v.w); l.w = f2bf(v.w - bf2f(h.w));
        *(ushort4v*)&lh[i] = h;
        *(ushort4v*)&llo[i] = l;
        return;
    }
    int t0 = blockIdx.x * 64;
    const float* Xb = X + (size_t)t0 * CM;
#pragma unroll
    for (int i = 0; i < 12; i++) {
        int f4 = tid + 256 * i;
        float4 v = *(const float4*)&Xb[f4 * 4];
        int row = f4 / 48, c = (f4 % 48) * 4;
        xt[row][c] = v.x; xt[row][c+1] = v.y; xt[row][c+2] = v.z; xt[row][c+3] = v.w;
    }
    __syncthreads();
    int tok = tid & 63, p = tid >> 6;
    float s = 0.f, q = 0.f;
#pragma unroll 8
    for (int i = 0; i < 48; i++) { float v = xt[tok][p*48+i]; s += v; q = fmaf(v, v, q); }
    reds[tok][p] = s; redq[tok][p] = q;
    __syncthreads();
    if (tid < 64) {
        float ss = reds[tid][0]+reds[tid][1]+reds[tid][2]+reds[tid][3];
        float qq = redq[tid][0]+redq[tid][1]+redq[tid][2]+redq[tid][3];
        float mu = ss * (1.f/CM);
        float var = qq * (1.f/CM) - mu*mu;
        mu_s[tid] = mu; rs_s[tid] = rsqrtf(var + 1e-5f);
    }
    __syncthreads();
    int tok2 = tid >> 2, c0 = (tid & 3) * 48;
    float mu = mu_s[tok2], rs = rs_s[tok2];
    size_t tb = (size_t)(t0 + tok2) * CM;
#pragma unroll 8
    for (int i = 0; i < 48; i++) {
        int c = c0 + i;
        float v = (xt[tok2][c] - mu) * rs * gw[c] + bw[c];
        ushort_t h = f2bf(v);
        oh[tb + c] = h;
        ol[tb + c] = f2bf(v - bf2f(h));
    }
}

// -------- split-bf16 MFMA GEMM, token-major bf16 A planes ---------------------
template<int MODE, int SPLIT, int KDIM>
__global__ __launch_bounds__(256) void gemm_mfma(
    const ushort_t* __restrict__ Ahi, const ushort_t* __restrict__ Alo,
    const ushort_t* __restrict__ Whi, const ushort_t* __restrict__ Wlo,
    float* __restrict__ out0, float* __restrict__ out1)
{
    __shared__ __align__(16) char smem[33280];
    ushort_t* sAh = (ushort_t*)smem;        // [4][128][8]
    ushort_t* sAl = sAh + 4096;
    ushort_t* sWh = sAh + 8192;             // [4][64][8]
    ushort_t* sWl = sAh + 10240;
    int tid = threadIdx.x;
    int t0 = blockIdx.x * 128;
    int b = t0 >> 12, l0 = t0 & 4095;
    int n0 = blockIdx.y * 64;
    int arow = tid >> 1, kgA = (tid & 1) * 2;
    int wrow = tid >> 2, kgW = tid & 3;
    const ushort_t* gAh = Ahi + (size_t)(t0 + arow) * KDIM + kgA * 8;
    const ushort_t* gAl = Alo + (size_t)(t0 + arow) * KDIM + kgA * 8;
    const ushort_t* gWh = Whi + (size_t)(n0 + wrow) * KDIM + kgW * 8;
    const ushort_t* gWl = Wlo + (size_t)(n0 + wrow) * KDIM + kgW * 8;
    int lane = tid & 63, w = tid >> 6;
    int ln = lane & 15, kg = lane >> 4;
    int am0 = w * 32 + ln;
    f32x4 acc[2][4];
#pragma unroll
    for (int mf = 0; mf < 2; mf++)
#pragma unroll
        for (int nf = 0; nf < 4; nf++) acc[mf][nf] = (f32x4){0.f, 0.f, 0.f, 0.f};

    for (int k0 = 0; k0 < KDIM; k0 += 32) {
        __syncthreads();
        {
            ushort8 a0 = *(const ushort8*)(gAh + k0);
            ushort8 a1 = *(const ushort8*)(gAh + k0 + 8);
            *(ushort8*)(sAh + kgA*1024 + arow*8) = a0;
            *(ushort8*)(sAh + (kgA+1)*1024 + arow*8) = a1;
            ushort8 w0 = *(const ushort8*)(gWh + k0);
            *(ushort8*)(sWh + kgW*512 + wrow*8) = w0;
            if (SPLIT == 3) {
                ushort8 b0 = *(const ushort8*)(gAl + k0);
                ushort8 b1 = *(const ushort8*)(gAl + k0 + 8);
                *(ushort8*)(sAl + kgA*1024 + arow*8) = b0;
                *(ushort8*)(sAl + (kgA+1)*1024 + arow*8) = b1;
                ushort8 w1 = *(const ushort8*)(gWl + k0);
                *(ushort8*)(sWl + kgW*512 + wrow*8) = w1;
            }
        }
        __syncthreads();
        bf16x8 aH[2], bH[4];
#pragma unroll
        for (int mf = 0; mf < 2; mf++)
            aH[mf] = *(const bf16x8*)(sAh + kg*1024 + (am0 + mf*16)*8);
#pragma unroll
        for (int nf = 0; nf < 4; nf++)
            bH[nf] = *(const bf16x8*)(sWh + kg*512 + (nf*16 + ln)*8);
#pragma unroll
        for (int mf = 0; mf < 2; mf++)
#pragma unroll
            for (int nf = 0; nf < 4; nf++)
                acc[mf][nf] = __builtin_amdgcn_mfma_f32_16x16x32_bf16(aH[mf], bH[nf], acc[mf][nf], 0, 0, 0);
        if (SPLIT == 3) {
            bf16x8 aL[2], bL[4];
#pragma unroll
            for (int mf = 0; mf < 2; mf++)
                aL[mf] = *(const bf16x8*)(sAl + kg*1024 + (am0 + mf*16)*8);
#pragma unroll
            for (int nf = 0; nf < 4; nf++)
                bL[nf] = *(const bf16x8*)(sWl + kg*512 + (nf*16 + ln)*8);
#pragma unroll
            for (int mf = 0; mf < 2; mf++)
#pragma unroll
                for (int nf = 0; nf < 4; nf++) {
                    acc[mf][nf] = __builtin_amdgcn_mfma_f32_16x16x32_bf16(aH[mf], bL[nf], acc[mf][nf], 0, 0, 0);
                    acc[mf][nf] = __builtin_amdgcn_mfma_f32_16x16x32_bf16(aL[mf], bH[nf], acc[mf][nf], 0, 0, 0);
                }
        }
    }
    __syncthreads();
    float* st = (float*)smem;   // [64][130]
#pragma unroll
    for (int mf = 0; mf < 2; mf++)
#pragma unroll
        for (int nf = 0; nf < 4; nf++)
#pragma unroll
            for (int j = 0; j < 4; j++) {
                int ml = w*32 + mf*16 + (lane>>4)*4 + j;
                int nl = nf*16 + ln;
                st[nl*130 + ml] = acc[mf][nf][j];
            }
    __syncthreads();
    int nl = tid >> 2, mq = (tid & 3) * 32;
    int n = n0 + nl;
    float* dst;
    if (MODE == 0) {
        dst = (n < DI) ? (out0 + ((size_t)b*DI + n)*LL + l0 + mq)
                       : (out1 + ((size_t)b*DI + (n - DI))*LL + l0 + mq);
    } else {
        dst = out0 + ((size_t)b*DI + n)*LL + l0 + mq;
    }
#pragma unroll
    for (int i = 0; i < 8; i++)
        *(float4*)(dst + i*4) = *(const float4*)&st[nl*130 + mq + i*4];
}

// -------- channel-major-A MFMA GEMM (fp32 A staged + on-the-fly bf16 split) ---
template<int MODE, int SPLIT, int PERM0>
__global__ __launch_bounds__(256) void gemm_cmaj(
    const float* __restrict__ A0, const float* __restrict__ A1,
    const ushort_t* __restrict__ W0h, const ushort_t* __restrict__ W0l,
    const ushort_t* __restrict__ W1h, const ushort_t* __restrict__ W1l,
    const float* __restrict__ resid,
    float* __restrict__ o0, float* __restrict__ o1, int Nreal)
{
    __shared__ __align__(16) char smem[33280];
    float* sA = (float*)smem;                       // [32][132]
    ushort_t* sWh = (ushort_t*)(smem + 16896);      // [4][64][8]
    ushort_t* sWl = (ushort_t*)(smem + 20992);
    bool sel = (blockIdx.z == 1);
    const float* A = sel ? A1 : A0;
    const ushort_t* Wh = sel ? W1h : W0h;
    const ushort_t* Wl = sel ? W1l : W0l;
    float* out0 = sel ? o1 : o0;
    const bool perm = sel ? false : (PERM0 != 0);
    int tid = threadIdx.x;
    int t0 = blockIdx.x * 128;
    int b = t0 >> 12, l0 = t0 & 4095;
    int n0 = blockIdx.y * 64;
    const float* Ab = A + (size_t)b * 384 * LL;
    int srow = tid >> 3, sc8 = tid & 7;
    int wrow = tid >> 2, kgW = tid & 3;
    int lane = tid & 63, w = tid >> 6;
    int ln = lane & 15, kg = lane >> 4;
    int am0 = w * 32 + ln;
    f32x4 acc[2][4];
#pragma unroll
    for (int mf = 0; mf < 2; mf++)
#pragma unroll
        for (int nf = 0; nf < 4; nf++) acc[mf][nf] = (f32x4){0.f, 0.f, 0.f, 0.f};

    for (int k0 = 0; k0 < 384; k0 += 32) {
        __syncthreads();
#pragma unroll
        for (int i = 0; i < 4; i++) {
            int m = (sc8 + 8*i) * 4;
            int src = perm ? ((((m >> 2) & 3) * 1024) + (((l0 + m) >> 4) << 2))
                           : (l0 + m);
            float4 v = *(const float4*)&Ab[(size_t)(k0 + srow)*LL + src];
            *(float4*)&sA[srow*132 + m] = v;
        }
        {
            ushort8 wv = *(const ushort8*)(Wh + (size_t)(n0 + wrow)*384 + k0 + kgW*8);
            *(ushort8*)(sWh + kgW*512 + wrow*8) = wv;
            if (SPLIT == 3) {
                ushort8 wl = *(const ushort8*)(Wl + (size_t)(n0 + wrow)*384 + k0 + kgW*8);
                *(ushort8*)(sWl + kgW*512 + wrow*8) = wl;
            }
        }
        __syncthreads();
        bf16x8 aH[2], aL[2];
#pragma unroll
        for (int mf = 0; mf < 2; mf++) {
            int am = am0 + mf*16;
#pragma unroll
            for (int e = 0; e < 8; e++) {
                float v = sA[(kg*8 + e)*132 + am];
                ushort_t h = f2bf(v);
                aH[mf][e] = (short)h;
                if (SPLIT == 3) aL[mf][e] = (short)f2bf(v - bf2f(h));
            }
        }
        bf16x8 bH[4], bL[4];
#pragma unroll
        for (int nf = 0; nf < 4; nf++) {
            bH[nf] = *(const bf16x8*)(sWh + kg*512 + (nf*16 + ln)*8);
            if (SPLIT == 3) bL[nf] = *(const bf16x8*)(sWl + kg*512 + (nf*16 + ln)*8);
        }
#pragma unroll
        for (int mf = 0; mf < 2; mf++)
#pragma unroll
            for (int nf = 0; nf < 4; nf++) {
                acc[mf][nf] = __builtin_amdgcn_mfma_f32_16x16x32_bf16(aH[mf], bH[nf], acc[mf][nf], 0, 0, 0);
                if (SPLIT == 3) {
                    acc[mf][nf] = __builtin_amdgcn_mfma_f32_16x16x32_bf16(aH[mf], bL[nf], acc[mf][nf], 0, 0, 0);
                    acc[mf][nf] = __builtin_amdgcn_mfma_f32_16x16x32_bf16(aL[mf], bH[nf], acc[mf][nf], 0, 0, 0);
                }
            }
    }

    if (MODE == 2) {
#pragma unroll
        for (int mf = 0; mf < 2; mf++)
#pragma unroll
            for (int j = 0; j < 4; j++) {
                int t = t0 + w*32 + mf*16 + (lane>>4)*4 + j;
#pragma unroll
                for (int nf = 0; nf < 4; nf++) {
                    int n = n0 + nf*16 + ln;
                    out0[(size_t)t*CM + n] = resid[(size_t)t*CM + n] + acc[mf][nf][j];
                }
            }
    } else {
        __syncthreads();
        float* st = (float*)smem;   // [64][130]
#pragma unroll
        for (int mf = 0; mf < 2; mf++)
#pragma unroll
            for (int nf = 0; nf < 4; nf++)
#pragma unroll
                for (int j = 0; j < 4; j++) {
                    int ml = w*32 + mf*16 + (lane>>4)*4 + j;
                    int nl = nf*16 + ln;
                    st[nl*130 + ml] = acc[mf][nf][j];
                }
        __syncthreads();
        int nl = tid >> 2, mq = (tid & 3) * 32;
        int n = n0 + nl;
        if (n < Nreal) {
            float* dst = out0 + ((size_t)b*Nreal + n)*LL + l0 + mq;
#pragma unroll
            for (int i = 0; i < 8; i++)
                *(float4*)(dst + i*4) = *(const float4*)&st[nl*130 + mq + i*4];
        }
    }
}

// -------- depthwise 3x3 conv + bias + SiLU -> xs in PERM layout ---------------
__global__ __launch_bounds__(256) void conv2d_silu_kernel(const float* __restrict__ xh,
    const float* __restrict__ w, const float* __restrict__ bias, float* __restrict__ xs)
{
    int tid = threadIdx.x;
    int l = blockIdx.x * 256 + tid;
    int c = blockIdx.y, b = blockIdx.z;
    const float* P = xh + ((size_t)b*DI + c)*LL;
    int h = l >> 6, ww = l & 63;
    float acc = bias[c];
#pragma unroll
    for (int kh = 0; kh < 3; kh++) {
        int hh = h + kh - 1;
        if ((unsigned)hh < 64u) {
#pragma unroll
            for (int kw = 0; kw < 3; kw++) {
                int wv = ww + kw - 1;
                if ((unsigned)wv < 64u) acc = fmaf(w[c*9 + kh*3 + kw], P[hh*64 + wv], acc);
            }
        }
    }
    float sg = 1.f / (1.f + __expf(-acc));
    xs[((size_t)b*DI + c)*LL + permidx(l)] = acc * sg;
}

// -------- SimpleGates on low B/C + sum high+low -> dbc [B][44][L] -------------
__global__ __launch_bounds__(256) void gates_kernel(const float* __restrict__ dbcH,
    const float* __restrict__ dbcL,
    const float* __restrict__ sgb1, const float* __restrict__ sgb2,
    const float* __restrict__ sgc1, const float* __restrict__ sgc2,
    float* __restrict__ dbc)
{
    __shared__ float w1[2][192*16];
    __shared__ float w2[2][16*96];
    __shared__ float red[4][16][64];
    int tid = threadIdx.x;
    for (int i = tid; i < 192*16; i += 256) { w1[0][i] = sgb1[i]; w1[1][i] = sgc1[i]; }
    for (int i = tid; i < 16*96;  i += 256) { w2[0][i] = sgb2[i]; w2[1][i] = sgc2[i]; }
    int lq = tid & 63, p = tid >> 6;
    int l = blockIdx.x * 64 + lq;
    int b = blockIdx.y;
    size_t pb_ = (size_t)b*NCH*LL + l;
    __syncthreads();
#pragma unroll
    for (int i = 0; i < 3; i++) {
        int c = p*3 + i;
        dbc[pb_ + (size_t)c*LL] = dbcH[pb_ + (size_t)c*LL] + dbcL[pb_ + (size_t)c*LL];
    }
    for (int gate = 0; gate < 2; gate++) {
        int coff = RK + gate*NST;
        float xin[16], og[16];
#pragma unroll
        for (int n = 0; n < 16; n++) { xin[n] = dbcL[pb_ + (size_t)(coff+n)*LL]; og[n] = 0.f; }
        int h0 = p * 24;
        for (int h = h0; h < h0 + 24; h++) {
            float ya = 0.f, yb = 0.f;
#pragma unroll
            for (int n = 0; n < 16; n++) {
                ya = fmaf(w1[gate][h*16+n], xin[n], ya);
                yb = fmaf(w1[gate][(h+SGH)*16+n], xin[n], yb);
            }
            float gg = 0.5f * ya * (1.f + erff(ya * 0.70710678f)) * yb;
#pragma unroll
            for (int n = 0; n < 16; n++) og[n] = fmaf(w2[gate][n*SGH+h], gg, og[n]);
        }
#pragma unroll
        for (int n = 0; n < 16; n++) red[p][n][lq] = og[n];
        __syncthreads();
#pragma unroll
        for (int i = 0; i < 4; i++) {
            int n = p*4 + i;
            float v = red[0][n][lq] + red[1][n][lq] + red[2][n][lq] + red[3][n][lq];
            dbc[pb_ + (size_t)(coff+n)*LL] = dbcH[pb_ + (size_t)(coff+n)*LL] + v;
        }
        __syncthreads();
    }
}

// -------- residual dilated dwconv1d: dts normal; Bs/Cs in PERM layout ---------
__global__ __launch_bounds__(256) void conv_dbc_kernel(const float* __restrict__ dbc,
    const float* __restrict__ wdt, const float* __restrict__ wB, const float* __restrict__ wC,
    float* __restrict__ dts, float* __restrict__ Bs, float* __restrict__ Cs)
{
    int l = blockIdx.x * 256 + threadIdx.x;
    int c = blockIdx.y, b = blockIdx.z;
    const float* wsrc = (c < RK) ? (wdt + c*15)
                      : (c < RK+NST ? wB + (c-RK)*15 : wC + (c-RK-NST)*15);
    float w[15];
#pragma unroll
    for (int k = 0; k < 15; k++) w[k] = wsrc[k];
    const float* P = dbc + ((size_t)b*NCH + c)*LL;
    float a = P[l];
#pragma unroll
    for (int k = 0; k < 15; k++) {
        int lt = l + 2*k - 14;
        if ((unsigned)lt < (unsigned)LL) a = fmaf(w[k], P[lt], a);
    }
    if (c < RK)            dts[((size_t)b*RK  + c)*LL + l] = a;
    else if (c < RK+NST)   Bs [((size_t)b*NST + (c-RK))*LL + permidx(l)] = a;
    else                   Cs [((size_t)b*NST + (c-RK-NST))*LL + permidx(l)] = a;
}

// -------- delta projection + softplus -> delta in PERM layout -----------------
__global__ __launch_bounds__(256) void delta_kernel(const float* __restrict__ dts,
    const float* __restrict__ dtw, const float* __restrict__ dtb, float* __restrict__ delta)
{
    __shared__ float sdt[RK][128];
    __shared__ float sw[64][RK];
    int tid = threadIdx.x;
    int l0 = blockIdx.x * 128, d0 = blockIdx.y * 64, b = blockIdx.z;
    for (int i = tid; i < RK*128; i += 256) {
        int r = i >> 7, lq = i & 127;
        sdt[r][lq] = dts[((size_t)b*RK + r)*LL + l0 + lq];
    }
    for (int i = tid; i < 64*RK; i += 256) {
        int dq = i / RK, r = i - dq*RK;
        sw[dq][r] = dtw[(size_t)(d0+dq)*RK + r];
    }
    __syncthreads();
    int lq = tid & 63, g = tid >> 6;
    for (int dd = 0; dd < 16; dd++) {
        int dqq = g*16 + dd, d = d0 + dqq;
        float wr[RK];
#pragma unroll
        for (int r = 0; r < RK; r++) wr[r] = sw[dqq][r];
        float bias = dtb[d];
#pragma unroll
        for (int li = 0; li < 2; li++) {
            int lloc = lq + li*64;
            float s = bias;
#pragma unroll
            for (int r = 0; r < RK; r++) s = fmaf(wr[r], sdt[r][lloc], s);
            float sp = fmaxf(s, 0.f) + __logf(1.f + __expf(-fabsf(s)));
            delta[((size_t)b*DI + d)*LL + permidx(l0 + lloc)] = sp;
        }
    }
}

// -------- selective scan v4 (measured best 56.6us): half-split + deferred fixup
__global__ __launch_bounds__(256) void scan_kernel(
    const float* __restrict__ u_, const float* __restrict__ delta_,
    const float* __restrict__ Bs_, const float* __restrict__ Cs_,
    const float* __restrict__ Alogs, const float* __restrict__ Ds,
    float* __restrict__ y0_, float* __restrict__ y1_)
{
    __shared__ float wAs[8][4], wBs[8][4];
    __shared__ float yt[16][258];
    int tid = threadIdx.x;
    int t4 = tid * 4;
    int bid = blockIdx.x;
    int half = bid & 1, bd = bid >> 1;
    int b = bd / DI, d = bd % DI;
    int n0 = half * 8;
    size_t rowoff = ((size_t)b*DI + d)*LL;
    float dl[16], du[16], yac[16];
    LD16P(du, u_ + rowoff, t4);
    LD16P(dl, delta_ + rowoff, t4);
    float Dd = Ds[d];
#pragma unroll
    for (int s = 0; s < 16; s++) {
        yac[s] = half ? 0.f : du[s]*Dd;
        du[s] = dl[s]*du[s];
    }
    int lane = tid & 63, w = tid >> 6;
#pragma unroll 1
    for (int j = 0; j < 8; j++) {
        float An = -__expf(Alogs[d*NST + n0 + j]);
        float Bn[16], Cn[16], t[16];
        LD16P(Bn, Bs_ + ((size_t)b*NST + n0 + j)*LL, t4);
        LD16P(Cn, Cs_ + ((size_t)b*NST + n0 + j)*LL, t4);
        float a = 1.f, h = 0.f;
#pragma unroll
        for (int s = 0; s < 16; s++) {
            float e = __expf(dl[s]*An);
            a *= e;
            h = fmaf(e, h, du[s]*Bn[s]);
            yac[s] = fmaf(Cn[s], h, yac[s]);
            t[s] = Cn[s]*a;
        }
        // cross-thread affine prefix on (a,h)
        float ap = a, hv = h;
        for (int off = 1; off < 64; off <<= 1) {
            float pa = __shfl_up(ap, (unsigned)off, 64);
            float pb = __shfl_up(hv, (unsigned)off, 64);
            if (lane >= off) { hv = fmaf(ap, pb, hv); ap *= pa; }
        }
        if (lane == 63) { wAs[j][w] = ap; wBs[j][w] = hv; }
        __syncthreads();
        float PB = 0.f;
        for (int ww = 0; ww < w; ww++) PB = fmaf(wAs[j][ww], PB, wBs[j][ww]);
        hv = fmaf(ap, PB, hv);
        float tt = __shfl_up(hv, 1u, 64);
        float hin = lane ? tt : PB;
#pragma unroll
        for (int s = 0; s < 16; s++) yac[s] = fmaf(t[s], hin, yac[s]);
    }
#pragma unroll
    for (int i = 0; i < 16; i++) yt[i][tid] = yac[i];
    __syncthreads();
    float* yout = (half ? y1_ : y0_) + rowoff;
#pragma unroll
    for (int r = 0; r < 16; r++)
        yout[r*256 + tid] = yt[tid & 15][r*16 + (tid >> 4)];
}

// -------- out-norm LN(384) on y0+y1 + z-SiLU gating (in-place over y1) --------
// 1024-thread blocks: 16 d-groups x 64 coalesced tokens -> 4 waves/SIMD
__global__ __launch_bounds__(1024) void outnorm_gate_kernel(const float* __restrict__ y0,
    float* y1g, const float* __restrict__ z,
    const float* __restrict__ g, const float* __restrict__ bt)
{
    __shared__ float rs_[16][64], rq_[16][64];
    __shared__ float mu_s[64], rstd_s[64];
    int tid = threadIdx.x;
    int lq = tid & 63, p = tid >> 6;          // p in 0..15
    int l = blockIdx.x * 64 + lq;
    int b = blockIdx.y;
    const float* yp0 = y0 + (size_t)b*DI*LL + l;
    float* yp1 = y1g + (size_t)b*DI*LL + l;
    float s = 0.f, q = 0.f;
#pragma unroll 4
    for (int i = 0; i < 24; i++) {
        int d = p*24 + i;
        float v = yp0[(size_t)d*LL] + yp1[(size_t)d*LL];
        s += v; q = fmaf(v, v, q);
    }
    rs_[p][lq] = s; rq_[p][lq] = q;
    __syncthreads();
    if (p == 0) {
        float ss = 0.f, qq = 0.f;
#pragma unroll
        for (int i = 0; i < 16; i++) { ss += rs_[i][lq]; qq += rq_[i][lq]; }
        float mu = ss * (1.f/DI);
        float var = qq * (1.f/DI) - mu*mu;
        mu_s[lq] = mu; rstd_s[lq] = rsqrtf(var + 1e-5f);
    }
    __syncthreads();
    float mu = mu_s[lq], rs = rstd_s[lq];
    const float* zp = z + (size_t)b*DI*LL + l;
#pragma unroll 4
    for (int i = 0; i < 24; i++) {
        int d = p*24 + i;
        float v = ((yp0[(size_t)d*LL] + yp1[(size_t)d*LL]) - mu)*rs*g[d] + bt[d];
        float zv = zp[(size_t)d*LL];
        float sg = 1.f / (1.f + __expf(-zv));
        yp1[(size_t)d*LL] = v * (zv * sg);
    }
}

extern "C" void kernel_launch(void* const* d_in, const int* in_sizes, int n_in,
                              void* d_out, int out_size, void* d_ws, size_t ws_size,
                              hipStream_t stream)
{
    (void)in_sizes; (void)n_in; (void)out_size; (void)ws_size;
    const float* x     = (const float*)d_in[0];
    const float* low   = (const float*)d_in[1];
    const float* ln_g  = (const float*)d_in[2];
    const float* ln_b  = (const float*)d_in[3];
    const float* w_in  = (const float*)d_in[4];
    const float* w_low = (const float*)d_in[5];
    const float* w_c2d = (const float*)d_in[6];
    const float* b_c2d = (const float*)d_in[7];
    const float* w_xp  = (const float*)d_in[8];
    const float* w_xpl = (const float*)d_in[9];
    const float* w_cdt = (const float*)d_in[10];
    const float* w_cB  = (const float*)d_in[11];
    const float* w_cC  = (const float*)d_in[12];
    const float* sgb1  = (const float*)d_in[13];
    const float* sgb2  = (const float*)d_in[14];
    const float* sgc1  = (const float*)d_in[15];
    const float* sgc2  = (const float*)d_in[16];
    const float* dtw   = (const float*)d_in[17];
    const float* dtb   = (const float*)d_in[18];
    const float* Alogs = (const float*)d_in[19];
    const float* Ds    = (const float*)d_in[20];
    const float* ong   = (const float*)d_in[21];
    const float* onb   = (const float*)d_in[22];
    const float* w_out = (const float*)d_in[23];
    float* ws  = (float*)d_ws;
    float* out = (float*)d_out;
    dim3 blk(256);

    // bf16 plane aliases
    ushort_t* wInH  = (ushort_t*)(ws + O_WT_IN);   ushort_t* wInL  = wInH + 147456;
    ushort_t* wLowH = (ushort_t*)(ws + O_WT_LOW);  ushort_t* wLowL = wLowH + 73728;
    ushort_t* wOutH = (ushort_t*)(ws + O_WT_OUT);  ushort_t* wOutL = wOutH + 73728;
    ushort_t* wXpH  = (ushort_t*)(ws + O_WT_XP);   ushort_t* wXpL  = wXpH + 24576;
    ushort_t* wXplH = (ushort_t*)(ws + O_WT_XPL);  ushort_t* wXplL = wXplH + 24576;
    ushort_t* xnh   = (ushort_t*)(ws + O_XN);      ushort_t* xnl   = xnh + 3145728;
    ushort_t* lowh  = (ushort_t*)(ws + O_LOWT);    ushort_t* lowl  = lowh + 3145728;

    wprep_kernel<<<336, blk, 0, stream>>>(w_in, wInH, wInL, w_low, wLowH, wLowL,
                                          w_out, wOutH, wOutL,
                                          w_xp, wXpH, wXpL, w_xpl, wXplH, wXplL);

    actprep_kernel<<<3328, blk, 0, stream>>>(x, ln_g, ln_b, xnh, xnl, low, lowh, lowl);

    gemm_mfma<0,3,192><<<dim3(128,12), blk, 0, stream>>>(xnh, xnl, wInH, wInL,
                                                         ws+O_XH, ws+O_Z);
    gemm_mfma<1,3,192><<<dim3(128,6),  blk, 0, stream>>>(lowh, lowl, wLowH, wLowL,
                                                         ws+O_LOWP, nullptr);

    conv2d_silu_kernel<<<dim3(16,384,4), blk, 0, stream>>>(ws+O_XH, w_c2d, b_c2d, ws+O_XS);

    gemm_cmaj<1,3,1><<<dim3(128,1,2), blk, 0, stream>>>(ws+O_XS, ws+O_LOWP,
                                                        wXpH, wXpL, wXplH, wXplL,
                                                        nullptr, ws+O_DBCH, ws+O_DBCL, NCH);

    gates_kernel<<<dim3(64,4), blk, 0, stream>>>(ws+O_DBCH, ws+O_DBCL, sgb1, sgb2, sgc1, sgc2, ws+O_DBC);

    conv_dbc_kernel<<<dim3(16,44,4), blk, 0, stream>>>(ws+O_DBC, w_cdt, w_cB, w_cC,
                                                       ws+O_DTS, ws+O_BS, ws+O_CS);
    delta_kernel<<<dim3(32,6,4), blk, 0, stream>>>(ws+O_DTS, dtw, dtb, ws+O_DELTA);

    scan_kernel<<<3072, blk, 0, stream>>>(ws+O_XS, ws+O_DELTA, ws+O_BS, ws+O_CS, Alogs, Ds,
                                          ws+O_Y, ws+O_Y1);

    outnorm_gate_kernel<<<dim3(64,4), dim3(1024), 0, stream>>>(ws+O_Y, ws+O_Y1, ws+O_Z, ong, onb);

    gemm_cmaj<2,1,0><<<dim3(128,3,1), blk, 0, stream>>>(ws+O_Y1, nullptr,
                                                        wOutH, wOutL, nullptr, nullptr,
                                                        x, out, nullptr, CM);
}

// Round 12
// 259.410 us; speedup vs baseline: 1.2692x; 1.0782x over previous
//
#include <hip/hip_runtime.h>
#include <math.h>

#define LL 4096
#define NBATCH 4
#define CM 192
#define DI 384
#define NST 16
#define RK 12
#define NCH 44
#define SGH 96

typedef unsigned short ushort_t;
typedef __attribute__((ext_vector_type(8))) short bf16x8;
typedef __attribute__((ext_vector_type(4))) float f32x4;
typedef __attribute__((ext_vector_type(8))) unsigned short ushort8;
typedef __attribute__((ext_vector_type(4))) unsigned short ushort4v;

// workspace offsets (float units)
#define O_WT_IN   0
#define O_WT_LOW  147456
#define O_WT_XP   221184
#define O_WT_XPL  245760
#define O_WT_OUT  270336
#define O_XN      344064
#define O_LOWT    3489792
#define O_XH      6635520
#define O_Z       12926976
#define O_LOWP    19218432
#define O_XS      25509888
#define O_DBCH    31801344
#define O_DBCL    32522240
#define O_DBC     33243136
#define O_BS      33964032
#define O_CS      34226176
#define O_DELTA   O_LOWP   // lowp dead after x_proj GEMMs
#define O_Y       O_XH     // xh dead after conv2d
#define O_Y1      O_XN     // xn/lowt bf16 planes dead after in/low GEMMs
#define O_DTS     O_DBCH   // dbcH dead after gates_kernel

__device__ __forceinline__ ushort_t f2bf(float v) {
    unsigned u = __float_as_uint(v);
    return (ushort_t)((u + 0x7FFFu + ((u >> 16) & 1u)) >> 16);
}
__device__ __forceinline__ float bf2f(ushort_t h) {
    return __uint_as_float(((unsigned)h) << 16);
}

// ---- chunk-transposed ("perm") layout within each 4096-element row ----------
__device__ __forceinline__ int permidx(int l) {
    return ((l >> 2) & 3) * 1024 + ((l >> 4) << 2) + (l & 3);
}

#define LD16P(dst, row, t4) { \
  float4 _a = *(const float4*)((row) + (t4)); \
  float4 _b = *(const float4*)((row) + 1024 + (t4)); \
  float4 _c = *(const float4*)((row) + 2048 + (t4)); \
  float4 _d = *(const float4*)((row) + 3072 + (t4)); \
  dst[0]=_a.x; dst[1]=_a.y; dst[2]=_a.z; dst[3]=_a.w; \
  dst[4]=_b.x; dst[5]=_b.y; dst[6]=_b.z; dst[7]=_b.w; \
  dst[8]=_c.x; dst[9]=_c.y; dst[10]=_c.z; dst[11]=_c.w; \
  dst[12]=_d.x; dst[13]=_d.y; dst[14]=_d.z; dst[15]=_d.w; }

// -------- merged prep: weight splits (bx<336) + LN/act splits (bx>=336) -------
__global__ __launch_bounds__(256) void prep_kernel(
    const float* __restrict__ i0, ushort_t* h0, ushort_t* l0_,
    const float* __restrict__ i1, ushort_t* h1, ushort_t* l1,
    const float* __restrict__ i2, ushort_t* h2, ushort_t* l2,
    const float* __restrict__ p0, ushort_t* ph0, ushort_t* pl0,
    const float* __restrict__ p1, ushort_t* ph1, ushort_t* pl1,
    const float* __restrict__ X, const float* __restrict__ gw, const float* __restrict__ bw,
    ushort_t* __restrict__ oh, ushort_t* __restrict__ ol,
    const float* __restrict__ LOW, ushort_t* __restrict__ lh, ushort_t* __restrict__ llo)
{
    __shared__ float xt[64][193];
    __shared__ float reds[64][4], redq[64][4];
    __shared__ float mu_s[64], rs_s[64];
    int bx = blockIdx.x;
    int tid = threadIdx.x;
    if (bx < 288) {
        const float* in; ushort_t* oh_; ushort_t* ol_; int base;
        if (bx < 144)      { in = i0; oh_ = h0; ol_ = l0_; base = bx * 1024; }
        else if (bx < 216) { in = i1; oh_ = h1; ol_ = l1;  base = (bx-144) * 1024; }
        else               { in = i2; oh_ = h2; ol_ = l2;  base = (bx-216) * 1024; }
        int i = base + tid * 4;
        float4 v = *(const float4*)&in[i];
        ushort4v h, l;
        h.x = f2bf(v.x); l.x = f2bf(v.x - bf2f(h.x));
        h.y = f2bf(v.y); l.y = f2bf(v.y - bf2f(h.y));
        h.z = f2bf(v.z); l.z = f2bf(v.z - bf2f(h.z));
        h.w = f2bf(v.w); l.w = f2bf(v.w - bf2f(h.w));
        *(ushort4v*)&oh_[i] = h;
        *(ushort4v*)&ol_[i] = l;
        return;
    }
    if (bx < 336) {
        int bb = bx - 288;
        int sel = bb / 24, bxx = bb % 24;
        const float* in = sel ? p1 : p0;
        ushort_t* oh_ = sel ? ph1 : ph0;
        ushort_t* ol_ = sel ? pl1 : pl0;
        int idx = (bxx * 256 + tid) * 4;
        int n = idx / 384;
        float4 v = (n < NCH) ? *(const float4*)&in[idx] : make_float4(0.f,0.f,0.f,0.f);
        ushort4v h, l;
        h.x = f2bf(v.x); l.x = f2bf(v.x - bf2f(h.x));
        h.y = f2bf(v.y); l.y = f2bf(v.y - bf2f(h.y));
        h.z = f2bf(v.z); l.z = f2bf(v.z - bf2f(h.z));
        h.w = f2bf(v.w); l.w = f2bf(v.w - bf2f(h.w));
        *(ushort4v*)&oh_[idx] = h;
        *(ushort4v*)&ol_[idx] = l;
        return;
    }
    int ax = bx - 336;
    if (ax >= 256) {
        int i = ((ax - 256) * 256 + tid) * 4;
        float4 v = *(const float4*)&LOW[i];
        ushort4v h, l;
        h.x = f2bf(v.x); l.x = f2bf(v.x - bf2f(h.x));
        h.y = f2bf(v.y); l.y = f2bf(v.y - bf2f(h.y));
        h.z = f2bf(v.z); l.z = f2bf(v.z - bf2f(h.z));
        h.w = f2bf(v.w); l.w = f2bf(v.w - bf2f(h.w));
        *(ushort4v*)&lh[i] = h;
        *(ushort4v*)&llo[i] = l;
        return;
    }
    int t0 = ax * 64;
    const float* Xb = X + (size_t)t0 * CM;
#pragma unroll
    for (int i = 0; i < 12; i++) {
        int f4 = tid + 256 * i;
        float4 v = *(const float4*)&Xb[f4 * 4];
        int row = f4 / 48, c = (f4 % 48) * 4;
        xt[row][c] = v.x; xt[row][c+1] = v.y; xt[row][c+2] = v.z; xt[row][c+3] = v.w;
    }
    __syncthreads();
    int tok = tid & 63, p = tid >> 6;
    float s = 0.f, q = 0.f;
#pragma unroll 8
    for (int i = 0; i < 48; i++) { float v = xt[tok][p*48+i]; s += v; q = fmaf(v, v, q); }
    reds[tok][p] = s; redq[tok][p] = q;
    __syncthreads();
    if (tid < 64) {
        float ss = reds[tid][0]+reds[tid][1]+reds[tid][2]+reds[tid][3];
        float qq = redq[tid][0]+redq[tid][1]+redq[tid][2]+redq[tid][3];
        float mu = ss * (1.f/CM);
        float var = qq * (1.f/CM) - mu*mu;
        mu_s[tid] = mu; rs_s[tid] = rsqrtf(var + 1e-5f);
    }
    __syncthreads();
    int tok2 = tid >> 2, c0 = (tid & 3) * 48;
    float mu = mu_s[tok2], rs = rs_s[tok2];
    size_t tb = (size_t)(t0 + tok2) * CM;
#pragma unroll 8
    for (int i = 0; i < 48; i++) {
        int c = c0 + i;
        float v = (xt[tok2][c] - mu) * rs * gw[c] + bw[c];
        ushort_t h = f2bf(v);
        oh[tb + c] = h;
        ol[tb + c] = f2bf(v - bf2f(h));
    }
}

// -------- merged in_proj + low_proj split-bf16 MFMA GEMM ----------------------
// grid (128, 18): y<12 -> in_proj (xnh/xnl x wIn -> xh/z); y>=12 -> low_proj.
__global__ __launch_bounds__(256) void gemm_inlow(
    const ushort_t* __restrict__ xnh, const ushort_t* __restrict__ xnl,
    const ushort_t* __restrict__ wInH, const ushort_t* __restrict__ wInL,
    const ushort_t* __restrict__ lowh, const ushort_t* __restrict__ lowl,
    const ushort_t* __restrict__ wLowH, const ushort_t* __restrict__ wLowL,
    float* __restrict__ xh, float* __restrict__ z, float* __restrict__ lowp)
{
    __shared__ __align__(16) char smem[33280];
    ushort_t* sAh = (ushort_t*)smem;        // [4][128][8]
    ushort_t* sAl = sAh + 4096;
    ushort_t* sWh = sAh + 8192;             // [4][64][8]
    ushort_t* sWl = sAh + 10240;
    const int KDIM = 192;
    int tid = threadIdx.x;
    int t0 = blockIdx.x * 128;
    int b = t0 >> 12, l0 = t0 & 4095;
    int ysel = blockIdx.y;
    bool isLow = ysel >= 12;
    int n0 = (isLow ? (ysel - 12) : ysel) * 64;
    const ushort_t* Ahi = isLow ? lowh : xnh;
    const ushort_t* Alo = isLow ? lowl : xnl;
    const ushort_t* Whi = isLow ? wLowH : wInH;
    const ushort_t* Wlo = isLow ? wLowL : wInL;
    int arow = tid >> 1, kgA = (tid & 1) * 2;
    int wrow = tid >> 2, kgW = tid & 3;
    const ushort_t* gAh = Ahi + (size_t)(t0 + arow) * KDIM + kgA * 8;
    const ushort_t* gAl = Alo + (size_t)(t0 + arow) * KDIM + kgA * 8;
    const ushort_t* gWh = Whi + (size_t)(n0 + wrow) * KDIM + kgW * 8;
    const ushort_t* gWl = Wlo + (size_t)(n0 + wrow) * KDIM + kgW * 8;
    int lane = tid & 63, w = tid >> 6;
    int ln = lane & 15, kg = lane >> 4;
    int am0 = w * 32 + ln;
    f32x4 acc[2][4];
#pragma unroll
    for (int mf = 0; mf < 2; mf++)
#pragma unroll
        for (int nf = 0; nf < 4; nf++) acc[mf][nf] = (f32x4){0.f, 0.f, 0.f, 0.f};

    for (int k0 = 0; k0 < KDIM; k0 += 32) {
        __syncthreads();
        {
            ushort8 a0 = *(const ushort8*)(gAh + k0);
            ushort8 a1 = *(const ushort8*)(gAh + k0 + 8);
            *(ushort8*)(sAh + kgA*1024 + arow*8) = a0;
            *(ushort8*)(sAh + (kgA+1)*1024 + arow*8) = a1;
            ushort8 w0 = *(const ushort8*)(gWh + k0);
            *(ushort8*)(sWh + kgW*512 + wrow*8) = w0;
            ushort8 b0 = *(const ushort8*)(gAl + k0);
            ushort8 b1 = *(const ushort8*)(gAl + k0 + 8);
            *(ushort8*)(sAl + kgA*1024 + arow*8) = b0;
            *(ushort8*)(sAl + (kgA+1)*1024 + arow*8) = b1;
            ushort8 w1 = *(const ushort8*)(gWl + k0);
            *(ushort8*)(sWl + kgW*512 + wrow*8) = w1;
        }
        __syncthreads();
        bf16x8 aH[2], bH[4], aL[2], bL[4];
#pragma unroll
        for (int mf = 0; mf < 2; mf++) {
            aH[mf] = *(const bf16x8*)(sAh + kg*1024 + (am0 + mf*16)*8);
            aL[mf] = *(const bf16x8*)(sAl + kg*1024 + (am0 + mf*16)*8);
        }
#pragma unroll
        for (int nf = 0; nf < 4; nf++) {
            bH[nf] = *(const bf16x8*)(sWh + kg*512 + (nf*16 + ln)*8);
            bL[nf] = *(const bf16x8*)(sWl + kg*512 + (nf*16 + ln)*8);
        }
#pragma unroll
        for (int mf = 0; mf < 2; mf++)
#pragma unroll
            for (int nf = 0; nf < 4; nf++) {
                acc[mf][nf] = __builtin_amdgcn_mfma_f32_16x16x32_bf16(aH[mf], bH[nf], acc[mf][nf], 0, 0, 0);
                acc[mf][nf] = __builtin_amdgcn_mfma_f32_16x16x32_bf16(aH[mf], bL[nf], acc[mf][nf], 0, 0, 0);
                acc[mf][nf] = __builtin_amdgcn_mfma_f32_16x16x32_bf16(aL[mf], bH[nf], acc[mf][nf], 0, 0, 0);
            }
    }
    __syncthreads();
    float* st = (float*)smem;   // [64][130]
#pragma unroll
    for (int mf = 0; mf < 2; mf++)
#pragma unroll
        for (int nf = 0; nf < 4; nf++)
#pragma unroll
            for (int j = 0; j < 4; j++) {
                int ml = w*32 + mf*16 + (lane>>4)*4 + j;
                int nl = nf*16 + ln;
                st[nl*130 + ml] = acc[mf][nf][j];
            }
    __syncthreads();
    int nl = tid >> 2, mq = (tid & 3) * 32;
    int n = n0 + nl;
    float* dst;
    if (!isLow) {
        dst = (n < DI) ? (xh + ((size_t)b*DI + n)*LL + l0 + mq)
                       : (z  + ((size_t)b*DI + (n - DI))*LL + l0 + mq);
    } else {
        dst = lowp + ((size_t)b*DI + n)*LL + l0 + mq;
    }
#pragma unroll
    for (int i = 0; i < 8; i++)
        *(float4*)(dst + i*4) = *(const float4*)&st[nl*130 + mq + i*4];
}

// -------- channel-major-A MFMA GEMM (fp32 A staged + on-the-fly bf16 split) ---
template<int MODE, int SPLIT, int PERM0>
__global__ __launch_bounds__(256) void gemm_cmaj(
    const float* __restrict__ A0, const float* __restrict__ A1,
    const ushort_t* __restrict__ W0h, const ushort_t* __restrict__ W0l,
    const ushort_t* __restrict__ W1h, const ushort_t* __restrict__ W1l,
    const float* __restrict__ resid,
    float* __restrict__ o0, float* __restrict__ o1, int Nreal)
{
    __shared__ __align__(16) char smem[33280];
    float* sA = (float*)smem;                       // [32][132]
    ushort_t* sWh = (ushort_t*)(smem + 16896);      // [4][64][8]
    ushort_t* sWl = (ushort_t*)(smem + 20992);
    bool sel = (blockIdx.z == 1);
    const float* A = sel ? A1 : A0;
    const ushort_t* Wh = sel ? W1h : W0h;
    const ushort_t* Wl = sel ? W1l : W0l;
    float* out0 = sel ? o1 : o0;
    const bool perm = sel ? false : (PERM0 != 0);
    int tid = threadIdx.x;
    int t0 = blockIdx.x * 128;
    int b = t0 >> 12, l0 = t0 & 4095;
    int n0 = blockIdx.y * 64;
    const float* Ab = A + (size_t)b * 384 * LL;
    int srow = tid >> 3, sc8 = tid & 7;
    int wrow = tid >> 2, kgW = tid & 3;
    int lane = tid & 63, w = tid >> 6;
    int ln = lane & 15, kg = lane >> 4;
    int am0 = w * 32 + ln;
    f32x4 acc[2][4];
#pragma unroll
    for (int mf = 0; mf < 2; mf++)
#pragma unroll
        for (int nf = 0; nf < 4; nf++) acc[mf][nf] = (f32x4){0.f, 0.f, 0.f, 0.f};

    for (int k0 = 0; k0 < 384; k0 += 32) {
        __syncthreads();
#pragma unroll
        for (int i = 0; i < 4; i++) {
            int m = (sc8 + 8*i) * 4;
            int src = perm ? ((((m >> 2) & 3) * 1024) + (((l0 + m) >> 4) << 2))
                           : (l0 + m);
            float4 v = *(const float4*)&Ab[(size_t)(k0 + srow)*LL + src];
            *(float4*)&sA[srow*132 + m] = v;
        }
        {
            ushort8 wv = *(const ushort8*)(Wh + (size_t)(n0 + wrow)*384 + k0 + kgW*8);
            *(ushort8*)(sWh + kgW*512 + wrow*8) = wv;
            if (SPLIT == 3) {
                ushort8 wl = *(const ushort8*)(Wl + (size_t)(n0 + wrow)*384 + k0 + kgW*8);
                *(ushort8*)(sWl + kgW*512 + wrow*8) = wl;
            }
        }
        __syncthreads();
        bf16x8 aH[2], aL[2];
#pragma unroll
        for (int mf = 0; mf < 2; mf++) {
            int am = am0 + mf*16;
#pragma unroll
            for (int e = 0; e < 8; e++) {
                float v = sA[(kg*8 + e)*132 + am];
                ushort_t h = f2bf(v);
                aH[mf][e] = (short)h;
                if (SPLIT == 3) aL[mf][e] = (short)f2bf(v - bf2f(h));
            }
        }
        bf16x8 bH[4], bL[4];
#pragma unroll
        for (int nf = 0; nf < 4; nf++) {
            bH[nf] = *(const bf16x8*)(sWh + kg*512 + (nf*16 + ln)*8);
            if (SPLIT == 3) bL[nf] = *(const bf16x8*)(sWl + kg*512 + (nf*16 + ln)*8);
        }
#pragma unroll
        for (int mf = 0; mf < 2; mf++)
#pragma unroll
            for (int nf = 0; nf < 4; nf++) {
                acc[mf][nf] = __builtin_amdgcn_mfma_f32_16x16x32_bf16(aH[mf], bH[nf], acc[mf][nf], 0, 0, 0);
                if (SPLIT == 3) {
                    acc[mf][nf] = __builtin_amdgcn_mfma_f32_16x16x32_bf16(aH[mf], bL[nf], acc[mf][nf], 0, 0, 0);
                    acc[mf][nf] = __builtin_amdgcn_mfma_f32_16x16x32_bf16(aL[mf], bH[nf], acc[mf][nf], 0, 0, 0);
                }
            }
    }

    if (MODE == 2) {
#pragma unroll
        for (int mf = 0; mf < 2; mf++)
#pragma unroll
            for (int j = 0; j < 4; j++) {
                int t = t0 + w*32 + mf*16 + (lane>>4)*4 + j;
#pragma unroll
                for (int nf = 0; nf < 4; nf++) {
                    int n = n0 + nf*16 + ln;
                    out0[(size_t)t*CM + n] = resid[(size_t)t*CM + n] + acc[mf][nf][j];
                }
            }
    } else {
        __syncthreads();
        float* st = (float*)smem;   // [64][130]
#pragma unroll
        for (int mf = 0; mf < 2; mf++)
#pragma unroll
            for (int nf = 0; nf < 4; nf++)
#pragma unroll
                for (int j = 0; j < 4; j++) {
                    int ml = w*32 + mf*16 + (lane>>4)*4 + j;
                    int nl = nf*16 + ln;
                    st[nl*130 + ml] = acc[mf][nf][j];
                }
        __syncthreads();
        int nl = tid >> 2, mq = (tid & 3) * 32;
        int n = n0 + nl;
        if (n < Nreal) {
            float* dst = out0 + ((size_t)b*Nreal + n)*LL + l0 + mq;
#pragma unroll
            for (int i = 0; i < 8; i++)
                *(float4*)(dst + i*4) = *(const float4*)&st[nl*130 + mq + i*4];
        }
    }
}

// -------- depthwise 3x3 conv + bias + SiLU -> xs in PERM layout ---------------
__global__ __launch_bounds__(256) void conv2d_silu_kernel(const float* __restrict__ xh,
    const float* __restrict__ w, const float* __restrict__ bias, float* __restrict__ xs)
{
    int tid = threadIdx.x;
    int l = blockIdx.x * 256 + tid;
    int c = blockIdx.y, b = blockIdx.z;
    const float* P = xh + ((size_t)b*DI + c)*LL;
    int h = l >> 6, ww = l & 63;
    float acc = bias[c];
#pragma unroll
    for (int kh = 0; kh < 3; kh++) {
        int hh = h + kh - 1;
        if ((unsigned)hh < 64u) {
#pragma unroll
            for (int kw = 0; kw < 3; kw++) {
                int wv = ww + kw - 1;
                if ((unsigned)wv < 64u) acc = fmaf(w[c*9 + kh*3 + kw], P[hh*64 + wv], acc);
            }
        }
    }
    float sg = 1.f / (1.f + __expf(-acc));
    xs[((size_t)b*DI + c)*LL + permidx(l)] = acc * sg;
}

// -------- SimpleGates on low B/C + sum high+low -> dbc [B][44][L] -------------
// grid (64,4,2): z=0 -> dt passthrough + B gate; z=1 -> C gate.
__global__ __launch_bounds__(256) void gates_kernel(const float* __restrict__ dbcH,
    const float* __restrict__ dbcL,
    const float* __restrict__ sgb1, const float* __restrict__ sgb2,
    const float* __restrict__ sgc1, const float* __restrict__ sgc2,
    float* __restrict__ dbc)
{
    __shared__ float w1[192*16];
    __shared__ float w2[16*96];
    __shared__ float red[4][16][64];
    int tid = threadIdx.x;
    int gate = blockIdx.z;
    const float* g1 = gate ? sgc1 : sgb1;
    const float* g2 = gate ? sgc2 : sgb2;
    for (int i = tid; i < 192*16; i += 256) w1[i] = g1[i];
    for (int i = tid; i < 16*96;  i += 256) w2[i] = g2[i];
    int lq = tid & 63, p = tid >> 6;
    int l = blockIdx.x * 64 + lq;
    int b = blockIdx.y;
    size_t pb_ = (size_t)b*NCH*LL + l;
    __syncthreads();
    if (!gate) {
#pragma unroll
        for (int i = 0; i < 3; i++) {
            int c = p*3 + i;
            dbc[pb_ + (size_t)c*LL] = dbcH[pb_ + (size_t)c*LL] + dbcL[pb_ + (size_t)c*LL];
        }
    }
    int coff = RK + gate*NST;
    float xin[16], og[16];
#pragma unroll
    for (int n = 0; n < 16; n++) { xin[n] = dbcL[pb_ + (size_t)(coff+n)*LL]; og[n] = 0.f; }
    int h0 = p * 24;
    for (int h = h0; h < h0 + 24; h++) {
        float ya = 0.f, yb = 0.f;
#pragma unroll
        for (int n = 0; n < 16; n++) {
            ya = fmaf(w1[h*16+n], xin[n], ya);
            yb = fmaf(w1[(h+SGH)*16+n], xin[n], yb);
        }
        float gg = 0.5f * ya * (1.f + erff(ya * 0.70710678f)) * yb;
#pragma unroll
        for (int n = 0; n < 16; n++) og[n] = fmaf(w2[n*SGH+h], gg, og[n]);
    }
#pragma unroll
    for (int n = 0; n < 16; n++) red[p][n][lq] = og[n];
    __syncthreads();
#pragma unroll
    for (int i = 0; i < 4; i++) {
        int n = p*4 + i;
        float v = red[0][n][lq] + red[1][n][lq] + red[2][n][lq] + red[3][n][lq];
        dbc[pb_ + (size_t)(coff+n)*LL] = dbcH[pb_ + (size_t)(coff+n)*LL] + v;
    }
}

// -------- residual dilated dwconv1d: dts normal; Bs/Cs in PERM layout ---------
__global__ __launch_bounds__(256) void conv_dbc_kernel(const float* __restrict__ dbc,
    const float* __restrict__ wdt, const float* __restrict__ wB, const float* __restrict__ wC,
    float* __restrict__ dts, float* __restrict__ Bs, float* __restrict__ Cs)
{
    int l = blockIdx.x * 256 + threadIdx.x;
    int c = blockIdx.y, b = blockIdx.z;
    const float* wsrc = (c < RK) ? (wdt + c*15)
                      : (c < RK+NST ? wB + (c-RK)*15 : wC + (c-RK-NST)*15);
    float w[15];
#pragma unroll
    for (int k = 0; k < 15; k++) w[k] = wsrc[k];
    const float* P = dbc + ((size_t)b*NCH + c)*LL;
    float a = P[l];
#pragma unroll
    for (int k = 0; k < 15; k++) {
        int lt = l + 2*k - 14;
        if ((unsigned)lt < (unsigned)LL) a = fmaf(w[k], P[lt], a);
    }
    if (c < RK)            dts[((size_t)b*RK  + c)*LL + l] = a;
    else if (c < RK+NST)   Bs [((size_t)b*NST + (c-RK))*LL + permidx(l)] = a;
    else                   Cs [((size_t)b*NST + (c-RK-NST))*LL + permidx(l)] = a;
}

// -------- delta projection + softplus -> delta in PERM layout -----------------
__global__ __launch_bounds__(256) void delta_kernel(const float* __restrict__ dts,
    const float* __restrict__ dtw, const float* __restrict__ dtb, float* __restrict__ delta)
{
    __shared__ float sdt[RK][128];
    __shared__ float sw[64][RK];
    int tid = threadIdx.x;
    int l0 = blockIdx.x * 128, d0 = blockIdx.y * 64, b = blockIdx.z;
    for (int i = tid; i < RK*128; i += 256) {
        int r = i >> 7, lq = i & 127;
        sdt[r][lq] = dts[((size_t)b*RK + r)*LL + l0 + lq];
    }
    for (int i = tid; i < 64*RK; i += 256) {
        int dq = i / RK, r = i - dq*RK;
        sw[dq][r] = dtw[(size_t)(d0+dq)*RK + r];
    }
    __syncthreads();
    int lq = tid & 63, g = tid >> 6;
    for (int dd = 0; dd < 16; dd++) {
        int dqq = g*16 + dd, d = d0 + dqq;
        float wr[RK];
#pragma unroll
        for (int r = 0; r < RK; r++) wr[r] = sw[dqq][r];
        float bias = dtb[d];
#pragma unroll
        for (int li = 0; li < 2; li++) {
            int lloc = lq + li*64;
            float s = bias;
#pragma unroll
            for (int r = 0; r < RK; r++) s = fmaf(wr[r], sdt[r][lloc], s);
            float sp = fmaxf(s, 0.f) + __logf(1.f + __expf(-fabsf(s)));
            delta[((size_t)b*DI + d)*LL + permidx(l0 + lloc)] = sp;
        }
    }
}

// -------- selective scan v4 (measured best): half-split + deferred fixup ------
__global__ __launch_bounds__(256) void scan_kernel(
    const float* __restrict__ u_, const float* __restrict__ delta_,
    const float* __restrict__ Bs_, const float* __restrict__ Cs_,
    const float* __restrict__ Alogs, const float* __restrict__ Ds,
    float* __restrict__ y0_, float* __restrict__ y1_)
{
    __shared__ float wAs[8][4], wBs[8][4];
    __shared__ float yt[16][258];
    int tid = threadIdx.x;
    int t4 = tid * 4;
    int bid = blockIdx.x;
    int half = bid & 1, bd = bid >> 1;
    int b = bd / DI, d = bd % DI;
    int n0 = half * 8;
    size_t rowoff = ((size_t)b*DI + d)*LL;
    float dl[16], du[16], yac[16];
    LD16P(du, u_ + rowoff, t4);
    LD16P(dl, delta_ + rowoff, t4);
    float Dd = Ds[d];
#pragma unroll
    for (int s = 0; s < 16; s++) {
        yac[s] = half ? 0.f : du[s]*Dd;
        du[s] = dl[s]*du[s];
    }
    int lane = tid & 63, w = tid >> 6;
#pragma unroll 1
    for (int j = 0; j < 8; j++) {
        float An = -__expf(Alogs[d*NST + n0 + j]);
        float Bn[16], Cn[16], t[16];
        LD16P(Bn, Bs_ + ((size_t)b*NST + n0 + j)*LL, t4);
        LD16P(Cn, Cs_ + ((size_t)b*NST + n0 + j)*LL, t4);
        float a = 1.f, h = 0.f;
#pragma unroll
        for (int s = 0; s < 16; s++) {
            float e = __expf(dl[s]*An);
            a *= e;
            h = fmaf(e, h, du[s]*Bn[s]);
            yac[s] = fmaf(Cn[s], h, yac[s]);
            t[s] = Cn[s]*a;
        }
        float ap = a, hv = h;
        for (int off = 1; off < 64; off <<= 1) {
            float pa = __shfl_up(ap, (unsigned)off, 64);
            float pb = __shfl_up(hv, (unsigned)off, 64);
            if (lane >= off) { hv = fmaf(ap, pb, hv); ap *= pa; }
        }
        if (lane == 63) { wAs[j][w] = ap; wBs[j][w] = hv; }
        __syncthreads();
        float PB = 0.f;
        for (int ww = 0; ww < w; ww++) PB = fmaf(wAs[j][ww], PB, wBs[j][ww]);
        hv = fmaf(ap, PB, hv);
        float tt = __shfl_up(hv, 1u, 64);
        float hin = lane ? tt : PB;
#pragma unroll
        for (int s = 0; s < 16; s++) yac[s] = fmaf(t[s], hin, yac[s]);
    }
#pragma unroll
    for (int i = 0; i < 16; i++) yt[i][tid] = yac[i];
    __syncthreads();
    float* yout = (half ? y1_ : y0_) + rowoff;
#pragma unroll
    for (int r = 0; r < 16; r++)
        yout[r*256 + tid] = yt[tid & 15][r*16 + (tid >> 4)];
}

// -------- out-norm LN(384) on y0+y1 + z-SiLU gating (in-place over y1) --------
__global__ __launch_bounds__(1024) void outnorm_gate_kernel(const float* __restrict__ y0,
    float* y1g, const float* __restrict__ z,
    const float* __restrict__ g, const float* __restrict__ bt)
{
    __shared__ float rs_[16][64], rq_[16][64];
    __shared__ float mu_s[64], rstd_s[64];
    int tid = threadIdx.x;
    int lq = tid & 63, p = tid >> 6;          // p in 0..15
    int l = blockIdx.x * 64 + lq;
    int b = blockIdx.y;
    const float* yp0 = y0 + (size_t)b*DI*LL + l;
    float* yp1 = y1g + (size_t)b*DI*LL + l;
    float s = 0.f, q = 0.f;
#pragma unroll 4
    for (int i = 0; i < 24; i++) {
        int d = p*24 + i;
        float v = yp0[(size_t)d*LL] + yp1[(size_t)d*LL];
        s += v; q = fmaf(v, v, q);
    }
    rs_[p][lq] = s; rq_[p][lq] = q;
    __syncthreads();
    if (p == 0) {
        float ss = 0.f, qq = 0.f;
#pragma unroll
        for (int i = 0; i < 16; i++) { ss += rs_[i][lq]; qq += rq_[i][lq]; }
        float mu = ss * (1.f/DI);
        float var = qq * (1.f/DI) - mu*mu;
        mu_s[lq] = mu; rstd_s[lq] = rsqrtf(var + 1e-5f);
    }
    __syncthreads();
    float mu = mu_s[lq], rs = rstd_s[lq];
    const float* zp = z + (size_t)b*DI*LL + l;
#pragma unroll 4
    for (int i = 0; i < 24; i++) {
        int d = p*24 + i;
        float v = ((yp0[(size_t)d*LL] + yp1[(size_t)d*LL]) - mu)*rs*g[d] + bt[d];
        float zv = zp[(size_t)d*LL];
        float sg = 1.f / (1.f + __expf(-zv));
        yp1[(size_t)d*LL] = v * (zv * sg);
    }
}

extern "C" void kernel_launch(void* const* d_in, const int* in_sizes, int n_in,
                              void* d_out, int out_size, void* d_ws, size_t ws_size,
                              hipStream_t stream)
{
    (void)in_sizes; (void)n_in; (void)out_size; (void)ws_size;
    const float* x     = (const float*)d_in[0];
    const float* low   = (const float*)d_in[1];
    const float* ln_g  = (const float*)d_in[2];
    const float* ln_b  = (const float*)d_in[3];
    const float* w_in  = (const float*)d_in[4];
    const float* w_low = (const float*)d_in[5];
    const float* w_c2d = (const float*)d_in[6];
    const float* b_c2d = (const float*)d_in[7];
    const float* w_xp  = (const float*)d_in[8];
    const float* w_xpl = (const float*)d_in[9];
    const float* w_cdt = (const float*)d_in[10];
    const float* w_cB  = (const float*)d_in[11];
    const float* w_cC  = (const float*)d_in[12];
    const float* sgb1  = (const float*)d_in[13];
    const float* sgb2  = (const float*)d_in[14];
    const float* sgc1  = (const float*)d_in[15];
    const float* sgc2  = (const float*)d_in[16];
    const float* dtw   = (const float*)d_in[17];
    const float* dtb   = (const float*)d_in[18];
    const float* Alogs = (const float*)d_in[19];
    const float* Ds    = (const float*)d_in[20];
    const float* ong   = (const float*)d_in[21];
    const float* onb   = (const float*)d_in[22];
    const float* w_out = (const float*)d_in[23];
    float* ws  = (float*)d_ws;
    float* out = (float*)d_out;
    dim3 blk(256);

    // bf16 plane aliases
    ushort_t* wInH  = (ushort_t*)(ws + O_WT_IN);   ushort_t* wInL  = wInH + 147456;
    ushort_t* wLowH = (ushort_t*)(ws + O_WT_LOW);  ushort_t* wLowL = wLowH + 73728;
    ushort_t* wOutH = (ushort_t*)(ws + O_WT_OUT);  ushort_t* wOutL = wOutH + 73728;
    ushort_t* wXpH  = (ushort_t*)(ws + O_WT_XP);   ushort_t* wXpL  = wXpH + 24576;
    ushort_t* wXplH = (ushort_t*)(ws + O_WT_XPL);  ushort_t* wXplL = wXplH + 24576;
    ushort_t* xnh   = (ushort_t*)(ws + O_XN);      ushort_t* xnl   = xnh + 3145728;
    ushort_t* lowh  = (ushort_t*)(ws + O_LOWT);    ushort_t* lowl  = lowh + 3145728;

    prep_kernel<<<3664, blk, 0, stream>>>(w_in, wInH, wInL, w_low, wLowH, wLowL,
                                          w_out, wOutH, wOutL,
                                          w_xp, wXpH, wXpL, w_xpl, wXplH, wXplL,
                                          x, ln_g, ln_b, xnh, xnl, low, lowh, lowl);

    gemm_inlow<<<dim3(128,18), blk, 0, stream>>>(xnh, xnl, wInH, wInL,
                                                 lowh, lowl, wLowH, wLowL,
                                                 ws+O_XH, ws+O_Z, ws+O_LOWP);

    conv2d_silu_kernel<<<dim3(16,384,4), blk, 0, stream>>>(ws+O_XH, w_c2d, b_c2d, ws+O_XS);

    gemm_cmaj<1,3,1><<<dim3(128,1,2), blk, 0, stream>>>(ws+O_XS, ws+O_LOWP,
                                                        wXpH, wXpL, wXplH, wXplL,
                                                        nullptr, ws+O_DBCH, ws+O_DBCL, NCH);

    gates_kernel<<<dim3(64,4,2), blk, 0, stream>>>(ws+O_DBCH, ws+O_DBCL, sgb1, sgb2, sgc1, sgc2, ws+O_DBC);

    conv_dbc_kernel<<<dim3(16,44,4), blk, 0, stream>>>(ws+O_DBC, w_cdt, w_cB, w_cC,
                                                       ws+O_DTS, ws+O_BS, ws+O_CS);
    delta_kernel<<<dim3(32,6,4), blk, 0, stream>>>(ws+O_DTS, dtw, dtb, ws+O_DELTA);

    scan_kernel<<<3072, blk, 0, stream>>>(ws+O_XS, ws+O_DELTA, ws+O_BS, ws+O_CS, Alogs, Ds,
                                          ws+O_Y, ws+O_Y1);

    outnorm_gate_kernel<<<dim3(64,4), dim3(1024), 0, stream>>>(ws+O_Y, ws+O_Y1, ws+O_Z, ong, onb);

    gemm_cmaj<2,1,0><<<dim3(128,3,1), blk, 0, stream>>>(ws+O_Y1, nullptr,
                                                        wOutH, wOutL, nullptr, nullptr,
                                                        x, out, nullptr, CM);
}

// Round 14
// 235.077 us; speedup vs baseline: 1.4005x; 1.1035x over previous
//
#include <hip/hip_runtime.h>
#include <math.h>

#define LL 4096
#define NBATCH 4
#define CM 192
#define DI 384
#define NST 16
#define RK 12
#define NCH 44
#define SGH 96

typedef unsigned short ushort_t;
typedef __attribute__((ext_vector_type(8))) short bf16x8;
typedef __attribute__((ext_vector_type(4))) float f32x4;
typedef __attribute__((ext_vector_type(8))) unsigned short ushort8;
typedef __attribute__((ext_vector_type(4))) unsigned short ushort4v;

// workspace offsets (float units)
#define O_WT_IN   0
#define O_WT_LOW  147456
#define O_WT_XP   221184
#define O_WT_XPL  245760
#define O_WT_OUT  270336
#define O_XN      344064
#define O_LOWT    3489792
#define O_XH      6635520
#define O_Z       12926976
#define O_LOWP    19218432
#define O_XS      25509888
#define O_DBCH    31801344
#define O_DBCL    32522240
#define O_DBC     33243136
#define O_BS      33964032
#define O_CS      34226176
#define O_DELTA   O_LOWP   // lowp dead after x_proj GEMMs
#define O_Y       O_XH     // xh dead after conv2d
#define O_Y1      O_XN     // xn/lowt bf16 planes dead after in/low GEMMs
#define O_DTS     O_DBCH   // dbcH dead after gates_kernel

__device__ __forceinline__ ushort_t f2bf(float v) {
    unsigned u = __float_as_uint(v);
    return (ushort_t)((u + 0x7FFFu + ((u >> 16) & 1u)) >> 16);
}
__device__ __forceinline__ float bf2f(ushort_t h) {
    return __uint_as_float(((unsigned)h) << 16);
}

// ---- chunk-transposed ("perm") layout within each 4096-element row ----------
__device__ __forceinline__ int permidx(int l) {
    return ((l >> 2) & 3) * 1024 + ((l >> 4) << 2) + (l & 3);
}

#define LD16P(dst, row, t4) { \
  float4 _a = *(const float4*)((row) + (t4)); \
  float4 _b = *(const float4*)((row) + 1024 + (t4)); \
  float4 _c = *(const float4*)((row) + 2048 + (t4)); \
  float4 _d = *(const float4*)((row) + 3072 + (t4)); \
  dst[0]=_a.x; dst[1]=_a.y; dst[2]=_a.z; dst[3]=_a.w; \
  dst[4]=_b.x; dst[5]=_b.y; dst[6]=_b.z; dst[7]=_b.w; \
  dst[8]=_c.x; dst[9]=_c.y; dst[10]=_c.z; dst[11]=_c.w; \
  dst[12]=_d.x; dst[13]=_d.y; dst[14]=_d.z; dst[15]=_d.w; }

// -------- merged prep: weight splits (bx<336) + LN/act splits (bx>=336) -------
__global__ __launch_bounds__(256) void prep_kernel(
    const float* __restrict__ i0, ushort_t* h0, ushort_t* l0_,
    const float* __restrict__ i1, ushort_t* h1, ushort_t* l1,
    const float* __restrict__ i2, ushort_t* h2, ushort_t* l2,
    const float* __restrict__ p0, ushort_t* ph0, ushort_t* pl0,
    const float* __restrict__ p1, ushort_t* ph1, ushort_t* pl1,
    const float* __restrict__ X, const float* __restrict__ gw, const float* __restrict__ bw,
    ushort_t* __restrict__ oh, ushort_t* __restrict__ ol,
    const float* __restrict__ LOW, ushort_t* __restrict__ lh, ushort_t* __restrict__ llo)
{
    __shared__ float xt[64][193];
    __shared__ float reds[64][4], redq[64][4];
    __shared__ float mu_s[64], rs_s[64];
    int bx = blockIdx.x;
    int tid = threadIdx.x;
    if (bx < 288) {
        const float* in; ushort_t* oh_; ushort_t* ol_; int base;
        if (bx < 144)      { in = i0; oh_ = h0; ol_ = l0_; base = bx * 1024; }
        else if (bx < 216) { in = i1; oh_ = h1; ol_ = l1;  base = (bx-144) * 1024; }
        else               { in = i2; oh_ = h2; ol_ = l2;  base = (bx-216) * 1024; }
        int i = base + tid * 4;
        float4 v = *(const float4*)&in[i];
        ushort4v h, l;
        h.x = f2bf(v.x); l.x = f2bf(v.x - bf2f(h.x));
        h.y = f2bf(v.y); l.y = f2bf(v.y - bf2f(h.y));
        h.z = f2bf(v.z); l.z = f2bf(v.z - bf2f(h.z));
        h.w = f2bf(v.w); l.w = f2bf(v.w - bf2f(h.w));
        *(ushort4v*)&oh_[i] = h;
        *(ushort4v*)&ol_[i] = l;
        return;
    }
    if (bx < 336) {
        int bb = bx - 288;
        int sel = bb / 24, bxx = bb % 24;
        const float* in = sel ? p1 : p0;
        ushort_t* oh_ = sel ? ph1 : ph0;
        ushort_t* ol_ = sel ? pl1 : pl0;
        int idx = (bxx * 256 + tid) * 4;
        int n = idx / 384;
        float4 v = (n < NCH) ? *(const float4*)&in[idx] : make_float4(0.f,0.f,0.f,0.f);
        ushort4v h, l;
        h.x = f2bf(v.x); l.x = f2bf(v.x - bf2f(h.x));
        h.y = f2bf(v.y); l.y = f2bf(v.y - bf2f(h.y));
        h.z = f2bf(v.z); l.z = f2bf(v.z - bf2f(h.z));
        h.w = f2bf(v.w); l.w = f2bf(v.w - bf2f(h.w));
        *(ushort4v*)&oh_[idx] = h;
        *(ushort4v*)&ol_[idx] = l;
        return;
    }
    int ax = bx - 336;
    if (ax >= 256) {
        int i = ((ax - 256) * 256 + tid) * 4;
        float4 v = *(const float4*)&LOW[i];
        ushort4v h, l;
        h.x = f2bf(v.x); l.x = f2bf(v.x - bf2f(h.x));
        h.y = f2bf(v.y); l.y = f2bf(v.y - bf2f(h.y));
        h.z = f2bf(v.z); l.z = f2bf(v.z - bf2f(h.z));
        h.w = f2bf(v.w); l.w = f2bf(v.w - bf2f(h.w));
        *(ushort4v*)&lh[i] = h;
        *(ushort4v*)&llo[i] = l;
        return;
    }
    int t0 = ax * 64;
    const float* Xb = X + (size_t)t0 * CM;
#pragma unroll
    for (int i = 0; i < 12; i++) {
        int f4 = tid + 256 * i;
        float4 v = *(const float4*)&Xb[f4 * 4];
        int row = f4 / 48, c = (f4 % 48) * 4;
        xt[row][c] = v.x; xt[row][c+1] = v.y; xt[row][c+2] = v.z; xt[row][c+3] = v.w;
    }
    __syncthreads();
    int tok = tid & 63, p = tid >> 6;
    float s = 0.f, q = 0.f;
#pragma unroll 8
    for (int i = 0; i < 48; i++) { float v = xt[tok][p*48+i]; s += v; q = fmaf(v, v, q); }
    reds[tok][p] = s; redq[tok][p] = q;
    __syncthreads();
    if (tid < 64) {
        float ss = reds[tid][0]+reds[tid][1]+reds[tid][2]+reds[tid][3];
        float qq = redq[tid][0]+redq[tid][1]+redq[tid][2]+redq[tid][3];
        float mu = ss * (1.f/CM);
        float var = qq * (1.f/CM) - mu*mu;
        mu_s[tid] = mu; rs_s[tid] = rsqrtf(var + 1e-5f);
    }
    __syncthreads();
    int tok2 = tid >> 2, c0 = (tid & 3) * 48;
    float mu = mu_s[tok2], rs = rs_s[tok2];
    size_t tb = (size_t)(t0 + tok2) * CM;
#pragma unroll 8
    for (int i = 0; i < 48; i++) {
        int c = c0 + i;
        float v = (xt[tok2][c] - mu) * rs * gw[c] + bw[c];
        ushort_t h = f2bf(v);
        oh[tb + c] = h;
        ol[tb + c] = f2bf(v - bf2f(h));
    }
}

// -------- merged in_proj + low_proj split-bf16 MFMA GEMM, 128x128 tiles -------
__global__ __launch_bounds__(256) void gemm_inlow(
    const ushort_t* __restrict__ xnh, const ushort_t* __restrict__ xnl,
    const ushort_t* __restrict__ wInH, const ushort_t* __restrict__ wInL,
    const ushort_t* __restrict__ lowh, const ushort_t* __restrict__ lowl,
    const ushort_t* __restrict__ wLowH, const ushort_t* __restrict__ wLowL,
    float* __restrict__ xh, float* __restrict__ z, float* __restrict__ lowp)
{
    __shared__ __align__(16) char smem[32768];
    ushort_t* sAh = (ushort_t*)smem;        // [4][128][8]
    ushort_t* sAl = sAh + 4096;
    ushort_t* sWh = sAh + 8192;             // [4][128][8]
    ushort_t* sWl = sAh + 12288;
    const int KDIM = 192;
    int tid = threadIdx.x;
    int t0 = blockIdx.x * 128;
    int b = t0 >> 12, l0 = t0 & 4095;
    int ysel = blockIdx.y;
    bool isLow = ysel >= 6;
    int n0 = (isLow ? (ysel - 6) : ysel) * 128;
    const ushort_t* Ahi = isLow ? lowh : xnh;
    const ushort_t* Alo = isLow ? lowl : xnl;
    const ushort_t* Whi = isLow ? wLowH : wInH;
    const ushort_t* Wlo = isLow ? wLowL : wInL;
    int arow = tid >> 1, kgA = (tid & 1) * 2;
    const ushort_t* gAh = Ahi + (size_t)(t0 + arow) * KDIM + kgA * 8;
    const ushort_t* gAl = Alo + (size_t)(t0 + arow) * KDIM + kgA * 8;
    const ushort_t* gWh = Whi + (size_t)(n0 + arow) * KDIM + kgA * 8;
    const ushort_t* gWl = Wlo + (size_t)(n0 + arow) * KDIM + kgA * 8;
    int lane = tid & 63, w = tid >> 6;
    int ln = lane & 15, kg = lane >> 4;
    int am0 = w * 32 + ln;
    f32x4 acc[2][8];
#pragma unroll
    for (int mf = 0; mf < 2; mf++)
#pragma unroll
        for (int nf = 0; nf < 8; nf++) acc[mf][nf] = (f32x4){0.f, 0.f, 0.f, 0.f};

    for (int k0 = 0; k0 < KDIM; k0 += 32) {
        __syncthreads();
        {
            ushort8 a0 = *(const ushort8*)(gAh + k0);
            ushort8 a1 = *(const ushort8*)(gAh + k0 + 8);
            *(ushort8*)(sAh + kgA*1024 + arow*8) = a0;
            *(ushort8*)(sAh + (kgA+1)*1024 + arow*8) = a1;
            ushort8 b0 = *(const ushort8*)(gAl + k0);
            ushort8 b1 = *(const ushort8*)(gAl + k0 + 8);
            *(ushort8*)(sAl + kgA*1024 + arow*8) = b0;
            *(ushort8*)(sAl + (kgA+1)*1024 + arow*8) = b1;
            ushort8 w0 = *(const ushort8*)(gWh + k0);
            ushort8 w1 = *(const ushort8*)(gWh + k0 + 8);
            *(ushort8*)(sWh + kgA*1024 + arow*8) = w0;
            *(ushort8*)(sWh + (kgA+1)*1024 + arow*8) = w1;
            ushort8 w2 = *(const ushort8*)(gWl + k0);
            ushort8 w3 = *(const ushort8*)(gWl + k0 + 8);
            *(ushort8*)(sWl + kgA*1024 + arow*8) = w2;
            *(ushort8*)(sWl + (kgA+1)*1024 + arow*8) = w3;
        }
        __syncthreads();
        bf16x8 aH[2], aL[2];
#pragma unroll
        for (int mf = 0; mf < 2; mf++) {
            aH[mf] = *(const bf16x8*)(sAh + kg*1024 + (am0 + mf*16)*8);
            aL[mf] = *(const bf16x8*)(sAl + kg*1024 + (am0 + mf*16)*8);
        }
#pragma unroll
        for (int half = 0; half < 2; half++) {
            bf16x8 bH[4], bL[4];
#pragma unroll
            for (int n4 = 0; n4 < 4; n4++) {
                int nr = (half*4 + n4)*16 + ln;
                bH[n4] = *(const bf16x8*)(sWh + kg*1024 + nr*8);
                bL[n4] = *(const bf16x8*)(sWl + kg*1024 + nr*8);
            }
#pragma unroll
            for (int mf = 0; mf < 2; mf++)
#pragma unroll
                for (int n4 = 0; n4 < 4; n4++) {
                    int nf = half*4 + n4;
                    acc[mf][nf] = __builtin_amdgcn_mfma_f32_16x16x32_bf16(aH[mf], bH[n4], acc[mf][nf], 0, 0, 0);
                    acc[mf][nf] = __builtin_amdgcn_mfma_f32_16x16x32_bf16(aH[mf], bL[n4], acc[mf][nf], 0, 0, 0);
                    acc[mf][nf] = __builtin_amdgcn_mfma_f32_16x16x32_bf16(aL[mf], bH[n4], acc[mf][nf], 0, 0, 0);
                }
        }
    }
    // direct stores: f32x4 over j = 4 consecutive l
#pragma unroll
    for (int mf = 0; mf < 2; mf++) {
        int l = l0 + w*32 + mf*16 + kg*4;
#pragma unroll
        for (int nf = 0; nf < 8; nf++) {
            int n = n0 + nf*16 + ln;
            float* dst;
            if (!isLow) {
                dst = (n < DI) ? (xh + ((size_t)b*DI + n)*LL + l)
                               : (z  + ((size_t)b*DI + (n - DI))*LL + l);
            } else {
                dst = lowp + ((size_t)b*DI + n)*LL + l;
            }
            *(f32x4*)dst = acc[mf][nf];
        }
    }
}

// -------- channel-major-A MFMA GEMM, 64-token tiles, direct stores ------------
template<int MODE, int SPLIT, int PERM0>
__global__ __launch_bounds__(256) void gemm_cmaj(
    const float* __restrict__ A0, const float* __restrict__ A1,
    const ushort_t* __restrict__ W0h, const ushort_t* __restrict__ W0l,
    const ushort_t* __restrict__ W1h, const ushort_t* __restrict__ W1l,
    const float* __restrict__ resid,
    float* __restrict__ o0, float* __restrict__ o1, int Nreal)
{
    __shared__ __align__(16) float sA[32*68];       // [32][68]
    __shared__ __align__(16) ushort_t sWh[4*64*8];  // [4][64][8]
    __shared__ __align__(16) ushort_t sWl[4*64*8];
    bool sel = (blockIdx.z == 1);
    const float* A = sel ? A1 : A0;
    const ushort_t* Wh = sel ? W1h : W0h;
    const ushort_t* Wl = sel ? W1l : W0l;
    float* out0 = sel ? o1 : o0;
    const bool perm = sel ? false : (PERM0 != 0);
    int tid = threadIdx.x;
    int t0 = blockIdx.x * 64;
    int b = t0 >> 12, l0 = t0 & 4095;
    int n0 = blockIdx.y * 64;
    const float* Ab = A + (size_t)b * 384 * LL;
    int wrow = tid >> 2, kgW = tid & 3;
    int lane = tid & 63, w = tid >> 6;
    int ln = lane & 15, kg = lane >> 4;
    int am0 = w * 16 + ln;
    f32x4 acc[4];
#pragma unroll
    for (int nf = 0; nf < 4; nf++) acc[nf] = (f32x4){0.f, 0.f, 0.f, 0.f};

    for (int k0 = 0; k0 < 384; k0 += 32) {
        __syncthreads();
#pragma unroll
        for (int i = 0; i < 2; i++) {
            int idx = tid + 256*i;
            int row = idx >> 4, ch = idx & 15;
            int m = ch * 4;
            int src = perm ? (((m >> 2) & 3) * 1024 + (((l0 + m) >> 4) << 2))
                           : (l0 + m);
            float4 v = *(const float4*)&Ab[(size_t)(k0 + row)*LL + src];
            *(float4*)&sA[row*68 + m] = v;
        }
        {
            ushort8 wv = *(const ushort8*)(Wh + (size_t)(n0 + wrow)*384 + k0 + kgW*8);
            *(ushort8*)(sWh + kgW*512 + wrow*8) = wv;
            if (SPLIT == 3) {
                ushort8 wl = *(const ushort8*)(Wl + (size_t)(n0 + wrow)*384 + k0 + kgW*8);
                *(ushort8*)(sWl + kgW*512 + wrow*8) = wl;
            }
        }
        __syncthreads();
        bf16x8 aH, aL;
#pragma unroll
        for (int e = 0; e < 8; e++) {
            float v = sA[(kg*8 + e)*68 + am0];
            ushort_t h = f2bf(v);
            aH[e] = (short)h;
            if (SPLIT == 3) aL[e] = (short)f2bf(v - bf2f(h));
        }
        bf16x8 bH[4], bL[4];
#pragma unroll
        for (int nf = 0; nf < 4; nf++) {
            bH[nf] = *(const bf16x8*)(sWh + kg*512 + (nf*16 + ln)*8);
            if (SPLIT == 3) bL[nf] = *(const bf16x8*)(sWl + kg*512 + (nf*16 + ln)*8);
        }
#pragma unroll
        for (int nf = 0; nf < 4; nf++) {
            acc[nf] = __builtin_amdgcn_mfma_f32_16x16x32_bf16(aH, bH[nf], acc[nf], 0, 0, 0);
            if (SPLIT == 3) {
                acc[nf] = __builtin_amdgcn_mfma_f32_16x16x32_bf16(aH, bL[nf], acc[nf], 0, 0, 0);
                acc[nf] = __builtin_amdgcn_mfma_f32_16x16x32_bf16(aL, bH[nf], acc[nf], 0, 0, 0);
            }
        }
    }

    if (MODE == 2) {
#pragma unroll
        for (int j = 0; j < 4; j++) {
            int t = t0 + w*16 + kg*4 + j;
#pragma unroll
            for (int nf = 0; nf < 4; nf++) {
                int n = n0 + nf*16 + ln;
                out0[(size_t)t*CM + n] = resid[(size_t)t*CM + n] + acc[nf][j];
            }
        }
    } else {
        int l = l0 + w*16 + kg*4;
#pragma unroll
        for (int nf = 0; nf < 4; nf++) {
            int n = n0 + nf*16 + ln;
            if (n < Nreal)
                *(f32x4*)(out0 + ((size_t)b*Nreal + n)*LL + l) = acc[nf];
        }
    }
}

// -------- depthwise 3x3 conv + bias + SiLU -> xs in PERM layout ---------------
__global__ __launch_bounds__(256) void conv2d_silu_kernel(const float* __restrict__ xh,
    const float* __restrict__ w, const float* __restrict__ bias, float* __restrict__ xs)
{
    int tid = threadIdx.x;
    int l = blockIdx.x * 256 + tid;
    int c = blockIdx.y, b = blockIdx.z;
    const float* P = xh + ((size_t)b*DI + c)*LL;
    int h = l >> 6, ww = l & 63;
    float acc = bias[c];
#pragma unroll
    for (int kh = 0; kh < 3; kh++) {
        int hh = h + kh - 1;
        if ((unsigned)hh < 64u) {
#pragma unroll
            for (int kw = 0; kw < 3; kw++) {
                int wv = ww + kw - 1;
                if ((unsigned)wv < 64u) acc = fmaf(w[c*9 + kh*3 + kw], P[hh*64 + wv], acc);
            }
        }
    }
    float sg = 1.f / (1.f + __expf(-acc));
    xs[((size_t)b*DI + c)*LL + permidx(l)] = acc * sg;
}

// -------- SimpleGates on low B/C + sum high+low -> dbc [B][44][L] -------------
__global__ __launch_bounds__(256) void gates_kernel(const float* __restrict__ dbcH,
    const float* __restrict__ dbcL,
    const float* __restrict__ sgb1, const float* __restrict__ sgb2,
    const float* __restrict__ sgc1, const float* __restrict__ sgc2,
    float* __restrict__ dbc)
{
    __shared__ float w1[192*16];
    __shared__ float w2[16*96];
    __shared__ float red[4][16][64];
    int tid = threadIdx.x;
    int gate = blockIdx.z;
    const float* g1 = gate ? sgc1 : sgb1;
    const float* g2 = gate ? sgc2 : sgb2;
    for (int i = tid; i < 192*16; i += 256) w1[i] = g1[i];
    for (int i = tid; i < 16*96;  i += 256) w2[i] = g2[i];
    int lq = tid & 63, p = tid >> 6;
    int l = blockIdx.x * 64 + lq;
    int b = blockIdx.y;
    size_t pb_ = (size_t)b*NCH*LL + l;
    __syncthreads();
    if (!gate) {
#pragma unroll
        for (int i = 0; i < 3; i++) {
            int c = p*3 + i;
            dbc[pb_ + (size_t)c*LL] = dbcH[pb_ + (size_t)c*LL] + dbcL[pb_ + (size_t)c*LL];
        }
    }
    int coff = RK + gate*NST;
    float xin[16], og[16];
#pragma unroll
    for (int n = 0; n < 16; n++) { xin[n] = dbcL[pb_ + (size_t)(coff+n)*LL]; og[n] = 0.f; }
    int h0 = p * 24;
    for (int h = h0; h < h0 + 24; h++) {
        float ya = 0.f, yb = 0.f;
#pragma unroll
        for (int n = 0; n < 16; n++) {
            ya = fmaf(w1[h*16+n], xin[n], ya);
            yb = fmaf(w1[(h+SGH)*16+n], xin[n], yb);
        }
        float gg = 0.5f * ya * (1.f + erff(ya * 0.70710678f)) * yb;
#pragma unroll
        for (int n = 0; n < 16; n++) og[n] = fmaf(w2[n*SGH+h], gg, og[n]);
    }
#pragma unroll
    for (int n = 0; n < 16; n++) red[p][n][lq] = og[n];
    __syncthreads();
#pragma unroll
    for (int i = 0; i < 4; i++) {
        int n = p*4 + i;
        float v = red[0][n][lq] + red[1][n][lq] + red[2][n][lq] + red[3][n][lq];
        dbc[pb_ + (size_t)(coff+n)*LL] = dbcH[pb_ + (size_t)(coff+n)*LL] + v;
    }
}

// -------- residual dilated dwconv1d: dts normal; Bs/Cs in PERM layout ---------
__global__ __launch_bounds__(256) void conv_dbc_kernel(const float* __restrict__ dbc,
    const float* __restrict__ wdt, const float* __restrict__ wB, const float* __restrict__ wC,
    float* __restrict__ dts, float* __restrict__ Bs, float* __restrict__ Cs)
{
    int l = blockIdx.x * 256 + threadIdx.x;
    int c = blockIdx.y, b = blockIdx.z;
    const float* wsrc = (c < RK) ? (wdt + c*15)
                      : (c < RK+NST ? wB + (c-RK)*15 : wC + (c-RK-NST)*15);
    float w[15];
#pragma unroll
    for (int k = 0; k < 15; k++) w[k] = wsrc[k];
    const float* P = dbc + ((size_t)b*NCH + c)*LL;
    float a = P[l];
#pragma unroll
    for (int k = 0; k < 15; k++) {
        int lt = l + 2*k - 14;
        if ((unsigned)lt < (unsigned)LL) a = fmaf(w[k], P[lt], a);
    }
    if (c < RK)            dts[((size_t)b*RK  + c)*LL + l] = a;
    else if (c < RK+NST)   Bs [((size_t)b*NST + (c-RK))*LL + permidx(l)] = a;
    else                   Cs [((size_t)b*NST + (c-RK-NST))*LL + permidx(l)] = a;
}

// -------- delta projection + softplus -> delta in PERM layout -----------------
__global__ __launch_bounds__(256) void delta_kernel(const float* __restrict__ dts,
    const float* __restrict__ dtw, const float* __restrict__ dtb, float* __restrict__ delta)
{
    __shared__ float sdt[RK][128];
    __shared__ float sw[64][RK];
    int tid = threadIdx.x;
    int l0 = blockIdx.x * 128, d0 = blockIdx.y * 64, b = blockIdx.z;
    for (int i = tid; i < RK*128; i += 256) {
        int r = i >> 7, lq = i & 127;
        sdt[r][lq] = dts[((size_t)b*RK + r)*LL + l0 + lq];
    }
    for (int i = tid; i < 64*RK; i += 256) {
        int dq = i / RK, r = i - dq*RK;
        sw[dq][r] = dtw[(size_t)(d0+dq)*RK + r];
    }
    __syncthreads();
    int lq = tid & 63, g = tid >> 6;
    for (int dd = 0; dd < 16; dd++) {
        int dqq = g*16 + dd, d = d0 + dqq;
        float wr[RK];
#pragma unroll
        for (int r = 0; r < RK; r++) wr[r] = sw[dqq][r];
        float bias = dtb[d];
#pragma unroll
        for (int li = 0; li < 2; li++) {
            int lloc = lq + li*64;
            float s = bias;
#pragma unroll
            for (int r = 0; r < RK; r++) s = fmaf(wr[r], sdt[r][lloc], s);
            float sp = fmaxf(s, 0.f) + __logf(1.f + __expf(-fabsf(s)));
            delta[((size_t)b*DI + d)*LL + permidx(l0 + lloc)] = sp;
        }
    }
}

// -------- selective scan v4 (measured best): half-split + deferred fixup ------
__global__ __launch_bounds__(256) void scan_kernel(
    const float* __restrict__ u_, const float* __restrict__ delta_,
    const float* __restrict__ Bs_, const float* __restrict__ Cs_,
    const float* __restrict__ Alogs, const float* __restrict__ Ds,
    float* __restrict__ y0_, float* __restrict__ y1_)
{
    __shared__ float wAs[8][4], wBs[8][4];
    __shared__ float yt[16][258];
    int tid = threadIdx.x;
    int t4 = tid * 4;
    int bid = blockIdx.x;
    int half = bid & 1, bd = bid >> 1;
    int b = bd / DI, d = bd % DI;
    int n0 = half * 8;
    size_t rowoff = ((size_t)b*DI + d)*LL;
    float dl[16], du[16], yac[16];
    LD16P(du, u_ + rowoff, t4);
    LD16P(dl, delta_ + rowoff, t4);
    float Dd = Ds[d];
#pragma unroll
    for (int s = 0; s < 16; s++) {
        yac[s] = half ? 0.f : du[s]*Dd;
        du[s] = dl[s]*du[s];
    }
    int lane = tid & 63, w = tid >> 6;
#pragma unroll 1
    for (int j = 0; j < 8; j++) {
        float An = -__expf(Alogs[d*NST + n0 + j]);
        float Bn[16], Cn[16], t[16];
        LD16P(Bn, Bs_ + ((size_t)b*NST + n0 + j)*LL, t4);
        LD16P(Cn, Cs_ + ((size_t)b*NST + n0 + j)*LL, t4);
        float a = 1.f, h = 0.f;
#pragma unroll
        for (int s = 0; s < 16; s++) {
            float e = __expf(dl[s]*An);
            a *= e;
            h = fmaf(e, h, du[s]*Bn[s]);
            yac[s] = fmaf(Cn[s], h, yac[s]);
            t[s] = Cn[s]*a;
        }
        float ap = a, hv = h;
        for (int off = 1; off < 64; off <<= 1) {
            float pa = __shfl_up(ap, (unsigned)off, 64);
            float pb = __shfl_up(hv, (unsigned)off, 64);
            if (lane >= off) { hv = fmaf(ap, pb, hv); ap *= pa; }
        }
        if (lane == 63) { wAs[j][w] = ap; wBs[j][w] = hv; }
        __syncthreads();
        float PB = 0.f;
        for (int ww = 0; ww < w; ww++) PB = fmaf(wAs[j][ww], PB, wBs[j][ww]);
        hv = fmaf(ap, PB, hv);
        float tt = __shfl_up(hv, 1u, 64);
        float hin = lane ? tt : PB;
#pragma unroll
        for (int s = 0; s < 16; s++) yac[s] = fmaf(t[s], hin, yac[s]);
    }
#pragma unroll
    for (int i = 0; i < 16; i++) yt[i][tid] = yac[i];
    __syncthreads();
    float* yout = (half ? y1_ : y0_) + rowoff;
#pragma unroll
    for (int r = 0; r < 16; r++)
        yout[r*256 + tid] = yt[tid & 15][r*16 + (tid >> 4)];
}

// -------- out-norm LN(384) on y0+y1 + z-SiLU gating (in-place over y1) --------
__global__ __launch_bounds__(1024) void outnorm_gate_kernel(const float* __restrict__ y0,
    float* y1g, const float* __restrict__ z,
    const float* __restrict__ g, const float* __restrict__ bt)
{
    __shared__ float rs_[16][64], rq_[16][64];
    __shared__ float mu_s[64], rstd_s[64];
    int tid = threadIdx.x;
    int lq = tid & 63, p = tid >> 6;          // p in 0..15
    int l = blockIdx.x * 64 + lq;
    int b = blockIdx.y;
    const float* yp0 = y0 + (size_t)b*DI*LL + l;
    float* yp1 = y1g + (size_t)b*DI*LL + l;
    float s = 0.f, q = 0.f;
#pragma unroll 4
    for (int i = 0; i < 24; i++) {
        int d = p*24 + i;
        float v = yp0[(size_t)d*LL] + yp1[(size_t)d*LL];
        s += v; q = fmaf(v, v, q);
    }
    rs_[p][lq] = s; rq_[p][lq] = q;
    __syncthreads();
    if (p == 0) {
        float ss = 0.f, qq = 0.f;
#pragma unroll
        for (int i = 0; i < 16; i++) { ss += rs_[i][lq]; qq += rq_[i][lq]; }
        float mu = ss * (1.f/DI);
        float var = qq * (1.f/DI) - mu*mu;
        mu_s[lq] = mu; rstd_s[lq] = rsqrtf(var + 1e-5f);
    }
    __syncthreads();
    float mu = mu_s[lq], rs = rstd_s[lq];
    const float* zp = z + (size_t)b*DI*LL + l;
#pragma unroll 4
    for (int i = 0; i < 24; i++) {
        int d = p*24 + i;
        float v = ((yp0[(size_t)d*LL] + yp1[(size_t)d*LL]) - mu)*rs*g[d] + bt[d];
        float zv = zp[(size_t)d*LL];
        float sg = 1.f / (1.f + __expf(-zv));
        yp1[(size_t)d*LL] = v * (zv * sg);
    }
}

extern "C" void kernel_launch(void* const* d_in, const int* in_sizes, int n_in,
                              void* d_out, int out_size, void* d_ws, size_t ws_size,
                              hipStream_t stream)
{
    (void)in_sizes; (void)n_in; (void)out_size; (void)ws_size;
    const float* x     = (const float*)d_in[0];
    const float* low   = (const float*)d_in[1];
    const float* ln_g  = (const float*)d_in[2];
    const float* ln_b  = (const float*)d_in[3];
    const float* w_in  = (const float*)d_in[4];
    const float* w_low = (const float*)d_in[5];
    const float* w_c2d = (const float*)d_in[6];
    const float* b_c2d = (const float*)d_in[7];
    const float* w_xp  = (const float*)d_in[8];
    const float* w_xpl = (const float*)d_in[9];
    const float* w_cdt = (const float*)d_in[10];
    const float* w_cB  = (const float*)d_in[11];
    const float* w_cC  = (const float*)d_in[12];
    const float* sgb1  = (const float*)d_in[13];
    const float* sgb2  = (const float*)d_in[14];
    const float* sgc1  = (const float*)d_in[15];
    const float* sgc2  = (const float*)d_in[16];
    const float* dtw   = (const float*)d_in[17];
    const float* dtb   = (const float*)d_in[18];
    const float* Alogs = (const float*)d_in[19];
    const float* Ds    = (const float*)d_in[20];
    const float* ong   = (const float*)d_in[21];
    const float* onb   = (const float*)d_in[22];
    const float* w_out = (const float*)d_in[23];
    float* ws  = (float*)d_ws;
    float* out = (float*)d_out;
    dim3 blk(256);

    // bf16 plane aliases
    ushort_t* wInH  = (ushort_t*)(ws + O_WT_IN);   ushort_t* wInL  = wInH + 147456;
    ushort_t* wLowH = (ushort_t*)(ws + O_WT_LOW);  ushort_t* wLowL = wLowH + 73728;
    ushort_t* wOutH = (ushort_t*)(ws + O_WT_OUT);  ushort_t* wOutL = wOutH + 73728;
    ushort_t* wXpH  = (ushort_t*)(ws + O_WT_XP);   ushort_t* wXpL  = wXpH + 24576;
    ushort_t* wXplH = (ushort_t*)(ws + O_WT_XPL);  ushort_t* wXplL = wXplH + 24576;
    ushort_t* xnh   = (ushort_t*)(ws + O_XN);      ushort_t* xnl   = xnh + 3145728;
    ushort_t* lowh  = (ushort_t*)(ws + O_LOWT);    ushort_t* lowl  = lowh + 3145728;

    prep_kernel<<<3664, blk, 0, stream>>>(w_in, wInH, wInL, w_low, wLowH, wLowL,
                                          w_out, wOutH, wOutL,
                                          w_xp, wXpH, wXpL, w_xpl, wXplH, wXplL,
                                          x, ln_g, ln_b, xnh, xnl, low, lowh, lowl);

    gemm_inlow<<<dim3(128,9), blk, 0, stream>>>(xnh, xnl, wInH, wInL,
                                                lowh, lowl, wLowH, wLowL,
                                                ws+O_XH, ws+O_Z, ws+O_LOWP);

    conv2d_silu_kernel<<<dim3(16,384,4), blk, 0, stream>>>(ws+O_XH, w_c2d, b_c2d, ws+O_XS);

    gemm_cmaj<1,3,1><<<dim3(256,1,2), blk, 0, stream>>>(ws+O_XS, ws+O_LOWP,
                                                        wXpH, wXpL, wXplH, wXplL,
                                                        nullptr, ws+O_DBCH, ws+O_DBCL, NCH);

    gates_kernel<<<dim3(64,4,2), blk, 0, stream>>>(ws+O_DBCH, ws+O_DBCL, sgb1, sgb2, sgc1, sgc2, ws+O_DBC);

    conv_dbc_kernel<<<dim3(16,44,4), blk, 0, stream>>>(ws+O_DBC, w_cdt, w_cB, w_cC,
                                                       ws+O_DTS, ws+O_BS, ws+O_CS);
    delta_kernel<<<dim3(32,6,4), blk, 0, stream>>>(ws+O_DTS, dtw, dtb, ws+O_DELTA);

    scan_kernel<<<3072, blk, 0, stream>>>(ws+O_XS, ws+O_DELTA, ws+O_BS, ws+O_CS, Alogs, Ds,
                                          ws+O_Y, ws+O_Y1);

    outnorm_gate_kernel<<<dim3(64,4), dim3(1024), 0, stream>>>(ws+O_Y, ws+O_Y1, ws+O_Z, ong, onb);

    gemm_cmaj<2,1,0><<<dim3(256,3,1), blk, 0, stream>>>(ws+O_Y1, nullptr,
                                                        wOutH, wOutL, nullptr, nullptr,
                                                        x, out, nullptr, CM);
}

// Round 15
// 211.532 us; speedup vs baseline: 1.5564x; 1.1113x over previous
//
#include <hip/hip_runtime.h>
#include <math.h>

#define LL 4096
#define NBATCH 4
#define CM 192
#define DI 384
#define NST 16
#define RK 12
#define NCH 44
#define SGH 96

typedef unsigned short ushort_t;
typedef __attribute__((ext_vector_type(8))) short bf16x8;
typedef __attribute__((ext_vector_type(4))) float f32x4;
typedef __attribute__((ext_vector_type(8))) unsigned short ushort8;
typedef __attribute__((ext_vector_type(4))) unsigned short ushort4v;

// workspace offsets (float units)
#define O_WT_IN   0
#define O_WT_LOW  147456
#define O_WT_XP   221184
#define O_WT_XPL  245760
#define O_WT_OUT  270336
#define O_XN      344064
#define O_LOWT    3489792
#define O_XH      6635520
#define O_Z       12926976
#define O_LOWP    19218432
#define O_XS      25509888
#define O_DBCH    31801344
#define O_DBCL    32522240
#define O_DBC     33243136
#define O_BS      33964032
#define O_CS      34226176
#define O_DELTA   O_LOWP   // lowp dead after x_proj GEMMs
#define O_Y       O_XH     // xh (bf16) dead after conv2d
#define O_Y1      O_XN     // xn/lowt bf16 planes dead after in/low GEMMs
#define O_DTS     O_DBCH   // dbcH dead after gates_kernel

__device__ __forceinline__ ushort_t f2bf(float v) {
    unsigned u = __float_as_uint(v);
    return (ushort_t)((u + 0x7FFFu + ((u >> 16) & 1u)) >> 16);
}
__device__ __forceinline__ float bf2f(ushort_t h) {
    return __uint_as_float(((unsigned)h) << 16);
}

// ---- chunk-transposed ("perm") layout within each 4096-element row ----------
__device__ __forceinline__ int permidx(int l) {
    return ((l >> 2) & 3) * 1024 + ((l >> 4) << 2) + (l & 3);
}

#define LD16P(dst, row, t4) { \
  float4 _a = *(const float4*)((row) + (t4)); \
  float4 _b = *(const float4*)((row) + 1024 + (t4)); \
  float4 _c = *(const float4*)((row) + 2048 + (t4)); \
  float4 _d = *(const float4*)((row) + 3072 + (t4)); \
  dst[0]=_a.x; dst[1]=_a.y; dst[2]=_a.z; dst[3]=_a.w; \
  dst[4]=_b.x; dst[5]=_b.y; dst[6]=_b.z; dst[7]=_b.w; \
  dst[8]=_c.x; dst[9]=_c.y; dst[10]=_c.z; dst[11]=_c.w; \
  dst[12]=_d.x; dst[13]=_d.y; dst[14]=_d.z; dst[15]=_d.w; }

// -------- merged prep: weight splits (bx<336) + LN/act splits (bx>=336) -------
__global__ __launch_bounds__(256) void prep_kernel(
    const float* __restrict__ i0, ushort_t* h0, ushort_t* l0_,
    const float* __restrict__ i1, ushort_t* h1, ushort_t* l1,
    const float* __restrict__ i2, ushort_t* h2, ushort_t* l2,
    const float* __restrict__ p0, ushort_t* ph0, ushort_t* pl0,
    const float* __restrict__ p1, ushort_t* ph1, ushort_t* pl1,
    const float* __restrict__ X, const float* __restrict__ gw, const float* __restrict__ bw,
    ushort_t* __restrict__ oh, ushort_t* __restrict__ ol,
    const float* __restrict__ LOW, ushort_t* __restrict__ lh, ushort_t* __restrict__ llo)
{
    __shared__ float xt[64][193];
    __shared__ float reds[64][4], redq[64][4];
    __shared__ float mu_s[64], rs_s[64];
    int bx = blockIdx.x;
    int tid = threadIdx.x;
    if (bx < 288) {
        const float* in; ushort_t* oh_; ushort_t* ol_; int base;
        if (bx < 144)      { in = i0; oh_ = h0; ol_ = l0_; base = bx * 1024; }
        else if (bx < 216) { in = i1; oh_ = h1; ol_ = l1;  base = (bx-144) * 1024; }
        else               { in = i2; oh_ = h2; ol_ = l2;  base = (bx-216) * 1024; }
        int i = base + tid * 4;
        float4 v = *(const float4*)&in[i];
        ushort4v h, l;
        h.x = f2bf(v.x); l.x = f2bf(v.x - bf2f(h.x));
        h.y = f2bf(v.y); l.y = f2bf(v.y - bf2f(h.y));
        h.z = f2bf(v.z); l.z = f2bf(v.z - bf2f(h.z));
        h.w = f2bf(v.w); l.w = f2bf(v.w - bf2f(h.w));
        *(ushort4v*)&oh_[i] = h;
        *(ushort4v*)&ol_[i] = l;
        return;
    }
    if (bx < 336) {
        int bb = bx - 288;
        int sel = bb / 24, bxx = bb % 24;
        const float* in = sel ? p1 : p0;
        ushort_t* oh_ = sel ? ph1 : ph0;
        ushort_t* ol_ = sel ? pl1 : pl0;
        int idx = (bxx * 256 + tid) * 4;
        int n = idx / 384;
        float4 v = (n < NCH) ? *(const float4*)&in[idx] : make_float4(0.f,0.f,0.f,0.f);
        ushort4v h, l;
        h.x = f2bf(v.x); l.x = f2bf(v.x - bf2f(h.x));
        h.y = f2bf(v.y); l.y = f2bf(v.y - bf2f(h.y));
        h.z = f2bf(v.z); l.z = f2bf(v.z - bf2f(h.z));
        h.w = f2bf(v.w); l.w = f2bf(v.w - bf2f(h.w));
        *(ushort4v*)&oh_[idx] = h;
        *(ushort4v*)&ol_[idx] = l;
        return;
    }
    int ax = bx - 336;
    if (ax >= 256) {
        int i = ((ax - 256) * 256 + tid) * 4;
        float4 v = *(const float4*)&LOW[i];
        ushort4v h, l;
        h.x = f2bf(v.x); l.x = f2bf(v.x - bf2f(h.x));
        h.y = f2bf(v.y); l.y = f2bf(v.y - bf2f(h.y));
        h.z = f2bf(v.z); l.z = f2bf(v.z - bf2f(h.z));
        h.w = f2bf(v.w); l.w = f2bf(v.w - bf2f(h.w));
        *(ushort4v*)&lh[i] = h;
        *(ushort4v*)&llo[i] = l;
        return;
    }
    int t0 = ax * 64;
    const float* Xb = X + (size_t)t0 * CM;
#pragma unroll
    for (int i = 0; i < 12; i++) {
        int f4 = tid + 256 * i;
        float4 v = *(const float4*)&Xb[f4 * 4];
        int row = f4 / 48, c = (f4 % 48) * 4;
        xt[row][c] = v.x; xt[row][c+1] = v.y; xt[row][c+2] = v.z; xt[row][c+3] = v.w;
    }
    __syncthreads();
    int tok = tid & 63, p = tid >> 6;
    float s = 0.f, q = 0.f;
#pragma unroll 8
    for (int i = 0; i < 48; i++) { float v = xt[tok][p*48+i]; s += v; q = fmaf(v, v, q); }
    reds[tok][p] = s; redq[tok][p] = q;
    __syncthreads();
    if (tid < 64) {
        float ss = reds[tid][0]+reds[tid][1]+reds[tid][2]+reds[tid][3];
        float qq = redq[tid][0]+redq[tid][1]+redq[tid][2]+redq[tid][3];
        float mu = ss * (1.f/CM);
        float var = qq * (1.f/CM) - mu*mu;
        mu_s[tid] = mu; rs_s[tid] = rsqrtf(var + 1e-5f);
    }
    __syncthreads();
    int tok2 = tid >> 2, c0 = (tid & 3) * 48;
    float mu = mu_s[tok2], rs = rs_s[tok2];
    size_t tb = (size_t)(t0 + tok2) * CM;
#pragma unroll 8
    for (int i = 0; i < 48; i++) {
        int c = c0 + i;
        float v = (xt[tok2][c] - mu) * rs * gw[c] + bw[c];
        ushort_t h = f2bf(v);
        oh[tb + c] = h;
        ol[tb + c] = f2bf(v - bf2f(h));
    }
}

// -------- merged in_proj + low_proj split-bf16 MFMA GEMM, 128x128 tiles -------
// in_proj outputs xh/z as BF16 (feed conv2d and outnorm gate only).
__global__ __launch_bounds__(256) void gemm_inlow(
    const ushort_t* __restrict__ xnh, const ushort_t* __restrict__ xnl,
    const ushort_t* __restrict__ wInH, const ushort_t* __restrict__ wInL,
    const ushort_t* __restrict__ lowh, const ushort_t* __restrict__ lowl,
    const ushort_t* __restrict__ wLowH, const ushort_t* __restrict__ wLowL,
    ushort_t* __restrict__ xhb, ushort_t* __restrict__ zb, float* __restrict__ lowp)
{
    __shared__ __align__(16) char smem[32768];
    ushort_t* sAh = (ushort_t*)smem;        // [4][128][8]
    ushort_t* sAl = sAh + 4096;
    ushort_t* sWh = sAh + 8192;             // [4][128][8]
    ushort_t* sWl = sAh + 12288;
    const int KDIM = 192;
    int tid = threadIdx.x;
    int t0 = blockIdx.x * 128;
    int b = t0 >> 12, l0 = t0 & 4095;
    int ysel = blockIdx.y;
    bool isLow = ysel >= 6;
    int n0 = (isLow ? (ysel - 6) : ysel) * 128;
    const ushort_t* Ahi = isLow ? lowh : xnh;
    const ushort_t* Alo = isLow ? lowl : xnl;
    const ushort_t* Whi = isLow ? wLowH : wInH;
    const ushort_t* Wlo = isLow ? wLowL : wInL;
    int arow = tid >> 1, kgA = (tid & 1) * 2;
    const ushort_t* gAh = Ahi + (size_t)(t0 + arow) * KDIM + kgA * 8;
    const ushort_t* gAl = Alo + (size_t)(t0 + arow) * KDIM + kgA * 8;
    const ushort_t* gWh = Whi + (size_t)(n0 + arow) * KDIM + kgA * 8;
    const ushort_t* gWl = Wlo + (size_t)(n0 + arow) * KDIM + kgA * 8;
    int lane = tid & 63, w = tid >> 6;
    int ln = lane & 15, kg = lane >> 4;
    int am0 = w * 32 + ln;
    f32x4 acc[2][8];
#pragma unroll
    for (int mf = 0; mf < 2; mf++)
#pragma unroll
        for (int nf = 0; nf < 8; nf++) acc[mf][nf] = (f32x4){0.f, 0.f, 0.f, 0.f};

    for (int k0 = 0; k0 < KDIM; k0 += 32) {
        __syncthreads();
        {
            ushort8 a0 = *(const ushort8*)(gAh + k0);
            ushort8 a1 = *(const ushort8*)(gAh + k0 + 8);
            *(ushort8*)(sAh + kgA*1024 + arow*8) = a0;
            *(ushort8*)(sAh + (kgA+1)*1024 + arow*8) = a1;
            ushort8 b0 = *(const ushort8*)(gAl + k0);
            ushort8 b1 = *(const ushort8*)(gAl + k0 + 8);
            *(ushort8*)(sAl + kgA*1024 + arow*8) = b0;
            *(ushort8*)(sAl + (kgA+1)*1024 + arow*8) = b1;
            ushort8 w0 = *(const ushort8*)(gWh + k0);
            ushort8 w1 = *(const ushort8*)(gWh + k0 + 8);
            *(ushort8*)(sWh + kgA*1024 + arow*8) = w0;
            *(ushort8*)(sWh + (kgA+1)*1024 + arow*8) = w1;
            ushort8 w2 = *(const ushort8*)(gWl + k0);
            ushort8 w3 = *(const ushort8*)(gWl + k0 + 8);
            *(ushort8*)(sWl + kgA*1024 + arow*8) = w2;
            *(ushort8*)(sWl + (kgA+1)*1024 + arow*8) = w3;
        }
        __syncthreads();
        bf16x8 aH[2], aL[2];
#pragma unroll
        for (int mf = 0; mf < 2; mf++) {
            aH[mf] = *(const bf16x8*)(sAh + kg*1024 + (am0 + mf*16)*8);
            aL[mf] = *(const bf16x8*)(sAl + kg*1024 + (am0 + mf*16)*8);
        }
#pragma unroll
        for (int half = 0; half < 2; half++) {
            bf16x8 bH[4], bL[4];
#pragma unroll
            for (int n4 = 0; n4 < 4; n4++) {
                int nr = (half*4 + n4)*16 + ln;
                bH[n4] = *(const bf16x8*)(sWh + kg*1024 + nr*8);
                bL[n4] = *(const bf16x8*)(sWl + kg*1024 + nr*8);
            }
#pragma unroll
            for (int mf = 0; mf < 2; mf++)
#pragma unroll
                for (int n4 = 0; n4 < 4; n4++) {
                    int nf = half*4 + n4;
                    acc[mf][nf] = __builtin_amdgcn_mfma_f32_16x16x32_bf16(aH[mf], bH[n4], acc[mf][nf], 0, 0, 0);
                    acc[mf][nf] = __builtin_amdgcn_mfma_f32_16x16x32_bf16(aH[mf], bL[n4], acc[mf][nf], 0, 0, 0);
                    acc[mf][nf] = __builtin_amdgcn_mfma_f32_16x16x32_bf16(aL[mf], bH[n4], acc[mf][nf], 0, 0, 0);
                }
        }
    }
    // direct stores: in_proj -> bf16 (xh/z), low_proj -> fp32 (lowp)
#pragma unroll
    for (int mf = 0; mf < 2; mf++) {
        int l = l0 + w*32 + mf*16 + kg*4;
#pragma unroll
        for (int nf = 0; nf < 8; nf++) {
            int n = n0 + nf*16 + ln;
            if (!isLow) {
                ushort4v hv;
#pragma unroll
                for (int j = 0; j < 4; j++) hv[j] = f2bf(acc[mf][nf][j]);
                ushort_t* dstb = (n < DI) ? (xhb + ((size_t)b*DI + n)*LL + l)
                                          : (zb  + ((size_t)b*DI + (n - DI))*LL + l);
                *(ushort4v*)dstb = hv;
            } else {
                *(f32x4*)(lowp + ((size_t)b*DI + n)*LL + l) = acc[mf][nf];
            }
        }
    }
}

// -------- channel-major-A MFMA GEMM, 64-token tiles, direct stores ------------
template<int MODE, int SPLIT, int PERM0>
__global__ __launch_bounds__(256) void gemm_cmaj(
    const float* __restrict__ A0, const float* __restrict__ A1,
    const ushort_t* __restrict__ W0h, const ushort_t* __restrict__ W0l,
    const ushort_t* __restrict__ W1h, const ushort_t* __restrict__ W1l,
    const float* __restrict__ resid,
    float* __restrict__ o0, float* __restrict__ o1, int Nreal)
{
    __shared__ __align__(16) float sA[32*68];       // [32][68]
    __shared__ __align__(16) ushort_t sWh[4*64*8];  // [4][64][8]
    __shared__ __align__(16) ushort_t sWl[4*64*8];
    bool sel = (blockIdx.z == 1);
    const float* A = sel ? A1 : A0;
    const ushort_t* Wh = sel ? W1h : W0h;
    const ushort_t* Wl = sel ? W1l : W0l;
    float* out0 = sel ? o1 : o0;
    const bool perm = sel ? false : (PERM0 != 0);
    int tid = threadIdx.x;
    int t0 = blockIdx.x * 64;
    int b = t0 >> 12, l0 = t0 & 4095;
    int n0 = blockIdx.y * 64;
    const float* Ab = A + (size_t)b * 384 * LL;
    int wrow = tid >> 2, kgW = tid & 3;
    int lane = tid & 63, w = tid >> 6;
    int ln = lane & 15, kg = lane >> 4;
    int am0 = w * 16 + ln;
    f32x4 acc[4];
#pragma unroll
    for (int nf = 0; nf < 4; nf++) acc[nf] = (f32x4){0.f, 0.f, 0.f, 0.f};

    for (int k0 = 0; k0 < 384; k0 += 32) {
        __syncthreads();
#pragma unroll
        for (int i = 0; i < 2; i++) {
            int idx = tid + 256*i;
            int row = idx >> 4, ch = idx & 15;
            int m = ch * 4;
            int src = perm ? (((m >> 2) & 3) * 1024 + (((l0 + m) >> 4) << 2))
                           : (l0 + m);
            float4 v = *(const float4*)&Ab[(size_t)(k0 + row)*LL + src];
            *(float4*)&sA[row*68 + m] = v;
        }
        {
            ushort8 wv = *(const ushort8*)(Wh + (size_t)(n0 + wrow)*384 + k0 + kgW*8);
            *(ushort8*)(sWh + kgW*512 + wrow*8) = wv;
            if (SPLIT == 3) {
                ushort8 wl = *(const ushort8*)(Wl + (size_t)(n0 + wrow)*384 + k0 + kgW*8);
                *(ushort8*)(sWl + kgW*512 + wrow*8) = wl;
            }
        }
        __syncthreads();
        bf16x8 aH, aL;
#pragma unroll
        for (int e = 0; e < 8; e++) {
            float v = sA[(kg*8 + e)*68 + am0];
            ushort_t h = f2bf(v);
            aH[e] = (short)h;
            if (SPLIT == 3) aL[e] = (short)f2bf(v - bf2f(h));
        }
        bf16x8 bH[4], bL[4];
#pragma unroll
        for (int nf = 0; nf < 4; nf++) {
            bH[nf] = *(const bf16x8*)(sWh + kg*512 + (nf*16 + ln)*8);
            if (SPLIT == 3) bL[nf] = *(const bf16x8*)(sWl + kg*512 + (nf*16 + ln)*8);
        }
#pragma unroll
        for (int nf = 0; nf < 4; nf++) {
            acc[nf] = __builtin_amdgcn_mfma_f32_16x16x32_bf16(aH, bH[nf], acc[nf], 0, 0, 0);
            if (SPLIT == 3) {
                acc[nf] = __builtin_amdgcn_mfma_f32_16x16x32_bf16(aH, bL[nf], acc[nf], 0, 0, 0);
                acc[nf] = __builtin_amdgcn_mfma_f32_16x16x32_bf16(aL, bH[nf], acc[nf], 0, 0, 0);
            }
        }
    }

    if (MODE == 2) {
#pragma unroll
        for (int j = 0; j < 4; j++) {
            int t = t0 + w*16 + kg*4 + j;
#pragma unroll
            for (int nf = 0; nf < 4; nf++) {
                int n = n0 + nf*16 + ln;
                out0[(size_t)t*CM + n] = resid[(size_t)t*CM + n] + acc[nf][j];
            }
        }
    } else {
        int l = l0 + w*16 + kg*4;
#pragma unroll
        for (int nf = 0; nf < 4; nf++) {
            int n = n0 + nf*16 + ln;
            if (n < Nreal)
                *(f32x4*)(out0 + ((size_t)b*Nreal + n)*LL + l) = acc[nf];
        }
    }
}

// -------- depthwise 3x3 conv + bias + SiLU (bf16 in) -> xs fp32 PERM layout ---
// 4 outputs/thread; perm layout keeps the 4 outputs contiguous -> float4 store.
__global__ __launch_bounds__(256) void conv2d_silu_kernel(const ushort_t* __restrict__ xhb,
    const float* __restrict__ w, const float* __restrict__ bias, float* __restrict__ xs)
{
    int tid = threadIdx.x;
    int l0 = (blockIdx.x * 256 + tid) * 4;
    int c = blockIdx.y, b = blockIdx.z;
    const ushort_t* P = xhb + ((size_t)b*DI + c)*LL;
    int h = l0 >> 6, w0 = l0 & 63;
    float wc[9];
#pragma unroll
    for (int k = 0; k < 9; k++) wc[k] = w[c*9 + k];
    float bs = bias[c];
    float av[4] = {bs, bs, bs, bs};
#pragma unroll
    for (int kh = 0; kh < 3; kh++) {
        int hh = h + kh - 1;
        if ((unsigned)hh < 64u) {
            const ushort_t* R = P + hh*64;
#pragma unroll
            for (int j = 0; j < 4; j++) {
#pragma unroll
                for (int kw = 0; kw < 3; kw++) {
                    int wv = w0 + j + kw - 1;
                    if ((unsigned)wv < 64u)
                        av[j] = fmaf(wc[kh*3 + kw], bf2f(R[wv]), av[j]);
                }
            }
        }
    }
    f32x4 o;
#pragma unroll
    for (int j = 0; j < 4; j++) {
        float sg = 1.f / (1.f + __expf(-av[j]));
        o[j] = av[j] * sg;
    }
    int pb = ((l0 >> 2) & 3) * 1024 + ((l0 >> 4) << 2);
    *(f32x4*)&xs[((size_t)b*DI + c)*LL + pb] = o;
}

// -------- SimpleGates on low B/C + sum high+low -> dbc [B][44][L] -------------
__global__ __launch_bounds__(256) void gates_kernel(const float* __restrict__ dbcH,
    const float* __restrict__ dbcL,
    const float* __restrict__ sgb1, const float* __restrict__ sgb2,
    const float* __restrict__ sgc1, const float* __restrict__ sgc2,
    float* __restrict__ dbc)
{
    __shared__ float w1[192*16];
    __shared__ float w2[16*96];
    __shared__ float red[4][16][64];
    int tid = threadIdx.x;
    int gate = blockIdx.z;
    const float* g1 = gate ? sgc1 : sgb1;
    const float* g2 = gate ? sgc2 : sgb2;
    for (int i = tid; i < 192*16; i += 256) w1[i] = g1[i];
    for (int i = tid; i < 16*96;  i += 256) w2[i] = g2[i];
    int lq = tid & 63, p = tid >> 6;
    int l = blockIdx.x * 64 + lq;
    int b = blockIdx.y;
    size_t pb_ = (size_t)b*NCH*LL + l;
    __syncthreads();
    if (!gate) {
#pragma unroll
        for (int i = 0; i < 3; i++) {
            int c = p*3 + i;
            dbc[pb_ + (size_t)c*LL] = dbcH[pb_ + (size_t)c*LL] + dbcL[pb_ + (size_t)c*LL];
        }
    }
    int coff = RK + gate*NST;
    float xin[16], og[16];
#pragma unroll
    for (int n = 0; n < 16; n++) { xin[n] = dbcL[pb_ + (size_t)(coff+n)*LL]; og[n] = 0.f; }
    int h0 = p * 24;
    for (int h = h0; h < h0 + 24; h++) {
        float ya = 0.f, yb = 0.f;
#pragma unroll
        for (int n = 0; n < 16; n++) {
            ya = fmaf(w1[h*16+n], xin[n], ya);
            yb = fmaf(w1[(h+SGH)*16+n], xin[n], yb);
        }
        float gg = 0.5f * ya * (1.f + erff(ya * 0.70710678f)) * yb;
#pragma unroll
        for (int n = 0; n < 16; n++) og[n] = fmaf(w2[n*SGH+h], gg, og[n]);
    }
#pragma unroll
    for (int n = 0; n < 16; n++) red[p][n][lq] = og[n];
    __syncthreads();
#pragma unroll
    for (int i = 0; i < 4; i++) {
        int n = p*4 + i;
        float v = red[0][n][lq] + red[1][n][lq] + red[2][n][lq] + red[3][n][lq];
        dbc[pb_ + (size_t)(coff+n)*LL] = dbcH[pb_ + (size_t)(coff+n)*LL] + v;
    }
}

// -------- residual dilated dwconv1d: dts normal; Bs/Cs in PERM layout ---------
__global__ __launch_bounds__(256) void conv_dbc_kernel(const float* __restrict__ dbc,
    const float* __restrict__ wdt, const float* __restrict__ wB, const float* __restrict__ wC,
    float* __restrict__ dts, float* __restrict__ Bs, float* __restrict__ Cs)
{
    int l = blockIdx.x * 256 + threadIdx.x;
    int c = blockIdx.y, b = blockIdx.z;
    const float* wsrc = (c < RK) ? (wdt + c*15)
                      : (c < RK+NST ? wB + (c-RK)*15 : wC + (c-RK-NST)*15);
    float w[15];
#pragma unroll
    for (int k = 0; k < 15; k++) w[k] = wsrc[k];
    const float* P = dbc + ((size_t)b*NCH + c)*LL;
    float a = P[l];
#pragma unroll
    for (int k = 0; k < 15; k++) {
        int lt = l + 2*k - 14;
        if ((unsigned)lt < (unsigned)LL) a = fmaf(w[k], P[lt], a);
    }
    if (c < RK)            dts[((size_t)b*RK  + c)*LL + l] = a;
    else if (c < RK+NST)   Bs [((size_t)b*NST + (c-RK))*LL + permidx(l)] = a;
    else                   Cs [((size_t)b*NST + (c-RK-NST))*LL + permidx(l)] = a;
}

// -------- delta projection + softplus -> delta in PERM layout -----------------
__global__ __launch_bounds__(256) void delta_kernel(const float* __restrict__ dts,
    const float* __restrict__ dtw, const float* __restrict__ dtb, float* __restrict__ delta)
{
    __shared__ float sdt[RK][128];
    __shared__ float sw[64][RK];
    int tid = threadIdx.x;
    int l0 = blockIdx.x * 128, d0 = blockIdx.y * 64, b = blockIdx.z;
    for (int i = tid; i < RK*128; i += 256) {
        int r = i >> 7, lq = i & 127;
        sdt[r][lq] = dts[((size_t)b*RK + r)*LL + l0 + lq];
    }
    for (int i = tid; i < 64*RK; i += 256) {
        int dq = i / RK, r = i - dq*RK;
        sw[dq][r] = dtw[(size_t)(d0+dq)*RK + r];
    }
    __syncthreads();
    int lq = tid & 63, g = tid >> 6;
    for (int dd = 0; dd < 16; dd++) {
        int dqq = g*16 + dd, d = d0 + dqq;
        float wr[RK];
#pragma unroll
        for (int r = 0; r < RK; r++) wr[r] = sw[dqq][r];
        float bias = dtb[d];
#pragma unroll
        for (int li = 0; li < 2; li++) {
            int lloc = lq + li*64;
            float s = bias;
#pragma unroll
            for (int r = 0; r < RK; r++) s = fmaf(wr[r], sdt[r][lloc], s);
            float sp = fmaxf(s, 0.f) + __logf(1.f + __expf(-fabsf(s)));
            delta[((size_t)b*DI + d)*LL + permidx(l0 + lloc)] = sp;
        }
    }
}

// -------- selective scan v9: v4 structure + A_n=-(n+1) power fast path --------
// Single variable vs v4: in the fast path the per-step exp(dl*An) is replaced
// by a running power E[s] *= e1[s] (e1 = exp(-dl), E init e1^(8*half)).
// Runtime-verified per block; exact v4 fallback otherwise.
__global__ __launch_bounds__(256) void scan_kernel(
    const float* __restrict__ u_, const float* __restrict__ delta_,
    const float* __restrict__ Bs_, const float* __restrict__ Cs_,
    const float* __restrict__ Alogs, const float* __restrict__ Ds,
    float* __restrict__ y0_, float* __restrict__ y1_)
{
    __shared__ float wAs[8][4], wBs[8][4];
    __shared__ float yt[16][258];
    int tid = threadIdx.x;
    int t4 = tid * 4;
    int bid = blockIdx.x;
    int half = bid & 1, bd = bid >> 1;
    int b = bd / DI, d = bd % DI;
    int n0 = half * 8;
    size_t rowoff = ((size_t)b*DI + d)*LL;
    float dl[16], du[16], yac[16];
    LD16P(du, u_ + rowoff, t4);
    LD16P(dl, delta_ + rowoff, t4);
    float Dd = Ds[d];
#pragma unroll
    for (int s = 0; s < 16; s++) {
        yac[s] = half ? 0.f : du[s]*Dd;
        du[s] = dl[s]*du[s];
    }
    bool fast = true;
#pragma unroll 1
    for (int n = 0; n < 8; n++) {
        float An = -__expf(Alogs[d*NST + n0 + n]);
        float tgt = (float)(n0 + n + 1);
        fast = fast && (fabsf(An + tgt) < 1e-3f * tgt);
    }
    int lane = tid & 63, w = tid >> 6;
    if (fast) {
        float E[16];
#pragma unroll
        for (int s = 0; s < 16; s++) dl[s] = __expf(-dl[s]);   // dl := e1
        if (half) {
#pragma unroll
            for (int s = 0; s < 16; s++) {
                float t2 = dl[s]*dl[s];
                float t4v = t2*t2;
                E[s] = t4v*t4v;                                 // e1^8
            }
        } else {
#pragma unroll
            for (int s = 0; s < 16; s++) E[s] = 1.f;
        }
#pragma unroll 1
        for (int j = 0; j < 8; j++) {
            float Bn[16], Cn[16], t[16];
            LD16P(Bn, Bs_ + ((size_t)b*NST + n0 + j)*LL, t4);
            LD16P(Cn, Cs_ + ((size_t)b*NST + n0 + j)*LL, t4);
            float a = 1.f, h = 0.f;
#pragma unroll
            for (int s = 0; s < 16; s++) {
                E[s] *= dl[s];
                a *= E[s];
                h = fmaf(E[s], h, du[s]*Bn[s]);
                yac[s] = fmaf(Cn[s], h, yac[s]);
                t[s] = Cn[s]*a;
            }
            float ap = a, hv = h;
            for (int off = 1; off < 64; off <<= 1) {
                float pa = __shfl_up(ap, (unsigned)off, 64);
                float pb = __shfl_up(hv, (unsigned)off, 64);
                if (lane >= off) { hv = fmaf(ap, pb, hv); ap *= pa; }
            }
            if (lane == 63) { wAs[j][w] = ap; wBs[j][w] = hv; }
            __syncthreads();
            float PB = 0.f;
            for (int ww = 0; ww < w; ww++) PB = fmaf(wAs[j][ww], PB, wBs[j][ww]);
            hv = fmaf(ap, PB, hv);
            float tt = __shfl_up(hv, 1u, 64);
            float hin = lane ? tt : PB;
#pragma unroll
            for (int s = 0; s < 16; s++) yac[s] = fmaf(t[s], hin, yac[s]);
        }
    } else {
#pragma unroll 1
        for (int j = 0; j < 8; j++) {
            float An = -__expf(Alogs[d*NST + n0 + j]);
            float Bn[16], Cn[16], t[16];
            LD16P(Bn, Bs_ + ((size_t)b*NST + n0 + j)*LL, t4);
            LD16P(Cn, Cs_ + ((size_t)b*NST + n0 + j)*LL, t4);
            float a = 1.f, h = 0.f;
#pragma unroll
            for (int s = 0; s < 16; s++) {
                float e = __expf(dl[s]*An);
                a *= e;
                h = fmaf(e, h, du[s]*Bn[s]);
                yac[s] = fmaf(Cn[s], h, yac[s]);
                t[s] = Cn[s]*a;
            }
            float ap = a, hv = h;
            for (int off = 1; off < 64; off <<= 1) {
                float pa = __shfl_up(ap, (unsigned)off, 64);
                float pb = __shfl_up(hv, (unsigned)off, 64);
                if (lane >= off) { hv = fmaf(ap, pb, hv); ap *= pa; }
            }
            if (lane == 63) { wAs[j][w] = ap; wBs[j][w] = hv; }
            __syncthreads();
            float PB = 0.f;
            for (int ww = 0; ww < w; ww++) PB = fmaf(wAs[j][ww], PB, wBs[j][ww]);
            hv = fmaf(ap, PB, hv);
            float tt = __shfl_up(hv, 1u, 64);
            float hin = lane ? tt : PB;
#pragma unroll
            for (int s = 0; s < 16; s++) yac[s] = fmaf(t[s], hin, yac[s]);
        }
    }
#pragma unroll
    for (int i = 0; i < 16; i++) yt[i][tid] = yac[i];
    __syncthreads();
    float* yout = (half ? y1_ : y0_) + rowoff;
#pragma unroll
    for (int r = 0; r < 16; r++)
        yout[r*256 + tid] = yt[tid & 15][r*16 + (tid >> 4)];
}

// -------- out-norm LN(384) on y0+y1 + bf16-z SiLU gating (in-place over y1) ---
__global__ __launch_bounds__(1024) void outnorm_gate_kernel(const float* __restrict__ y0,
    float* y1g, const ushort_t* __restrict__ zb,
    const float* __restrict__ g, const float* __restrict__ bt)
{
    __shared__ float rs_[16][64], rq_[16][64];
    __shared__ float mu_s[64], rstd_s[64];
    int tid = threadIdx.x;
    int lq = tid & 63, p = tid >> 6;          // p in 0..15
    int l = blockIdx.x * 64 + lq;
    int b = blockIdx.y;
    const float* yp0 = y0 + (size_t)b*DI*LL + l;
    float* yp1 = y1g + (size_t)b*DI*LL + l;
    float s = 0.f, q = 0.f;
#pragma unroll 4
    for (int i = 0; i < 24; i++) {
        int d = p*24 + i;
        float v = yp0[(size_t)d*LL] + yp1[(size_t)d*LL];
        s += v; q = fmaf(v, v, q);
    }
    rs_[p][lq] = s; rq_[p][lq] = q;
    __syncthreads();
    if (p == 0) {
        float ss = 0.f, qq = 0.f;
#pragma unroll
        for (int i = 0; i < 16; i++) { ss += rs_[i][lq]; qq += rq_[i][lq]; }
        float mu = ss * (1.f/DI);
        float var = qq * (1.f/DI) - mu*mu;
        mu_s[lq] = mu; rstd_s[lq] = rsqrtf(var + 1e-5f);
    }
    __syncthreads();
    float mu = mu_s[lq], rs = rstd_s[lq];
    const ushort_t* zp = zb + (size_t)b*DI*LL + l;
#pragma unroll 4
    for (int i = 0; i < 24; i++) {
        int d = p*24 + i;
        float v = ((yp0[(size_t)d*LL] + yp1[(size_t)d*LL]) - mu)*rs*g[d] + bt[d];
        float zv = bf2f(zp[(size_t)d*LL]);
        float sg = 1.f / (1.f + __expf(-zv));
        yp1[(size_t)d*LL] = v * (zv * sg);
    }
}

extern "C" void kernel_launch(void* const* d_in, const int* in_sizes, int n_in,
                              void* d_out, int out_size, void* d_ws, size_t ws_size,
                              hipStream_t stream)
{
    (void)in_sizes; (void)n_in; (void)out_size; (void)ws_size;
    const float* x     = (const float*)d_in[0];
    const float* low   = (const float*)d_in[1];
    const float* ln_g  = (const float*)d_in[2];
    const float* ln_b  = (const float*)d_in[3];
    const float* w_in  = (const float*)d_in[4];
    const float* w_low = (const float*)d_in[5];
    const float* w_c2d = (const float*)d_in[6];
    const float* b_c2d = (const float*)d_in[7];
    const float* w_xp  = (const float*)d_in[8];
    const float* w_xpl = (const float*)d_in[9];
    const float* w_cdt = (const float*)d_in[10];
    const float* w_cB  = (const float*)d_in[11];
    const float* w_cC  = (const float*)d_in[12];
    const float* sgb1  = (const float*)d_in[13];
    const float* sgb2  = (const float*)d_in[14];
    const float* sgc1  = (const float*)d_in[15];
    const float* sgc2  = (const float*)d_in[16];
    const float* dtw   = (const float*)d_in[17];
    const float* dtb   = (const float*)d_in[18];
    const float* Alogs = (const float*)d_in[19];
    const float* Ds    = (const float*)d_in[20];
    const float* ong   = (const float*)d_in[21];
    const float* onb   = (const float*)d_in[22];
    const float* w_out = (const float*)d_in[23];
    float* ws  = (float*)d_ws;
    float* out = (float*)d_out;
    dim3 blk(256);

    // bf16 plane aliases
    ushort_t* wInH  = (ushort_t*)(ws + O_WT_IN);   ushort_t* wInL  = wInH + 147456;
    ushort_t* wLowH = (ushort_t*)(ws + O_WT_LOW);  ushort_t* wLowL = wLowH + 73728;
    ushort_t* wOutH = (ushort_t*)(ws + O_WT_OUT);  ushort_t* wOutL = wOutH + 73728;
    ushort_t* wXpH  = (ushort_t*)(ws + O_WT_XP);   ushort_t* wXpL  = wXpH + 24576;
    ushort_t* wXplH = (ushort_t*)(ws + O_WT_XPL);  ushort_t* wXplL = wXplH + 24576;
    ushort_t* xnh   = (ushort_t*)(ws + O_XN);      ushort_t* xnl   = xnh + 3145728;
    ushort_t* lowh  = (ushort_t*)(ws + O_LOWT);    ushort_t* lowl  = lowh + 3145728;
    ushort_t* xhb   = (ushort_t*)(ws + O_XH);      // bf16 xh
    ushort_t* zb    = (ushort_t*)(ws + O_Z);       // bf16 z

    prep_kernel<<<3664, blk, 0, stream>>>(w_in, wInH, wInL, w_low, wLowH, wLowL,
                                          w_out, wOutH, wOutL,
                                          w_xp, wXpH, wXpL, w_xpl, wXplH, wXplL,
                                          x, ln_g, ln_b, xnh, xnl, low, lowh, lowl);

    gemm_inlow<<<dim3(128,9), blk, 0, stream>>>(xnh, xnl, wInH, wInL,
                                                lowh, lowl, wLowH, wLowL,
                                                xhb, zb, ws+O_LOWP);

    conv2d_silu_kernel<<<dim3(4,384,4), blk, 0, stream>>>(xhb, w_c2d, b_c2d, ws+O_XS);

    gemm_cmaj<1,3,1><<<dim3(256,1,2), blk, 0, stream>>>(ws+O_XS, ws+O_LOWP,
                                                        wXpH, wXpL, wXplH, wXplL,
                                                        nullptr, ws+O_DBCH, ws+O_DBCL, NCH);

    gates_kernel<<<dim3(64,4,2), blk, 0, stream>>>(ws+O_DBCH, ws+O_DBCL, sgb1, sgb2, sgc1, sgc2, ws+O_DBC);

    conv_dbc_kernel<<<dim3(16,44,4), blk, 0, stream>>>(ws+O_DBC, w_cdt, w_cB, w_cC,
                                                       ws+O_DTS, ws+O_BS, ws+O_CS);
    delta_kernel<<<dim3(32,6,4), blk, 0, stream>>>(ws+O_DTS, dtw, dtb, ws+O_DELTA);

    scan_kernel<<<3072, blk, 0, stream>>>(ws+O_XS, ws+O_DELTA, ws+O_BS, ws+O_CS, Alogs, Ds,
                                          ws+O_Y, ws+O_Y1);

    outnorm_gate_kernel<<<dim3(64,4), dim3(1024), 0, stream>>>(ws+O_Y, ws+O_Y1, zb, ong, onb);

    gemm_cmaj<2,1,0><<<dim3(256,3,1), blk, 0, stream>>>(ws+O_Y1, nullptr,
                                                        wOutH, wOutL, nullptr, nullptr,
                                                        x, out, nullptr, CM);
}

// Round 16
// 208.728 us; speedup vs baseline: 1.5773x; 1.0134x over previous
//
#include <hip/hip_runtime.h>
#include <math.h>

#define LL 4096
#define NBATCH 4
#define CM 192
#define DI 384
#define NST 16
#define RK 12
#define NCH 44
#define SGH 96

typedef unsigned short ushort_t;
typedef __attribute__((ext_vector_type(8))) short bf16x8;
typedef __attribute__((ext_vector_type(4))) float f32x4;
typedef __attribute__((ext_vector_type(8))) unsigned short ushort8;
typedef __attribute__((ext_vector_type(4))) unsigned short ushort4v;

// workspace offsets (float units)
#define O_WT_IN   0
#define O_WT_LOW  147456
#define O_WT_XP   221184
#define O_WT_XPL  245760
#define O_WT_OUT  270336
#define O_XN      344064
#define O_LOWT    3489792
#define O_XH      6635520
#define O_Z       12926976
#define O_LOWP    19218432
#define O_XS      25509888
#define O_DBCH    31801344
#define O_DBCL    32522240
#define O_DBC     33243136
#define O_BS      33964032
#define O_CS      34226176
#define O_DELTA   O_LOWP   // lowp dead after x_proj GEMMs
#define O_Y       O_XH     // xh (bf16) dead after conv2d
#define O_Y1      O_XN     // xn/lowt bf16 planes dead after in/low GEMMs
#define O_DTS     O_DBCH   // dbcH dead after gates_kernel

__device__ __forceinline__ ushort_t f2bf(float v) {
    unsigned u = __float_as_uint(v);
    return (ushort_t)((u + 0x7FFFu + ((u >> 16) & 1u)) >> 16);
}
__device__ __forceinline__ float bf2f(ushort_t h) {
    return __uint_as_float(((unsigned)h) << 16);
}

// ---- chunk-transposed ("perm") layout within each 4096-element row ----------
__device__ __forceinline__ int permidx(int l) {
    return ((l >> 2) & 3) * 1024 + ((l >> 4) << 2) + (l & 3);
}

#define LD16P(dst, row, t4) { \
  float4 _a = *(const float4*)((row) + (t4)); \
  float4 _b = *(const float4*)((row) + 1024 + (t4)); \
  float4 _c = *(const float4*)((row) + 2048 + (t4)); \
  float4 _d = *(const float4*)((row) + 3072 + (t4)); \
  dst[0]=_a.x; dst[1]=_a.y; dst[2]=_a.z; dst[3]=_a.w; \
  dst[4]=_b.x; dst[5]=_b.y; dst[6]=_b.z; dst[7]=_b.w; \
  dst[8]=_c.x; dst[9]=_c.y; dst[10]=_c.z; dst[11]=_c.w; \
  dst[12]=_d.x; dst[13]=_d.y; dst[14]=_d.z; dst[15]=_d.w; }

// -------- merged prep: weight splits (bx<336) + LN/act splits (bx>=336) -------
__global__ __launch_bounds__(256) void prep_kernel(
    const float* __restrict__ i0, ushort_t* h0, ushort_t* l0_,
    const float* __restrict__ i1, ushort_t* h1, ushort_t* l1,
    const float* __restrict__ i2, ushort_t* h2, ushort_t* l2,
    const float* __restrict__ p0, ushort_t* ph0, ushort_t* pl0,
    const float* __restrict__ p1, ushort_t* ph1, ushort_t* pl1,
    const float* __restrict__ X, const float* __restrict__ gw, const float* __restrict__ bw,
    ushort_t* __restrict__ oh, ushort_t* __restrict__ ol,
    const float* __restrict__ LOW, ushort_t* __restrict__ lh, ushort_t* __restrict__ llo)
{
    __shared__ float xt[64][193];
    __shared__ float reds[64][4], redq[64][4];
    __shared__ float mu_s[64], rs_s[64];
    int bx = blockIdx.x;
    int tid = threadIdx.x;
    if (bx < 288) {
        const float* in; ushort_t* oh_; ushort_t* ol_; int base;
        if (bx < 144)      { in = i0; oh_ = h0; ol_ = l0_; base = bx * 1024; }
        else if (bx < 216) { in = i1; oh_ = h1; ol_ = l1;  base = (bx-144) * 1024; }
        else               { in = i2; oh_ = h2; ol_ = l2;  base = (bx-216) * 1024; }
        int i = base + tid * 4;
        float4 v = *(const float4*)&in[i];
        ushort4v h, l;
        h.x = f2bf(v.x); l.x = f2bf(v.x - bf2f(h.x));
        h.y = f2bf(v.y); l.y = f2bf(v.y - bf2f(h.y));
        h.z = f2bf(v.z); l.z = f2bf(v.z - bf2f(h.z));
        h.w = f2bf(v.w); l.w = f2bf(v.w - bf2f(h.w));
        *(ushort4v*)&oh_[i] = h;
        *(ushort4v*)&ol_[i] = l;
        return;
    }
    if (bx < 336) {
        int bb = bx - 288;
        int sel = bb / 24, bxx = bb % 24;
        const float* in = sel ? p1 : p0;
        ushort_t* oh_ = sel ? ph1 : ph0;
        ushort_t* ol_ = sel ? pl1 : pl0;
        int idx = (bxx * 256 + tid) * 4;
        int n = idx / 384;
        float4 v = (n < NCH) ? *(const float4*)&in[idx] : make_float4(0.f,0.f,0.f,0.f);
        ushort4v h, l;
        h.x = f2bf(v.x); l.x = f2bf(v.x - bf2f(h.x));
        h.y = f2bf(v.y); l.y = f2bf(v.y - bf2f(h.y));
        h.z = f2bf(v.z); l.z = f2bf(v.z - bf2f(h.z));
        h.w = f2bf(v.w); l.w = f2bf(v.w - bf2f(h.w));
        *(ushort4v*)&oh_[idx] = h;
        *(ushort4v*)&ol_[idx] = l;
        return;
    }
    int ax = bx - 336;
    if (ax >= 256) {
        int i = ((ax - 256) * 256 + tid) * 4;
        float4 v = *(const float4*)&LOW[i];
        ushort4v h, l;
        h.x = f2bf(v.x); l.x = f2bf(v.x - bf2f(h.x));
        h.y = f2bf(v.y); l.y = f2bf(v.y - bf2f(h.y));
        h.z = f2bf(v.z); l.z = f2bf(v.z - bf2f(h.z));
        h.w = f2bf(v.w); l.w = f2bf(v.w - bf2f(h.w));
        *(ushort4v*)&lh[i] = h;
        *(ushort4v*)&llo[i] = l;
        return;
    }
    int t0 = ax * 64;
    const float* Xb = X + (size_t)t0 * CM;
#pragma unroll
    for (int i = 0; i < 12; i++) {
        int f4 = tid + 256 * i;
        float4 v = *(const float4*)&Xb[f4 * 4];
        int row = f4 / 48, c = (f4 % 48) * 4;
        xt[row][c] = v.x; xt[row][c+1] = v.y; xt[row][c+2] = v.z; xt[row][c+3] = v.w;
    }
    __syncthreads();
    int tok = tid & 63, p = tid >> 6;
    float s = 0.f, q = 0.f;
#pragma unroll 8
    for (int i = 0; i < 48; i++) { float v = xt[tok][p*48+i]; s += v; q = fmaf(v, v, q); }
    reds[tok][p] = s; redq[tok][p] = q;
    __syncthreads();
    if (tid < 64) {
        float ss = reds[tid][0]+reds[tid][1]+reds[tid][2]+reds[tid][3];
        float qq = redq[tid][0]+redq[tid][1]+redq[tid][2]+redq[tid][3];
        float mu = ss * (1.f/CM);
        float var = qq * (1.f/CM) - mu*mu;
        mu_s[tid] = mu; rs_s[tid] = rsqrtf(var + 1e-5f);
    }
    __syncthreads();
    int tok2 = tid >> 2, c0 = (tid & 3) * 48;
    float mu = mu_s[tok2], rs = rs_s[tok2];
    size_t tb = (size_t)(t0 + tok2) * CM;
#pragma unroll 8
    for (int i = 0; i < 48; i++) {
        int c = c0 + i;
        float v = (xt[tok2][c] - mu) * rs * gw[c] + bw[c];
        ushort_t h = f2bf(v);
        oh[tb + c] = h;
        ol[tb + c] = f2bf(v - bf2f(h));
    }
}

// -------- merged in_proj + low_proj split-bf16 MFMA GEMM, 128x128 tiles -------
// in_proj outputs xh/z as BF16 (feed conv2d and outnorm gate only).
__global__ __launch_bounds__(256) void gemm_inlow(
    const ushort_t* __restrict__ xnh, const ushort_t* __restrict__ xnl,
    const ushort_t* __restrict__ wInH, const ushort_t* __restrict__ wInL,
    const ushort_t* __restrict__ lowh, const ushort_t* __restrict__ lowl,
    const ushort_t* __restrict__ wLowH, const ushort_t* __restrict__ wLowL,
    ushort_t* __restrict__ xhb, ushort_t* __restrict__ zb, float* __restrict__ lowp)
{
    __shared__ __align__(16) char smem[32768];
    ushort_t* sAh = (ushort_t*)smem;        // [4][128][8]
    ushort_t* sAl = sAh + 4096;
    ushort_t* sWh = sAh + 8192;             // [4][128][8]
    ushort_t* sWl = sAh + 12288;
    const int KDIM = 192;
    int tid = threadIdx.x;
    int t0 = blockIdx.x * 128;
    int b = t0 >> 12, l0 = t0 & 4095;
    int ysel = blockIdx.y;
    bool isLow = ysel >= 6;
    int n0 = (isLow ? (ysel - 6) : ysel) * 128;
    const ushort_t* Ahi = isLow ? lowh : xnh;
    const ushort_t* Alo = isLow ? lowl : xnl;
    const ushort_t* Whi = isLow ? wLowH : wInH;
    const ushort_t* Wlo = isLow ? wLowL : wInL;
    int arow = tid >> 1, kgA = (tid & 1) * 2;
    const ushort_t* gAh = Ahi + (size_t)(t0 + arow) * KDIM + kgA * 8;
    const ushort_t* gAl = Alo + (size_t)(t0 + arow) * KDIM + kgA * 8;
    const ushort_t* gWh = Whi + (size_t)(n0 + arow) * KDIM + kgA * 8;
    const ushort_t* gWl = Wlo + (size_t)(n0 + arow) * KDIM + kgA * 8;
    int lane = tid & 63, w = tid >> 6;
    int ln = lane & 15, kg = lane >> 4;
    int am0 = w * 32 + ln;
    f32x4 acc[2][8];
#pragma unroll
    for (int mf = 0; mf < 2; mf++)
#pragma unroll
        for (int nf = 0; nf < 8; nf++) acc[mf][nf] = (f32x4){0.f, 0.f, 0.f, 0.f};

    for (int k0 = 0; k0 < KDIM; k0 += 32) {
        __syncthreads();
        {
            ushort8 a0 = *(const ushort8*)(gAh + k0);
            ushort8 a1 = *(const ushort8*)(gAh + k0 + 8);
            *(ushort8*)(sAh + kgA*1024 + arow*8) = a0;
            *(ushort8*)(sAh + (kgA+1)*1024 + arow*8) = a1;
            ushort8 b0 = *(const ushort8*)(gAl + k0);
            ushort8 b1 = *(const ushort8*)(gAl + k0 + 8);
            *(ushort8*)(sAl + kgA*1024 + arow*8) = b0;
            *(ushort8*)(sAl + (kgA+1)*1024 + arow*8) = b1;
            ushort8 w0 = *(const ushort8*)(gWh + k0);
            ushort8 w1 = *(const ushort8*)(gWh + k0 + 8);
            *(ushort8*)(sWh + kgA*1024 + arow*8) = w0;
            *(ushort8*)(sWh + (kgA+1)*1024 + arow*8) = w1;
            ushort8 w2 = *(const ushort8*)(gWl + k0);
            ushort8 w3 = *(const ushort8*)(gWl + k0 + 8);
            *(ushort8*)(sWl + kgA*1024 + arow*8) = w2;
            *(ushort8*)(sWl + (kgA+1)*1024 + arow*8) = w3;
        }
        __syncthreads();
        bf16x8 aH[2], aL[2];
#pragma unroll
        for (int mf = 0; mf < 2; mf++) {
            aH[mf] = *(const bf16x8*)(sAh + kg*1024 + (am0 + mf*16)*8);
            aL[mf] = *(const bf16x8*)(sAl + kg*1024 + (am0 + mf*16)*8);
        }
#pragma unroll
        for (int half = 0; half < 2; half++) {
            bf16x8 bH[4], bL[4];
#pragma unroll
            for (int n4 = 0; n4 < 4; n4++) {
                int nr = (half*4 + n4)*16 + ln;
                bH[n4] = *(const bf16x8*)(sWh + kg*1024 + nr*8);
                bL[n4] = *(const bf16x8*)(sWl + kg*1024 + nr*8);
            }
#pragma unroll
            for (int mf = 0; mf < 2; mf++)
#pragma unroll
                for (int n4 = 0; n4 < 4; n4++) {
                    int nf = half*4 + n4;
                    acc[mf][nf] = __builtin_amdgcn_mfma_f32_16x16x32_bf16(aH[mf], bH[n4], acc[mf][nf], 0, 0, 0);
                    acc[mf][nf] = __builtin_amdgcn_mfma_f32_16x16x32_bf16(aH[mf], bL[n4], acc[mf][nf], 0, 0, 0);
                    acc[mf][nf] = __builtin_amdgcn_mfma_f32_16x16x32_bf16(aL[mf], bH[n4], acc[mf][nf], 0, 0, 0);
                }
        }
    }
    // direct stores: in_proj -> bf16 (xh/z), low_proj -> fp32 (lowp)
#pragma unroll
    for (int mf = 0; mf < 2; mf++) {
        int l = l0 + w*32 + mf*16 + kg*4;
#pragma unroll
        for (int nf = 0; nf < 8; nf++) {
            int n = n0 + nf*16 + ln;
            if (!isLow) {
                ushort4v hv;
#pragma unroll
                for (int j = 0; j < 4; j++) hv[j] = f2bf(acc[mf][nf][j]);
                ushort_t* dstb = (n < DI) ? (xhb + ((size_t)b*DI + n)*LL + l)
                                          : (zb  + ((size_t)b*DI + (n - DI))*LL + l);
                *(ushort4v*)dstb = hv;
            } else {
                *(f32x4*)(lowp + ((size_t)b*DI + n)*LL + l) = acc[mf][nf];
            }
        }
    }
}

// -------- channel-major-A MFMA GEMM, 64-token tiles, direct stores ------------
template<int MODE, int SPLIT, int PERM0>
__global__ __launch_bounds__(256) void gemm_cmaj(
    const float* __restrict__ A0, const float* __restrict__ A1,
    const ushort_t* __restrict__ W0h, const ushort_t* __restrict__ W0l,
    const ushort_t* __restrict__ W1h, const ushort_t* __restrict__ W1l,
    const float* __restrict__ resid,
    float* __restrict__ o0, float* __restrict__ o1, int Nreal)
{
    __shared__ __align__(16) float sA[32*68];       // [32][68]
    __shared__ __align__(16) ushort_t sWh[4*64*8];  // [4][64][8]
    __shared__ __align__(16) ushort_t sWl[4*64*8];
    bool sel = (blockIdx.z == 1);
    const float* A = sel ? A1 : A0;
    const ushort_t* Wh = sel ? W1h : W0h;
    const ushort_t* Wl = sel ? W1l : W0l;
    float* out0 = sel ? o1 : o0;
    const bool perm = sel ? false : (PERM0 != 0);
    int tid = threadIdx.x;
    int t0 = blockIdx.x * 64;
    int b = t0 >> 12, l0 = t0 & 4095;
    int n0 = blockIdx.y * 64;
    const float* Ab = A + (size_t)b * 384 * LL;
    int wrow = tid >> 2, kgW = tid & 3;
    int lane = tid & 63, w = tid >> 6;
    int ln = lane & 15, kg = lane >> 4;
    int am0 = w * 16 + ln;
    f32x4 acc[4];
#pragma unroll
    for (int nf = 0; nf < 4; nf++) acc[nf] = (f32x4){0.f, 0.f, 0.f, 0.f};

    for (int k0 = 0; k0 < 384; k0 += 32) {
        __syncthreads();
#pragma unroll
        for (int i = 0; i < 2; i++) {
            int idx = tid + 256*i;
            int row = idx >> 4, ch = idx & 15;
            int m = ch * 4;
            int src = perm ? (((m >> 2) & 3) * 1024 + (((l0 + m) >> 4) << 2))
                           : (l0 + m);
            float4 v = *(const float4*)&Ab[(size_t)(k0 + row)*LL + src];
            *(float4*)&sA[row*68 + m] = v;
        }
        {
            ushort8 wv = *(const ushort8*)(Wh + (size_t)(n0 + wrow)*384 + k0 + kgW*8);
            *(ushort8*)(sWh + kgW*512 + wrow*8) = wv;
            if (SPLIT == 3) {
                ushort8 wl = *(const ushort8*)(Wl + (size_t)(n0 + wrow)*384 + k0 + kgW*8);
                *(ushort8*)(sWl + kgW*512 + wrow*8) = wl;
            }
        }
        __syncthreads();
        bf16x8 aH, aL;
#pragma unroll
        for (int e = 0; e < 8; e++) {
            float v = sA[(kg*8 + e)*68 + am0];
            ushort_t h = f2bf(v);
            aH[e] = (short)h;
            if (SPLIT == 3) aL[e] = (short)f2bf(v - bf2f(h));
        }
        bf16x8 bH[4], bL[4];
#pragma unroll
        for (int nf = 0; nf < 4; nf++) {
            bH[nf] = *(const bf16x8*)(sWh + kg*512 + (nf*16 + ln)*8);
            if (SPLIT == 3) bL[nf] = *(const bf16x8*)(sWl + kg*512 + (nf*16 + ln)*8);
        }
#pragma unroll
        for (int nf = 0; nf < 4; nf++) {
            acc[nf] = __builtin_amdgcn_mfma_f32_16x16x32_bf16(aH, bH[nf], acc[nf], 0, 0, 0);
            if (SPLIT == 3) {
                acc[nf] = __builtin_amdgcn_mfma_f32_16x16x32_bf16(aH, bL[nf], acc[nf], 0, 0, 0);
                acc[nf] = __builtin_amdgcn_mfma_f32_16x16x32_bf16(aL, bH[nf], acc[nf], 0, 0, 0);
            }
        }
    }

    if (MODE == 2) {
#pragma unroll
        for (int j = 0; j < 4; j++) {
            int t = t0 + w*16 + kg*4 + j;
#pragma unroll
            for (int nf = 0; nf < 4; nf++) {
                int n = n0 + nf*16 + ln;
                out0[(size_t)t*CM + n] = resid[(size_t)t*CM + n] + acc[nf][j];
            }
        }
    } else {
        int l = l0 + w*16 + kg*4;
#pragma unroll
        for (int nf = 0; nf < 4; nf++) {
            int n = n0 + nf*16 + ln;
            if (n < Nreal)
                *(f32x4*)(out0 + ((size_t)b*Nreal + n)*LL + l) = acc[nf];
        }
    }
}

// -------- depthwise 3x3 conv + bias + SiLU (bf16 in) -> xs fp32 PERM layout ---
__global__ __launch_bounds__(256) void conv2d_silu_kernel(const ushort_t* __restrict__ xhb,
    const float* __restrict__ w, const float* __restrict__ bias, float* __restrict__ xs)
{
    int tid = threadIdx.x;
    int l0 = (blockIdx.x * 256 + tid) * 4;
    int c = blockIdx.y, b = blockIdx.z;
    const ushort_t* P = xhb + ((size_t)b*DI + c)*LL;
    int h = l0 >> 6, w0 = l0 & 63;
    float wc[9];
#pragma unroll
    for (int k = 0; k < 9; k++) wc[k] = w[c*9 + k];
    float bs = bias[c];
    float av[4] = {bs, bs, bs, bs};
#pragma unroll
    for (int kh = 0; kh < 3; kh++) {
        int hh = h + kh - 1;
        if ((unsigned)hh < 64u) {
            const ushort_t* R = P + hh*64;
#pragma unroll
            for (int j = 0; j < 4; j++) {
#pragma unroll
                for (int kw = 0; kw < 3; kw++) {
                    int wv = w0 + j + kw - 1;
                    if ((unsigned)wv < 64u)
                        av[j] = fmaf(wc[kh*3 + kw], bf2f(R[wv]), av[j]);
                }
            }
        }
    }
    f32x4 o;
#pragma unroll
    for (int j = 0; j < 4; j++) {
        float sg = 1.f / (1.f + __expf(-av[j]));
        o[j] = av[j] * sg;
    }
    int pb = ((l0 >> 2) & 3) * 1024 + ((l0 >> 4) << 2);
    *(f32x4*)&xs[((size_t)b*DI + c)*LL + pb] = o;
}

// -------- SimpleGates on low B/C + sum high+low -> dbc [B][44][L] -------------
__global__ __launch_bounds__(256) void gates_kernel(const float* __restrict__ dbcH,
    const float* __restrict__ dbcL,
    const float* __restrict__ sgb1, const float* __restrict__ sgb2,
    const float* __restrict__ sgc1, const float* __restrict__ sgc2,
    float* __restrict__ dbc)
{
    __shared__ float w1[192*16];
    __shared__ float w2[16*96];
    __shared__ float red[4][16][64];
    int tid = threadIdx.x;
    int gate = blockIdx.z;
    const float* g1 = gate ? sgc1 : sgb1;
    const float* g2 = gate ? sgc2 : sgb2;
    for (int i = tid; i < 192*16; i += 256) w1[i] = g1[i];
    for (int i = tid; i < 16*96;  i += 256) w2[i] = g2[i];
    int lq = tid & 63, p = tid >> 6;
    int l = blockIdx.x * 64 + lq;
    int b = blockIdx.y;
    size_t pb_ = (size_t)b*NCH*LL + l;
    __syncthreads();
    if (!gate) {
#pragma unroll
        for (int i = 0; i < 3; i++) {
            int c = p*3 + i;
            dbc[pb_ + (size_t)c*LL] = dbcH[pb_ + (size_t)c*LL] + dbcL[pb_ + (size_t)c*LL];
        }
    }
    int coff = RK + gate*NST;
    float xin[16], og[16];
#pragma unroll
    for (int n = 0; n < 16; n++) { xin[n] = dbcL[pb_ + (size_t)(coff+n)*LL]; og[n] = 0.f; }
    int h0 = p * 24;
    for (int h = h0; h < h0 + 24; h++) {
        float ya = 0.f, yb = 0.f;
#pragma unroll
        for (int n = 0; n < 16; n++) {
            ya = fmaf(w1[h*16+n], xin[n], ya);
            yb = fmaf(w1[(h+SGH)*16+n], xin[n], yb);
        }
        float gg = 0.5f * ya * (1.f + erff(ya * 0.70710678f)) * yb;
#pragma unroll
        for (int n = 0; n < 16; n++) og[n] = fmaf(w2[n*SGH+h], gg, og[n]);
    }
#pragma unroll
    for (int n = 0; n < 16; n++) red[p][n][lq] = og[n];
    __syncthreads();
#pragma unroll
    for (int i = 0; i < 4; i++) {
        int n = p*4 + i;
        float v = red[0][n][lq] + red[1][n][lq] + red[2][n][lq] + red[3][n][lq];
        dbc[pb_ + (size_t)(coff+n)*LL] = dbcH[pb_ + (size_t)(coff+n)*LL] + v;
    }
}

// -------- residual dilated dwconv1d: dts normal; Bs/Cs in PERM layout ---------
__global__ __launch_bounds__(256) void conv_dbc_kernel(const float* __restrict__ dbc,
    const float* __restrict__ wdt, const float* __restrict__ wB, const float* __restrict__ wC,
    float* __restrict__ dts, float* __restrict__ Bs, float* __restrict__ Cs)
{
    int l = blockIdx.x * 256 + threadIdx.x;
    int c = blockIdx.y, b = blockIdx.z;
    const float* wsrc = (c < RK) ? (wdt + c*15)
                      : (c < RK+NST ? wB + (c-RK)*15 : wC + (c-RK-NST)*15);
    float w[15];
#pragma unroll
    for (int k = 0; k < 15; k++) w[k] = wsrc[k];
    const float* P = dbc + ((size_t)b*NCH + c)*LL;
    float a = P[l];
#pragma unroll
    for (int k = 0; k < 15; k++) {
        int lt = l + 2*k - 14;
        if ((unsigned)lt < (unsigned)LL) a = fmaf(w[k], P[lt], a);
    }
    if (c < RK)            dts[((size_t)b*RK  + c)*LL + l] = a;
    else if (c < RK+NST)   Bs [((size_t)b*NST + (c-RK))*LL + permidx(l)] = a;
    else                   Cs [((size_t)b*NST + (c-RK-NST))*LL + permidx(l)] = a;
}

// -------- delta projection + softplus -> delta in PERM layout -----------------
__global__ __launch_bounds__(256) void delta_kernel(const float* __restrict__ dts,
    const float* __restrict__ dtw, const float* __restrict__ dtb, float* __restrict__ delta)
{
    __shared__ float sdt[RK][128];
    __shared__ float sw[64][RK];
    int tid = threadIdx.x;
    int l0 = blockIdx.x * 128, d0 = blockIdx.y * 64, b = blockIdx.z;
    for (int i = tid; i < RK*128; i += 256) {
        int r = i >> 7, lq = i & 127;
        sdt[r][lq] = dts[((size_t)b*RK + r)*LL + l0 + lq];
    }
    for (int i = tid; i < 64*RK; i += 256) {
        int dq = i / RK, r = i - dq*RK;
        sw[dq][r] = dtw[(size_t)(d0+dq)*RK + r];
    }
    __syncthreads();
    int lq = tid & 63, g = tid >> 6;
    for (int dd = 0; dd < 16; dd++) {
        int dqq = g*16 + dd, d = d0 + dqq;
        float wr[RK];
#pragma unroll
        for (int r = 0; r < RK; r++) wr[r] = sw[dqq][r];
        float bias = dtb[d];
#pragma unroll
        for (int li = 0; li < 2; li++) {
            int lloc = lq + li*64;
            float s = bias;
#pragma unroll
            for (int r = 0; r < RK; r++) s = fmaf(wr[r], sdt[r][lloc], s);
            float sp = fmaxf(s, 0.f) + __logf(1.f + __expf(-fabsf(s)));
            delta[((size_t)b*DI + d)*LL + permidx(l0 + lloc)] = sp;
        }
    }
}

// -------- selective scan v4 (measured best, 64 VGPR): half-split + fixup ------
__global__ __launch_bounds__(256) void scan_kernel(
    const float* __restrict__ u_, const float* __restrict__ delta_,
    const float* __restrict__ Bs_, const float* __restrict__ Cs_,
    const float* __restrict__ Alogs, const float* __restrict__ Ds,
    float* __restrict__ y0_, float* __restrict__ y1_)
{
    __shared__ float wAs[8][4], wBs[8][4];
    __shared__ float yt[16][258];
    int tid = threadIdx.x;
    int t4 = tid * 4;
    int bid = blockIdx.x;
    int half = bid & 1, bd = bid >> 1;
    int b = bd / DI, d = bd % DI;
    int n0 = half * 8;
    size_t rowoff = ((size_t)b*DI + d)*LL;
    float dl[16], du[16], yac[16];
    LD16P(du, u_ + rowoff, t4);
    LD16P(dl, delta_ + rowoff, t4);
    float Dd = Ds[d];
#pragma unroll
    for (int s = 0; s < 16; s++) {
        yac[s] = half ? 0.f : du[s]*Dd;
        du[s] = dl[s]*du[s];
    }
    int lane = tid & 63, w = tid >> 6;
#pragma unroll 1
    for (int j = 0; j < 8; j++) {
        float An = -__expf(Alogs[d*NST + n0 + j]);
        float Bn[16], Cn[16], t[16];
        LD16P(Bn, Bs_ + ((size_t)b*NST + n0 + j)*LL, t4);
        LD16P(Cn, Cs_ + ((size_t)b*NST + n0 + j)*LL, t4);
        float a = 1.f, h = 0.f;
#pragma unroll
        for (int s = 0; s < 16; s++) {
            float e = __expf(dl[s]*An);
            a *= e;
            h = fmaf(e, h, du[s]*Bn[s]);
            yac[s] = fmaf(Cn[s], h, yac[s]);
            t[s] = Cn[s]*a;
        }
        float ap = a, hv = h;
        for (int off = 1; off < 64; off <<= 1) {
            float pa = __shfl_up(ap, (unsigned)off, 64);
            float pb = __shfl_up(hv, (unsigned)off, 64);
            if (lane >= off) { hv = fmaf(ap, pb, hv); ap *= pa; }
        }
        if (lane == 63) { wAs[j][w] = ap; wBs[j][w] = hv; }
        __syncthreads();
        float PB = 0.f;
        for (int ww = 0; ww < w; ww++) PB = fmaf(wAs[j][ww], PB, wBs[j][ww]);
        hv = fmaf(ap, PB, hv);
        float tt = __shfl_up(hv, 1u, 64);
        float hin = lane ? tt : PB;
#pragma unroll
        for (int s = 0; s < 16; s++) yac[s] = fmaf(t[s], hin, yac[s]);
    }
#pragma unroll
    for (int i = 0; i < 16; i++) yt[i][tid] = yac[i];
    __syncthreads();
    float* yout = (half ? y1_ : y0_) + rowoff;
#pragma unroll
    for (int r = 0; r < 16; r++)
        yout[r*256 + tid] = yt[tid & 15][r*16 + (tid >> 4)];
}

// -------- out-norm LN(384) on y0+y1 + bf16-z SiLU gating (in-place over y1) ---
__global__ __launch_bounds__(1024) void outnorm_gate_kernel(const float* __restrict__ y0,
    float* y1g, const ushort_t* __restrict__ zb,
    const float* __restrict__ g, const float* __restrict__ bt)
{
    __shared__ float rs_[16][64], rq_[16][64];
    __shared__ float mu_s[64], rstd_s[64];
    int tid = threadIdx.x;
    int lq = tid & 63, p = tid >> 6;          // p in 0..15
    int l = blockIdx.x * 64 + lq;
    int b = blockIdx.y;
    const float* yp0 = y0 + (size_t)b*DI*LL + l;
    float* yp1 = y1g + (size_t)b*DI*LL + l;
    float s = 0.f, q = 0.f;
#pragma unroll 4
    for (int i = 0; i < 24; i++) {
        int d = p*24 + i;
        float v = yp0[(size_t)d*LL] + yp1[(size_t)d*LL];
        s += v; q = fmaf(v, v, q);
    }
    rs_[p][lq] = s; rq_[p][lq] = q;
    __syncthreads();
    if (p == 0) {
        float ss = 0.f, qq = 0.f;
#pragma unroll
        for (int i = 0; i < 16; i++) { ss += rs_[i][lq]; qq += rq_[i][lq]; }
        float mu = ss * (1.f/DI);
        float var = qq * (1.f/DI) - mu*mu;
        mu_s[lq] = mu; rstd_s[lq] = rsqrtf(var + 1e-5f);
    }
    __syncthreads();
    float mu = mu_s[lq], rs = rstd_s[lq];
    const ushort_t* zp = zb + (size_t)b*DI*LL + l;
#pragma unroll 4
    for (int i = 0; i < 24; i++) {
        int d = p*24 + i;
        float v = ((yp0[(size_t)d*LL] + yp1[(size_t)d*LL]) - mu)*rs*g[d] + bt[d];
        float zv = bf2f(zp[(size_t)d*LL]);
        float sg = 1.f / (1.f + __expf(-zv));
        yp1[(size_t)d*LL] = v * (zv * sg);
    }
}

extern "C" void kernel_launch(void* const* d_in, const int* in_sizes, int n_in,
                              void* d_out, int out_size, void* d_ws, size_t ws_size,
                              hipStream_t stream)
{
    (void)in_sizes; (void)n_in; (void)out_size; (void)ws_size;
    const float* x     = (const float*)d_in[0];
    const float* low   = (const float*)d_in[1];
    const float* ln_g  = (const float*)d_in[2];
    const float* ln_b  = (const float*)d_in[3];
    const float* w_in  = (const float*)d_in[4];
    const float* w_low = (const float*)d_in[5];
    const float* w_c2d = (const float*)d_in[6];
    const float* b_c2d = (const float*)d_in[7];
    const float* w_xp  = (const float*)d_in[8];
    const float* w_xpl = (const float*)d_in[9];
    const float* w_cdt = (const float*)d_in[10];
    const float* w_cB  = (const float*)d_in[11];
    const float* w_cC  = (const float*)d_in[12];
    const float* sgb1  = (const float*)d_in[13];
    const float* sgb2  = (const float*)d_in[14];
    const float* sgc1  = (const float*)d_in[15];
    const float* sgc2  = (const float*)d_in[16];
    const float* dtw   = (const float*)d_in[17];
    const float* dtb   = (const float*)d_in[18];
    const float* Alogs = (const float*)d_in[19];
    const float* Ds    = (const float*)d_in[20];
    const float* ong   = (const float*)d_in[21];
    const float* onb   = (const float*)d_in[22];
    const float* w_out = (const float*)d_in[23];
    float* ws  = (float*)d_ws;
    float* out = (float*)d_out;
    dim3 blk(256);

    // bf16 plane aliases
    ushort_t* wInH  = (ushort_t*)(ws + O_WT_IN);   ushort_t* wInL  = wInH + 147456;
    ushort_t* wLowH = (ushort_t*)(ws + O_WT_LOW);  ushort_t* wLowL = wLowH + 73728;
    ushort_t* wOutH = (ushort_t*)(ws + O_WT_OUT);  ushort_t* wOutL = wOutH + 73728;
    ushort_t* wXpH  = (ushort_t*)(ws + O_WT_XP);   ushort_t* wXpL  = wXpH + 24576;
    ushort_t* wXplH = (ushort_t*)(ws + O_WT_XPL);  ushort_t* wXplL = wXplH + 24576;
    ushort_t* xnh   = (ushort_t*)(ws + O_XN);      ushort_t* xnl   = xnh + 3145728;
    ushort_t* lowh  = (ushort_t*)(ws + O_LOWT);    ushort_t* lowl  = lowh + 3145728;
    ushort_t* xhb   = (ushort_t*)(ws + O_XH);      // bf16 xh
    ushort_t* zb    = (ushort_t*)(ws + O_Z);       // bf16 z

    prep_kernel<<<3664, blk, 0, stream>>>(w_in, wInH, wInL, w_low, wLowH, wLowL,
                                          w_out, wOutH, wOutL,
                                          w_xp, wXpH, wXpL, w_xpl, wXplH, wXplL,
                                          x, ln_g, ln_b, xnh, xnl, low, lowh, lowl);

    gemm_inlow<<<dim3(128,9), blk, 0, stream>>>(xnh, xnl, wInH, wInL,
                                                lowh, lowl, wLowH, wLowL,
                                                xhb, zb, ws+O_LOWP);

    conv2d_silu_kernel<<<dim3(4,384,4), blk, 0, stream>>>(xhb, w_c2d, b_c2d, ws+O_XS);

    gemm_cmaj<1,3,1><<<dim3(256,1,2), blk, 0, stream>>>(ws+O_XS, ws+O_LOWP,
                                                        wXpH, wXpL, wXplH, wXplL,
                                                        nullptr, ws+O_DBCH, ws+O_DBCL, NCH);

    gates_kernel<<<dim3(64,4,2), blk, 0, stream>>>(ws+O_DBCH, ws+O_DBCL, sgb1, sgb2, sgc1, sgc2, ws+O_DBC);

    conv_dbc_kernel<<<dim3(16,44,4), blk, 0, stream>>>(ws+O_DBC, w_cdt, w_cB, w_cC,
                                                       ws+O_DTS, ws+O_BS, ws+O_CS);
    delta_kernel<<<dim3(32,6,4), blk, 0, stream>>>(ws+O_DTS, dtw, dtb, ws+O_DELTA);

    scan_kernel<<<3072, blk, 0, stream>>>(ws+O_XS, ws+O_DELTA, ws+O_BS, ws+O_CS, Alogs, Ds,
                                          ws+O_Y, ws+O_Y1);

    outnorm_gate_kernel<<<dim3(64,4), dim3(1024), 0, stream>>>(ws+O_Y, ws+O_Y1, zb, ong, onb);

    gemm_cmaj<2,1,0><<<dim3(256,3,1), blk, 0, stream>>>(ws+O_Y1, nullptr,
                                                        wOutH, wOutL, nullptr, nullptr,
                                                        x, out, nullptr, CM);
}

// Round 17
// 208.399 us; speedup vs baseline: 1.5798x; 1.0016x over previous
//
#include <hip/hip_runtime.h>
#include <math.h>

#define LL 4096
#define NBATCH 4
#define CM 192
#define DI 384
#define NST 16
#define RK 12
#define NCH 44
#define SGH 96

typedef unsigned short ushort_t;
typedef __attribute__((ext_vector_type(8))) short bf16x8;
typedef __attribute__((ext_vector_type(4))) float f32x4;
typedef __attribute__((ext_vector_type(8))) unsigned short ushort8;
typedef __attribute__((ext_vector_type(4))) unsigned short ushort4v;

// workspace offsets (float units)
#define O_WT_IN   0
#define O_WT_LOW  147456
#define O_WT_XP   221184
#define O_WT_XPL  245760
#define O_WT_OUT  270336
#define O_XN      344064
#define O_LOWT    3489792
#define O_XH      6635520
#define O_Z       12926976
#define O_LOWP    19218432
#define O_XS      25509888
#define O_DBCH    31801344
#define O_DBCL    32522240
#define O_DBC     33243136
#define O_BS      33964032
#define O_CS      34226176
#define O_DELTA   O_LOWP   // lowp dead after x_proj GEMMs
#define O_Y       O_XH     // xh (bf16) dead after conv2d
#define O_Y1      O_XN     // xn/lowt bf16 planes dead after in/low GEMMs
#define O_YGB     O_LOWP   // delta dead after scan -> bf16 gated output
#define O_DTS     O_DBCH   // dbcH dead after gates_kernel

__device__ __forceinline__ ushort_t f2bf(float v) {
    unsigned u = __float_as_uint(v);
    return (ushort_t)((u + 0x7FFFu + ((u >> 16) & 1u)) >> 16);
}
__device__ __forceinline__ float bf2f(ushort_t h) {
    return __uint_as_float(((unsigned)h) << 16);
}

// ---- chunk-transposed ("perm") layout within each 4096-element row ----------
__device__ __forceinline__ int permidx(int l) {
    return ((l >> 2) & 3) * 1024 + ((l >> 4) << 2) + (l & 3);
}

#define LD16P(dst, row, t4) { \
  float4 _a = *(const float4*)((row) + (t4)); \
  float4 _b = *(const float4*)((row) + 1024 + (t4)); \
  float4 _c = *(const float4*)((row) + 2048 + (t4)); \
  float4 _d = *(const float4*)((row) + 3072 + (t4)); \
  dst[0]=_a.x; dst[1]=_a.y; dst[2]=_a.z; dst[3]=_a.w; \
  dst[4]=_b.x; dst[5]=_b.y; dst[6]=_b.z; dst[7]=_b.w; \
  dst[8]=_c.x; dst[9]=_c.y; dst[10]=_c.z; dst[11]=_c.w; \
  dst[12]=_d.x; dst[13]=_d.y; dst[14]=_d.z; dst[15]=_d.w; }

// -------- merged prep: weight splits (bx<336) + LN/act splits (bx>=336) -------
__global__ __launch_bounds__(256) void prep_kernel(
    const float* __restrict__ i0, ushort_t* h0, ushort_t* l0_,
    const float* __restrict__ i1, ushort_t* h1, ushort_t* l1,
    const float* __restrict__ i2, ushort_t* h2, ushort_t* l2,
    const float* __restrict__ p0, ushort_t* ph0, ushort_t* pl0,
    const float* __restrict__ p1, ushort_t* ph1, ushort_t* pl1,
    const float* __restrict__ X, const float* __restrict__ gw, const float* __restrict__ bw,
    ushort_t* __restrict__ oh, ushort_t* __restrict__ ol,
    const float* __restrict__ LOW, ushort_t* __restrict__ lh, ushort_t* __restrict__ llo)
{
    __shared__ float xt[64][193];
    __shared__ float reds[64][4], redq[64][4];
    __shared__ float mu_s[64], rs_s[64];
    int bx = blockIdx.x;
    int tid = threadIdx.x;
    if (bx < 288) {
        const float* in; ushort_t* oh_; ushort_t* ol_; int base;
        if (bx < 144)      { in = i0; oh_ = h0; ol_ = l0_; base = bx * 1024; }
        else if (bx < 216) { in = i1; oh_ = h1; ol_ = l1;  base = (bx-144) * 1024; }
        else               { in = i2; oh_ = h2; ol_ = l2;  base = (bx-216) * 1024; }
        int i = base + tid * 4;
        float4 v = *(const float4*)&in[i];
        ushort4v h, l;
        h.x = f2bf(v.x); l.x = f2bf(v.x - bf2f(h.x));
        h.y = f2bf(v.y); l.y = f2bf(v.y - bf2f(h.y));
        h.z = f2bf(v.z); l.z = f2bf(v.z - bf2f(h.z));
        h.w = f2bf(v.w); l.w = f2bf(v.w - bf2f(h.w));
        *(ushort4v*)&oh_[i] = h;
        *(ushort4v*)&ol_[i] = l;
        return;
    }
    if (bx < 336) {
        int bb = bx - 288;
        int sel = bb / 24, bxx = bb % 24;
        const float* in = sel ? p1 : p0;
        ushort_t* oh_ = sel ? ph1 : ph0;
        ushort_t* ol_ = sel ? pl1 : pl0;
        int idx = (bxx * 256 + tid) * 4;
        int n = idx / 384;
        float4 v = (n < NCH) ? *(const float4*)&in[idx] : make_float4(0.f,0.f,0.f,0.f);
        ushort4v h, l;
        h.x = f2bf(v.x); l.x = f2bf(v.x - bf2f(h.x));
        h.y = f2bf(v.y); l.y = f2bf(v.y - bf2f(h.y));
        h.z = f2bf(v.z); l.z = f2bf(v.z - bf2f(h.z));
        h.w = f2bf(v.w); l.w = f2bf(v.w - bf2f(h.w));
        *(ushort4v*)&oh_[idx] = h;
        *(ushort4v*)&ol_[idx] = l;
        return;
    }
    int ax = bx - 336;
    if (ax >= 256) {
        int i = ((ax - 256) * 256 + tid) * 4;
        float4 v = *(const float4*)&LOW[i];
        ushort4v h, l;
        h.x = f2bf(v.x); l.x = f2bf(v.x - bf2f(h.x));
        h.y = f2bf(v.y); l.y = f2bf(v.y - bf2f(h.y));
        h.z = f2bf(v.z); l.z = f2bf(v.z - bf2f(h.z));
        h.w = f2bf(v.w); l.w = f2bf(v.w - bf2f(h.w));
        *(ushort4v*)&lh[i] = h;
        *(ushort4v*)&llo[i] = l;
        return;
    }
    int t0 = ax * 64;
    const float* Xb = X + (size_t)t0 * CM;
#pragma unroll
    for (int i = 0; i < 12; i++) {
        int f4 = tid + 256 * i;
        float4 v = *(const float4*)&Xb[f4 * 4];
        int row = f4 / 48, c = (f4 % 48) * 4;
        xt[row][c] = v.x; xt[row][c+1] = v.y; xt[row][c+2] = v.z; xt[row][c+3] = v.w;
    }
    __syncthreads();
    int tok = tid & 63, p = tid >> 6;
    float s = 0.f, q = 0.f;
#pragma unroll 8
    for (int i = 0; i < 48; i++) { float v = xt[tok][p*48+i]; s += v; q = fmaf(v, v, q); }
    reds[tok][p] = s; redq[tok][p] = q;
    __syncthreads();
    if (tid < 64) {
        float ss = reds[tid][0]+reds[tid][1]+reds[tid][2]+reds[tid][3];
        float qq = redq[tid][0]+redq[tid][1]+redq[tid][2]+redq[tid][3];
        float mu = ss * (1.f/CM);
        float var = qq * (1.f/CM) - mu*mu;
        mu_s[tid] = mu; rs_s[tid] = rsqrtf(var + 1e-5f);
    }
    __syncthreads();
    int tok2 = tid >> 2, c0 = (tid & 3) * 48;
    float mu = mu_s[tok2], rs = rs_s[tok2];
    size_t tb = (size_t)(t0 + tok2) * CM;
#pragma unroll 8
    for (int i = 0; i < 48; i++) {
        int c = c0 + i;
        float v = (xt[tok2][c] - mu) * rs * gw[c] + bw[c];
        ushort_t h = f2bf(v);
        oh[tb + c] = h;
        ol[tb + c] = f2bf(v - bf2f(h));
    }
}

// -------- merged in_proj + low_proj split-bf16 MFMA GEMM, 128x128 tiles -------
__global__ __launch_bounds__(256) void gemm_inlow(
    const ushort_t* __restrict__ xnh, const ushort_t* __restrict__ xnl,
    const ushort_t* __restrict__ wInH, const ushort_t* __restrict__ wInL,
    const ushort_t* __restrict__ lowh, const ushort_t* __restrict__ lowl,
    const ushort_t* __restrict__ wLowH, const ushort_t* __restrict__ wLowL,
    ushort_t* __restrict__ xhb, ushort_t* __restrict__ zb, float* __restrict__ lowp)
{
    __shared__ __align__(16) char smem[32768];
    ushort_t* sAh = (ushort_t*)smem;        // [4][128][8]
    ushort_t* sAl = sAh + 4096;
    ushort_t* sWh = sAh + 8192;             // [4][128][8]
    ushort_t* sWl = sAh + 12288;
    const int KDIM = 192;
    int tid = threadIdx.x;
    int t0 = blockIdx.x * 128;
    int b = t0 >> 12, l0 = t0 & 4095;
    int ysel = blockIdx.y;
    bool isLow = ysel >= 6;
    int n0 = (isLow ? (ysel - 6) : ysel) * 128;
    const ushort_t* Ahi = isLow ? lowh : xnh;
    const ushort_t* Alo = isLow ? lowl : xnl;
    const ushort_t* Whi = isLow ? wLowH : wInH;
    const ushort_t* Wlo = isLow ? wLowL : wInL;
    int arow = tid >> 1, kgA = (tid & 1) * 2;
    const ushort_t* gAh = Ahi + (size_t)(t0 + arow) * KDIM + kgA * 8;
    const ushort_t* gAl = Alo + (size_t)(t0 + arow) * KDIM + kgA * 8;
    const ushort_t* gWh = Whi + (size_t)(n0 + arow) * KDIM + kgA * 8;
    const ushort_t* gWl = Wlo + (size_t)(n0 + arow) * KDIM + kgA * 8;
    int lane = tid & 63, w = tid >> 6;
    int ln = lane & 15, kg = lane >> 4;
    int am0 = w * 32 + ln;
    f32x4 acc[2][8];
#pragma unroll
    for (int mf = 0; mf < 2; mf++)
#pragma unroll
        for (int nf = 0; nf < 8; nf++) acc[mf][nf] = (f32x4){0.f, 0.f, 0.f, 0.f};

    for (int k0 = 0; k0 < KDIM; k0 += 32) {
        __syncthreads();
        {
            ushort8 a0 = *(const ushort8*)(gAh + k0);
            ushort8 a1 = *(const ushort8*)(gAh + k0 + 8);
            *(ushort8*)(sAh + kgA*1024 + arow*8) = a0;
            *(ushort8*)(sAh + (kgA+1)*1024 + arow*8) = a1;
            ushort8 b0 = *(const ushort8*)(gAl + k0);
            ushort8 b1 = *(const ushort8*)(gAl + k0 + 8);
            *(ushort8*)(sAl + kgA*1024 + arow*8) = b0;
            *(ushort8*)(sAl + (kgA+1)*1024 + arow*8) = b1;
            ushort8 w0 = *(const ushort8*)(gWh + k0);
            ushort8 w1 = *(const ushort8*)(gWh + k0 + 8);
            *(ushort8*)(sWh + kgA*1024 + arow*8) = w0;
            *(ushort8*)(sWh + (kgA+1)*1024 + arow*8) = w1;
            ushort8 w2 = *(const ushort8*)(gWl + k0);
            ushort8 w3 = *(const ushort8*)(gWl + k0 + 8);
            *(ushort8*)(sWl + kgA*1024 + arow*8) = w2;
            *(ushort8*)(sWl + (kgA+1)*1024 + arow*8) = w3;
        }
        __syncthreads();
        bf16x8 aH[2], aL[2];
#pragma unroll
        for (int mf = 0; mf < 2; mf++) {
            aH[mf] = *(const bf16x8*)(sAh + kg*1024 + (am0 + mf*16)*8);
            aL[mf] = *(const bf16x8*)(sAl + kg*1024 + (am0 + mf*16)*8);
        }
#pragma unroll
        for (int half = 0; half < 2; half++) {
            bf16x8 bH[4], bL[4];
#pragma unroll
            for (int n4 = 0; n4 < 4; n4++) {
                int nr = (half*4 + n4)*16 + ln;
                bH[n4] = *(const bf16x8*)(sWh + kg*1024 + nr*8);
                bL[n4] = *(const bf16x8*)(sWl + kg*1024 + nr*8);
            }
#pragma unroll
            for (int mf = 0; mf < 2; mf++)
#pragma unroll
                for (int n4 = 0; n4 < 4; n4++) {
                    int nf = half*4 + n4;
                    acc[mf][nf] = __builtin_amdgcn_mfma_f32_16x16x32_bf16(aH[mf], bH[n4], acc[mf][nf], 0, 0, 0);
                    acc[mf][nf] = __builtin_amdgcn_mfma_f32_16x16x32_bf16(aH[mf], bL[n4], acc[mf][nf], 0, 0, 0);
                    acc[mf][nf] = __builtin_amdgcn_mfma_f32_16x16x32_bf16(aL[mf], bH[n4], acc[mf][nf], 0, 0, 0);
                }
        }
    }
    // direct stores: in_proj -> bf16 (xh/z), low_proj -> fp32 (lowp)
#pragma unroll
    for (int mf = 0; mf < 2; mf++) {
        int l = l0 + w*32 + mf*16 + kg*4;
#pragma unroll
        for (int nf = 0; nf < 8; nf++) {
            int n = n0 + nf*16 + ln;
            if (!isLow) {
                ushort4v hv;
#pragma unroll
                for (int j = 0; j < 4; j++) hv[j] = f2bf(acc[mf][nf][j]);
                ushort_t* dstb = (n < DI) ? (xhb + ((size_t)b*DI + n)*LL + l)
                                          : (zb  + ((size_t)b*DI + (n - DI))*LL + l);
                *(ushort4v*)dstb = hv;
            } else {
                *(f32x4*)(lowp + ((size_t)b*DI + n)*LL + l) = acc[mf][nf];
            }
        }
    }
}

// -------- channel-major-A MFMA GEMM (fp32 A), 64-token tiles: x_proj ----------
template<int MODE, int SPLIT, int PERM0>
__global__ __launch_bounds__(256) void gemm_cmaj(
    const float* __restrict__ A0, const float* __restrict__ A1,
    const ushort_t* __restrict__ W0h, const ushort_t* __restrict__ W0l,
    const ushort_t* __restrict__ W1h, const ushort_t* __restrict__ W1l,
    const float* __restrict__ resid,
    float* __restrict__ o0, float* __restrict__ o1, int Nreal)
{
    __shared__ __align__(16) float sA[32*68];       // [32][68]
    __shared__ __align__(16) ushort_t sWh[4*64*8];  // [4][64][8]
    __shared__ __align__(16) ushort_t sWl[4*64*8];
    bool sel = (blockIdx.z == 1);
    const float* A = sel ? A1 : A0;
    const ushort_t* Wh = sel ? W1h : W0h;
    const ushort_t* Wl = sel ? W1l : W0l;
    float* out0 = sel ? o1 : o0;
    const bool perm = sel ? false : (PERM0 != 0);
    int tid = threadIdx.x;
    int t0 = blockIdx.x * 64;
    int b = t0 >> 12, l0 = t0 & 4095;
    int n0 = blockIdx.y * 64;
    const float* Ab = A + (size_t)b * 384 * LL;
    int wrow = tid >> 2, kgW = tid & 3;
    int lane = tid & 63, w = tid >> 6;
    int ln = lane & 15, kg = lane >> 4;
    int am0 = w * 16 + ln;
    f32x4 acc[4];
#pragma unroll
    for (int nf = 0; nf < 4; nf++) acc[nf] = (f32x4){0.f, 0.f, 0.f, 0.f};

    for (int k0 = 0; k0 < 384; k0 += 32) {
        __syncthreads();
#pragma unroll
        for (int i = 0; i < 2; i++) {
            int idx = tid + 256*i;
            int row = idx >> 4, ch = idx & 15;
            int m = ch * 4;
            int src = perm ? (((m >> 2) & 3) * 1024 + (((l0 + m) >> 4) << 2))
                           : (l0 + m);
            float4 v = *(const float4*)&Ab[(size_t)(k0 + row)*LL + src];
            *(float4*)&sA[row*68 + m] = v;
        }
        {
            ushort8 wv = *(const ushort8*)(Wh + (size_t)(n0 + wrow)*384 + k0 + kgW*8);
            *(ushort8*)(sWh + kgW*512 + wrow*8) = wv;
            if (SPLIT == 3) {
                ushort8 wl = *(const ushort8*)(Wl + (size_t)(n0 + wrow)*384 + k0 + kgW*8);
                *(ushort8*)(sWl + kgW*512 + wrow*8) = wl;
            }
        }
        __syncthreads();
        bf16x8 aH, aL;
#pragma unroll
        for (int e = 0; e < 8; e++) {
            float v = sA[(kg*8 + e)*68 + am0];
            ushort_t h = f2bf(v);
            aH[e] = (short)h;
            if (SPLIT == 3) aL[e] = (short)f2bf(v - bf2f(h));
        }
        bf16x8 bH[4], bL[4];
#pragma unroll
        for (int nf = 0; nf < 4; nf++) {
            bH[nf] = *(const bf16x8*)(sWh + kg*512 + (nf*16 + ln)*8);
            if (SPLIT == 3) bL[nf] = *(const bf16x8*)(sWl + kg*512 + (nf*16 + ln)*8);
        }
#pragma unroll
        for (int nf = 0; nf < 4; nf++) {
            acc[nf] = __builtin_amdgcn_mfma_f32_16x16x32_bf16(aH, bH[nf], acc[nf], 0, 0, 0);
            if (SPLIT == 3) {
                acc[nf] = __builtin_amdgcn_mfma_f32_16x16x32_bf16(aH, bL[nf], acc[nf], 0, 0, 0);
                acc[nf] = __builtin_amdgcn_mfma_f32_16x16x32_bf16(aL, bH[nf], acc[nf], 0, 0, 0);
            }
        }
    }

    if (MODE == 2) {
#pragma unroll
        for (int j = 0; j < 4; j++) {
            int t = t0 + w*16 + kg*4 + j;
#pragma unroll
            for (int nf = 0; nf < 4; nf++) {
                int n = n0 + nf*16 + ln;
                out0[(size_t)t*CM + n] = resid[(size_t)t*CM + n] + acc[nf][j];
            }
        }
    } else {
        int l = l0 + w*16 + kg*4;
#pragma unroll
        for (int nf = 0; nf < 4; nf++) {
            int n = n0 + nf*16 + ln;
            if (n < Nreal)
                *(f32x4*)(out0 + ((size_t)b*Nreal + n)*LL + l) = acc[nf];
        }
    }
}

// -------- out_proj GEMM: bf16 A-plane (ygb) x wOutH -> out = resid + acc ------
// A is ALREADY the bf16-hi values out_proj used before (bit-identical result);
// halves the y1 HBM round-trip and removes per-k f2bf VALU work.
__global__ __launch_bounds__(256) void gemm_out(
    const ushort_t* __restrict__ Ab_, const ushort_t* __restrict__ Wh,
    const float* __restrict__ resid, float* __restrict__ out0)
{
    __shared__ __align__(16) ushort_t sAb[32*72];   // [32][72] bf16
    __shared__ __align__(16) ushort_t sWh[4*64*8];  // [4][64][8]
    int tid = threadIdx.x;
    int t0 = blockIdx.x * 64;
    int b = t0 >> 12, l0 = t0 & 4095;
    int n0 = blockIdx.y * 64;
    const ushort_t* Ab = Ab_ + (size_t)b * 384 * LL;
    int wrow = tid >> 2, kgW = tid & 3;
    int lane = tid & 63, w = tid >> 6;
    int ln = lane & 15, kg = lane >> 4;
    int am0 = w * 16 + ln;
    int arow = tid >> 3, acol = (tid & 7) * 8;
    f32x4 acc[4];
#pragma unroll
    for (int nf = 0; nf < 4; nf++) acc[nf] = (f32x4){0.f, 0.f, 0.f, 0.f};

    for (int k0 = 0; k0 < 384; k0 += 32) {
        __syncthreads();
        {
            ushort8 v = *(const ushort8*)&Ab[(size_t)(k0 + arow)*LL + l0 + acol];
            *(ushort8*)&sAb[arow*72 + acol] = v;
            ushort8 wv = *(const ushort8*)(Wh + (size_t)(n0 + wrow)*384 + k0 + kgW*8);
            *(ushort8*)(sWh + kgW*512 + wrow*8) = wv;
        }
        __syncthreads();
        bf16x8 aH;
#pragma unroll
        for (int e = 0; e < 8; e++) aH[e] = (short)sAb[(kg*8 + e)*72 + am0];
        bf16x8 bH[4];
#pragma unroll
        for (int nf = 0; nf < 4; nf++)
            bH[nf] = *(const bf16x8*)(sWh + kg*512 + (nf*16 + ln)*8);
#pragma unroll
        for (int nf = 0; nf < 4; nf++)
            acc[nf] = __builtin_amdgcn_mfma_f32_16x16x32_bf16(aH, bH[nf], acc[nf], 0, 0, 0);
    }
#pragma unroll
    for (int j = 0; j < 4; j++) {
        int t = t0 + w*16 + kg*4 + j;
#pragma unroll
        for (int nf = 0; nf < 4; nf++) {
            int n = n0 + nf*16 + ln;
            out0[(size_t)t*CM + n] = resid[(size_t)t*CM + n] + acc[nf][j];
        }
    }
}

// -------- depthwise 3x3 conv + bias + SiLU (bf16 in) -> xs fp32 PERM layout ---
__global__ __launch_bounds__(256) void conv2d_silu_kernel(const ushort_t* __restrict__ xhb,
    const float* __restrict__ w, const float* __restrict__ bias, float* __restrict__ xs)
{
    int tid = threadIdx.x;
    int l0 = (blockIdx.x * 256 + tid) * 4;
    int c = blockIdx.y, b = blockIdx.z;
    const ushort_t* P = xhb + ((size_t)b*DI + c)*LL;
    int h = l0 >> 6, w0 = l0 & 63;
    float wc[9];
#pragma unroll
    for (int k = 0; k < 9; k++) wc[k] = w[c*9 + k];
    float bs = bias[c];
    float av[4] = {bs, bs, bs, bs};
#pragma unroll
    for (int kh = 0; kh < 3; kh++) {
        int hh = h + kh - 1;
        if ((unsigned)hh < 64u) {
            const ushort_t* R = P + hh*64;
#pragma unroll
            for (int j = 0; j < 4; j++) {
#pragma unroll
                for (int kw = 0; kw < 3; kw++) {
                    int wv = w0 + j + kw - 1;
                    if ((unsigned)wv < 64u)
                        av[j] = fmaf(wc[kh*3 + kw], bf2f(R[wv]), av[j]);
                }
            }
        }
    }
    f32x4 o;
#pragma unroll
    for (int j = 0; j < 4; j++) {
        float sg = 1.f / (1.f + __expf(-av[j]));
        o[j] = av[j] * sg;
    }
    int pb = ((l0 >> 2) & 3) * 1024 + ((l0 >> 4) << 2);
    *(f32x4*)&xs[((size_t)b*DI + c)*LL + pb] = o;
}

// -------- SimpleGates on low B/C + sum high+low -> dbc [B][44][L] -------------
__global__ __launch_bounds__(256) void gates_kernel(const float* __restrict__ dbcH,
    const float* __restrict__ dbcL,
    const float* __restrict__ sgb1, const float* __restrict__ sgb2,
    const float* __restrict__ sgc1, const float* __restrict__ sgc2,
    float* __restrict__ dbc)
{
    __shared__ float w1[192*16];
    __shared__ float w2[16*96];
    __shared__ float red[4][16][64];
    int tid = threadIdx.x;
    int gate = blockIdx.z;
    const float* g1 = gate ? sgc1 : sgb1;
    const float* g2 = gate ? sgc2 : sgb2;
    for (int i = tid; i < 192*16; i += 256) w1[i] = g1[i];
    for (int i = tid; i < 16*96;  i += 256) w2[i] = g2[i];
    int lq = tid & 63, p = tid >> 6;
    int l = blockIdx.x * 64 + lq;
    int b = blockIdx.y;
    size_t pb_ = (size_t)b*NCH*LL + l;
    __syncthreads();
    if (!gate) {
#pragma unroll
        for (int i = 0; i < 3; i++) {
            int c = p*3 + i;
            dbc[pb_ + (size_t)c*LL] = dbcH[pb_ + (size_t)c*LL] + dbcL[pb_ + (size_t)c*LL];
        }
    }
    int coff = RK + gate*NST;
    float xin[16], og[16];
#pragma unroll
    for (int n = 0; n < 16; n++) { xin[n] = dbcL[pb_ + (size_t)(coff+n)*LL]; og[n] = 0.f; }
    int h0 = p * 24;
    for (int h = h0; h < h0 + 24; h++) {
        float ya = 0.f, yb = 0.f;
#pragma unroll
        for (int n = 0; n < 16; n++) {
            ya = fmaf(w1[h*16+n], xin[n], ya);
            yb = fmaf(w1[(h+SGH)*16+n], xin[n], yb);
        }
        float gg = 0.5f * ya * (1.f + erff(ya * 0.70710678f)) * yb;
#pragma unroll
        for (int n = 0; n < 16; n++) og[n] = fmaf(w2[n*SGH+h], gg, og[n]);
    }
#pragma unroll
    for (int n = 0; n < 16; n++) red[p][n][lq] = og[n];
    __syncthreads();
#pragma unroll
    for (int i = 0; i < 4; i++) {
        int n = p*4 + i;
        float v = red[0][n][lq] + red[1][n][lq] + red[2][n][lq] + red[3][n][lq];
        dbc[pb_ + (size_t)(coff+n)*LL] = dbcH[pb_ + (size_t)(coff+n)*LL] + v;
    }
}

// -------- residual dilated dwconv1d: dts normal; Bs/Cs in PERM layout ---------
__global__ __launch_bounds__(256) void conv_dbc_kernel(const float* __restrict__ dbc,
    const float* __restrict__ wdt, const float* __restrict__ wB, const float* __restrict__ wC,
    float* __restrict__ dts, float* __restrict__ Bs, float* __restrict__ Cs)
{
    int l = blockIdx.x * 256 + threadIdx.x;
    int c = blockIdx.y, b = blockIdx.z;
    const float* wsrc = (c < RK) ? (wdt + c*15)
                      : (c < RK+NST ? wB + (c-RK)*15 : wC + (c-RK-NST)*15);
    float w[15];
#pragma unroll
    for (int k = 0; k < 15; k++) w[k] = wsrc[k];
    const float* P = dbc + ((size_t)b*NCH + c)*LL;
    float a = P[l];
#pragma unroll
    for (int k = 0; k < 15; k++) {
        int lt = l + 2*k - 14;
        if ((unsigned)lt < (unsigned)LL) a = fmaf(w[k], P[lt], a);
    }
    if (c < RK)            dts[((size_t)b*RK  + c)*LL + l] = a;
    else if (c < RK+NST)   Bs [((size_t)b*NST + (c-RK))*LL + permidx(l)] = a;
    else                   Cs [((size_t)b*NST + (c-RK-NST))*LL + permidx(l)] = a;
}

// -------- delta projection + softplus -> delta in PERM layout -----------------
__global__ __launch_bounds__(256) void delta_kernel(const float* __restrict__ dts,
    const float* __restrict__ dtw, const float* __restrict__ dtb, float* __restrict__ delta)
{
    __shared__ float sdt[RK][128];
    __shared__ float sw[64][RK];
    int tid = threadIdx.x;
    int l0 = blockIdx.x * 128, d0 = blockIdx.y * 64, b = blockIdx.z;
    for (int i = tid; i < RK*128; i += 256) {
        int r = i >> 7, lq = i & 127;
        sdt[r][lq] = dts[((size_t)b*RK + r)*LL + l0 + lq];
    }
    for (int i = tid; i < 64*RK; i += 256) {
        int dq = i / RK, r = i - dq*RK;
        sw[dq][r] = dtw[(size_t)(d0+dq)*RK + r];
    }
    __syncthreads();
    int lq = tid & 63, g = tid >> 6;
    for (int dd = 0; dd < 16; dd++) {
        int dqq = g*16 + dd, d = d0 + dqq;
        float wr[RK];
#pragma unroll
        for (int r = 0; r < RK; r++) wr[r] = sw[dqq][r];
        float bias = dtb[d];
#pragma unroll
        for (int li = 0; li < 2; li++) {
            int lloc = lq + li*64;
            float s = bias;
#pragma unroll
            for (int r = 0; r < RK; r++) s = fmaf(wr[r], sdt[r][lloc], s);
            float sp = fmaxf(s, 0.f) + __logf(1.f + __expf(-fabsf(s)));
            delta[((size_t)b*DI + d)*LL + permidx(l0 + lloc)] = sp;
        }
    }
}

// -------- selective scan v4 (measured best, 64 VGPR): half-split + fixup ------
__global__ __launch_bounds__(256) void scan_kernel(
    const float* __restrict__ u_, const float* __restrict__ delta_,
    const float* __restrict__ Bs_, const float* __restrict__ Cs_,
    const float* __restrict__ Alogs, const float* __restrict__ Ds,
    float* __restrict__ y0_, float* __restrict__ y1_)
{
    __shared__ float wAs[8][4], wBs[8][4];
    __shared__ float yt[16][258];
    int tid = threadIdx.x;
    int t4 = tid * 4;
    int bid = blockIdx.x;
    int half = bid & 1, bd = bid >> 1;
    int b = bd / DI, d = bd % DI;
    int n0 = half * 8;
    size_t rowoff = ((size_t)b*DI + d)*LL;
    float dl[16], du[16], yac[16];
    LD16P(du, u_ + rowoff, t4);
    LD16P(dl, delta_ + rowoff, t4);
    float Dd = Ds[d];
#pragma unroll
    for (int s = 0; s < 16; s++) {
        yac[s] = half ? 0.f : du[s]*Dd;
        du[s] = dl[s]*du[s];
    }
    int lane = tid & 63, w = tid >> 6;
#pragma unroll 1
    for (int j = 0; j < 8; j++) {
        float An = -__expf(Alogs[d*NST + n0 + j]);
        float Bn[16], Cn[16], t[16];
        LD16P(Bn, Bs_ + ((size_t)b*NST + n0 + j)*LL, t4);
        LD16P(Cn, Cs_ + ((size_t)b*NST + n0 + j)*LL, t4);
        float a = 1.f, h = 0.f;
#pragma unroll
        for (int s = 0; s < 16; s++) {
            float e = __expf(dl[s]*An);
            a *= e;
            h = fmaf(e, h, du[s]*Bn[s]);
            yac[s] = fmaf(Cn[s], h, yac[s]);
            t[s] = Cn[s]*a;
        }
        float ap = a, hv = h;
        for (int off = 1; off < 64; off <<= 1) {
            float pa = __shfl_up(ap, (unsigned)off, 64);
            float pb = __shfl_up(hv, (unsigned)off, 64);
            if (lane >= off) { hv = fmaf(ap, pb, hv); ap *= pa; }
        }
        if (lane == 63) { wAs[j][w] = ap; wBs[j][w] = hv; }
        __syncthreads();
        float PB = 0.f;
        for (int ww = 0; ww < w; ww++) PB = fmaf(wAs[j][ww], PB, wBs[j][ww]);
        hv = fmaf(ap, PB, hv);
        float tt = __shfl_up(hv, 1u, 64);
        float hin = lane ? tt : PB;
#pragma unroll
        for (int s = 0; s < 16; s++) yac[s] = fmaf(t[s], hin, yac[s]);
    }
#pragma unroll
    for (int i = 0; i < 16; i++) yt[i][tid] = yac[i];
    __syncthreads();
    float* yout = (half ? y1_ : y0_) + rowoff;
#pragma unroll
    for (int r = 0; r < 16; r++)
        yout[r*256 + tid] = yt[tid & 15][r*16 + (tid >> 4)];
}

// -------- out-norm LN(384) on y0+y1 + bf16-z SiLU gating -> bf16 ygb ----------
__global__ __launch_bounds__(1024) void outnorm_gate_kernel(const float* __restrict__ y0,
    const float* __restrict__ y1, const ushort_t* __restrict__ zb,
    const float* __restrict__ g, const float* __restrict__ bt,
    ushort_t* __restrict__ ygb)
{
    __shared__ float rs_[16][64], rq_[16][64];
    __shared__ float mu_s[64], rstd_s[64];
    int tid = threadIdx.x;
    int lq = tid & 63, p = tid >> 6;          // p in 0..15
    int l = blockIdx.x * 64 + lq;
    int b = blockIdx.y;
    const float* yp0 = y0 + (size_t)b*DI*LL + l;
    const float* yp1 = y1 + (size_t)b*DI*LL + l;
    float s = 0.f, q = 0.f;
#pragma unroll 4
    for (int i = 0; i < 24; i++) {
        int d = p*24 + i;
        float v = yp0[(size_t)d*LL] + yp1[(size_t)d*LL];
        s += v; q = fmaf(v, v, q);
    }
    rs_[p][lq] = s; rq_[p][lq] = q;
    __syncthreads();
    if (p == 0) {
        float ss = 0.f, qq = 0.f;
#pragma unroll
        for (int i = 0; i < 16; i++) { ss += rs_[i][lq]; qq += rq_[i][lq]; }
        float mu = ss * (1.f/DI);
        float var = qq * (1.f/DI) - mu*mu;
        mu_s[lq] = mu; rstd_s[lq] = rsqrtf(var + 1e-5f);
    }
    __syncthreads();
    float mu = mu_s[lq], rs = rstd_s[lq];
    const ushort_t* zp = zb + (size_t)b*DI*LL + l;
    ushort_t* op = ygb + (size_t)b*DI*LL + l;
#pragma unroll 4
    for (int i = 0; i < 24; i++) {
        int d = p*24 + i;
        float v = ((yp0[(size_t)d*LL] + yp1[(size_t)d*LL]) - mu)*rs*g[d] + bt[d];
        float zv = bf2f(zp[(size_t)d*LL]);
        float sg = 1.f / (1.f + __expf(-zv));
        op[(size_t)d*LL] = f2bf(v * (zv * sg));
    }
}

extern "C" void kernel_launch(void* const* d_in, const int* in_sizes, int n_in,
                              void* d_out, int out_size, void* d_ws, size_t ws_size,
                              hipStream_t stream)
{
    (void)in_sizes; (void)n_in; (void)out_size; (void)ws_size;
    const float* x     = (const float*)d_in[0];
    const float* low   = (const float*)d_in[1];
    const float* ln_g  = (const float*)d_in[2];
    const float* ln_b  = (const float*)d_in[3];
    const float* w_in  = (const float*)d_in[4];
    const float* w_low = (const float*)d_in[5];
    const float* w_c2d = (const float*)d_in[6];
    const float* b_c2d = (const float*)d_in[7];
    const float* w_xp  = (const float*)d_in[8];
    const float* w_xpl = (const float*)d_in[9];
    const float* w_cdt = (const float*)d_in[10];
    const float* w_cB  = (const float*)d_in[11];
    const float* w_cC  = (const float*)d_in[12];
    const float* sgb1  = (const float*)d_in[13];
    const float* sgb2  = (const float*)d_in[14];
    const float* sgc1  = (const float*)d_in[15];
    const float* sgc2  = (const float*)d_in[16];
    const float* dtw   = (const float*)d_in[17];
    const float* dtb   = (const float*)d_in[18];
    const float* Alogs = (const float*)d_in[19];
    const float* Ds    = (const float*)d_in[20];
    const float* ong   = (const float*)d_in[21];
    const float* onb   = (const float*)d_in[22];
    const float* w_out = (const float*)d_in[23];
    float* ws  = (float*)d_ws;
    float* out = (float*)d_out;
    dim3 blk(256);

    // bf16 plane aliases
    ushort_t* wInH  = (ushort_t*)(ws + O_WT_IN);   ushort_t* wInL  = wInH + 147456;
    ushort_t* wLowH = (ushort_t*)(ws + O_WT_LOW);  ushort_t* wLowL = wLowH + 73728;
    ushort_t* wOutH = (ushort_t*)(ws + O_WT_OUT);  ushort_t* wOutL = wOutH + 73728;
    ushort_t* wXpH  = (ushort_t*)(ws + O_WT_XP);   ushort_t* wXpL  = wXpH + 24576;
    ushort_t* wXplH = (ushort_t*)(ws + O_WT_XPL);  ushort_t* wXplL = wXplH + 24576;
    ushort_t* xnh   = (ushort_t*)(ws + O_XN);      ushort_t* xnl   = xnh + 3145728;
    ushort_t* lowh  = (ushort_t*)(ws + O_LOWT);    ushort_t* lowl  = lowh + 3145728;
    ushort_t* xhb   = (ushort_t*)(ws + O_XH);      // bf16 xh
    ushort_t* zb    = (ushort_t*)(ws + O_Z);       // bf16 z
    ushort_t* ygb   = (ushort_t*)(ws + O_YGB);     // bf16 gated output

    prep_kernel<<<3664, blk, 0, stream>>>(w_in, wInH, wInL, w_low, wLowH, wLowL,
                                          w_out, wOutH, wOutL,
                                          w_xp, wXpH, wXpL, w_xpl, wXplH, wXplL,
                                          x, ln_g, ln_b, xnh, xnl, low, lowh, lowl);

    gemm_inlow<<<dim3(128,9), blk, 0, stream>>>(xnh, xnl, wInH, wInL,
                                                lowh, lowl, wLowH, wLowL,
                                                xhb, zb, ws+O_LOWP);

    conv2d_silu_kernel<<<dim3(4,384,4), blk, 0, stream>>>(xhb, w_c2d, b_c2d, ws+O_XS);

    gemm_cmaj<1,3,1><<<dim3(256,1,2), blk, 0, stream>>>(ws+O_XS, ws+O_LOWP,
                                                        wXpH, wXpL, wXplH, wXplL,
                                                        nullptr, ws+O_DBCH, ws+O_DBCL, NCH);

    gates_kernel<<<dim3(64,4,2), blk, 0, stream>>>(ws+O_DBCH, ws+O_DBCL, sgb1, sgb2, sgc1, sgc2, ws+O_DBC);

    conv_dbc_kernel<<<dim3(16,44,4), blk, 0, stream>>>(ws+O_DBC, w_cdt, w_cB, w_cC,
                                                       ws+O_DTS, ws+O_BS, ws+O_CS);
    delta_kernel<<<dim3(32,6,4), blk, 0, stream>>>(ws+O_DTS, dtw, dtb, ws+O_DELTA);

    scan_kernel<<<3072, blk, 0, stream>>>(ws+O_XS, ws+O_DELTA, ws+O_BS, ws+O_CS, Alogs, Ds,
                                          ws+O_Y, ws+O_Y1);

    outnorm_gate_kernel<<<dim3(64,4), dim3(1024), 0, stream>>>(ws+O_Y, ws+O_Y1, zb, ong, onb, ygb);

    gemm_out<<<dim3(256,3), blk, 0, stream>>>(ygb, wOutH, x, out);
}